// Round 2
// baseline (677.247 us; speedup 1.0000x reference)
//
#include <hip/hip_runtime.h>

typedef _Float16 half8 __attribute__((ext_vector_type(8)));
typedef float f32x4 __attribute__((ext_vector_type(4)));

#define B_ 4
#define C_ 64
#define N_ 8192
#define K_ 20
#define LCELL 8                   // per-(split,class) sorted list depth
#define NSPLIT 4
#define NCAND (16 * LCELL * NSPLIT)  // 512 candidates per query into refine
#define CNT_TOTAL (B_ * N_ * K_)  // 655360
#define BN_EPSF 1e-5f

__device__ __forceinline__ f32x4 max4(f32x4 a, f32x4 b) {
  f32x4 r;
  r.x = fmaxf(a.x, b.x); r.y = fmaxf(a.y, b.y);
  r.z = fmaxf(a.z, b.z); r.w = fmaxf(a.w, b.w);
  return r;
}
__device__ __forceinline__ f32x4 min4(f32x4 a, f32x4 b) {
  f32x4 r;
  r.x = fminf(a.x, b.x); r.y = fminf(a.y, b.y);
  r.z = fminf(a.z, b.z); r.w = fminf(a.w, b.w);
  return r;
}

// ---- Kernel 1: transpose x -> xt (f32 + f16), per-point sq (f32+f64),
// y1 = xt*W1^T, y2 = xt*W2^T - y1. W row o==lane held in 128 VGPRs.
// sq is stored PRE-BIASED by +512 (knn key bias folded in; refine uses sqd).
__global__ __launch_bounds__(256) void prep_kernel(
    const float* __restrict__ x, const float* __restrict__ W,
    float* __restrict__ xt, _Float16* __restrict__ xt16,
    float* __restrict__ sq, double* __restrict__ sqd,
    float* __restrict__ y1, float* __restrict__ y2) {
  __shared__ float xs[64 * 68];  // [n][c], stride 68 (16B-aligned rows)
  int b = blockIdx.x >> 7;
  int n0 = (blockIdx.x & 127) * 64;
  int t = threadIdx.x;
  int lane = t & 63;
  int wv = t >> 6;
#pragma unroll
  for (int i = 0; i < 16; ++i) {
    int lin = i * 256 + t;
    int c = lin >> 6, j = lin & 63;
    xs[j * 68 + c] = x[((b * 64 + c) * N_) + n0 + j];
  }
  // W row o = lane into registers (L1/L2-hot, 32 KB total)
  float4 w1[16], w2[16];
  const float4* wr = (const float4*)(W + lane * 128);
#pragma unroll
  for (int u = 0; u < 16; ++u) {
    w1[u] = wr[u];
    w2[u] = wr[16 + u];
  }
  __syncthreads();
#pragma unroll 2
  for (int i = 0; i < 16; ++i) {
    int nl = i * 4 + wv;
    const float4* xr = (const float4*)&xs[nl * 68];
    float d1 = 0.f, d2 = 0.f;
#pragma unroll
    for (int u = 0; u < 16; ++u) {
      float4 xv = xr[u];
      d1 = fmaf(xv.x, w1[u].x, d1); d1 = fmaf(xv.y, w1[u].y, d1);
      d1 = fmaf(xv.z, w1[u].z, d1); d1 = fmaf(xv.w, w1[u].w, d1);
      d2 = fmaf(xv.x, w2[u].x, d2); d2 = fmaf(xv.y, w2[u].y, d2);
      d2 = fmaf(xv.z, w2[u].z, d2); d2 = fmaf(xv.w, w2[u].w, d2);
    }
    int n = n0 + nl;
    y1[((b * N_) + n) * 64 + lane] = d1;
    y2[((b * N_) + n) * 64 + lane] = d2 - d1;
  }
#pragma unroll
  for (int i = 0; i < 16; ++i) {
    int lin = i * 256 + t;
    int c = lin & 63, nl = lin >> 6;
    float v = xs[nl * 68 + c];
    size_t o = ((size_t)(b * N_) + n0 + nl) * 64 + c;
    xt[o] = v;
    xt16[o] = (_Float16)v;
  }
  if (t < 64) {
    float s = 0.f;
    double sd = 0.0;
#pragma unroll
    for (int c = 0; c < 64; ++c) {
      float v = xs[t * 68 + c];
      s = fmaf(v, v, s);
      sd = fma((double)v, (double)v, sd);
    }
    sq[b * N_ + n0 + t] = s + 512.0f;  // pre-biased for knn key
    sqd[b * N_ + n0 + t] = sd;
  }
}

// ---- Kernel 2: MFMA distance scan over one of 4 candidate splits (2048
// cands each). NSPLIT=4 doubles the grid (2048 blocks = 8 blocks/CU) and the
// register diet (single-pair in-iteration prefetch instead of 2-deep
// ping-pong; live set ~72 regs) + __launch_bounds__(256,6) raises resident
// waves/SIMD from 4 to ~6 — the round-1 post-mortem showed the kernel is
// latency-bound with every pipe <50% busy at exactly 4 waves/SIMD.
// Pair-merge insert kept: sorted candidate pair (lo,hi) merged into the
// sorted-8 list via out[j] = min3(dl[j], max(dl[j-1],lo), max(dl[j-2],hi)).
// Packed value: (float_bits(sq512 - 2dot) & ~255) | tile_id(7b). Refine
// reconstructs (key, index) from (value, slot).
__global__ __launch_bounds__(256, 6) void knn_mfma_kernel(
    const _Float16* __restrict__ xt16, const float* __restrict__ sq,
    int* __restrict__ pidx) {
  int t = threadIdx.x;
  int wave = t >> 6;
  int lane = t & 63;
  int col = lane & 15;
  int quad = lane >> 4;
  int blk = blockIdx.x;
  int split = blk & 3;
  int qt = (blk >> 2) & 127;
  int b = blk >> 9;
  int q0 = qt * 64 + wave * 16;
  size_t bbase = (size_t)b * N_;

  // A fragments: A[m=col][k=quad*8+j] -> query row q0+col
  const _Float16* arow = xt16 + (bbase + q0 + col) * 64;
  half8 A0 = *(const half8*)(arow + quad * 8);
  half8 A1 = *(const half8*)(arow + 32 + quad * 8);

  int dl[4][LCELL];
#pragma unroll
  for (int r = 0; r < 4; ++r)
#pragma unroll
    for (int j = 0; j < LCELL; ++j) dl[r][j] = 0x7fffffff;

#define PAIR_INSERT(accX, accY, sA, sB, CTB)                                 \
  {                                                                          \
    const int ctb_ = (CTB);                                                  \
    _Pragma("unroll") for (int r = 0; r < 4; ++r) {                          \
      float kA = fmaf((accX)[r], -2.0f, (sA));                               \
      float kB = fmaf((accY)[r], -2.0f, (sB));                               \
      int va = (__float_as_int(kA) & ~255) | ctb_;                           \
      int vb = (__float_as_int(kB) & ~255) | (ctb_ + 1);                     \
      int lo = min(va, vb), hi = max(va, vb);                                \
      int o0 = min(dl[r][0], lo);                                            \
      int o1 = min(min(dl[r][1], max(dl[r][0], lo)), hi);                    \
      int o2 = min(min(dl[r][2], max(dl[r][1], lo)), max(dl[r][0], hi));     \
      int o3 = min(min(dl[r][3], max(dl[r][2], lo)), max(dl[r][1], hi));     \
      int o4 = min(min(dl[r][4], max(dl[r][3], lo)), max(dl[r][2], hi));     \
      int o5 = min(min(dl[r][5], max(dl[r][4], lo)), max(dl[r][3], hi));     \
      int o6 = min(min(dl[r][6], max(dl[r][5], lo)), max(dl[r][4], hi));     \
      int o7 = min(min(dl[r][7], max(dl[r][6], lo)), max(dl[r][5], hi));     \
      dl[r][0] = o0; dl[r][1] = o1; dl[r][2] = o2; dl[r][3] = o3;            \
      dl[r][4] = o4; dl[r][5] = o5; dl[r][6] = o6; dl[r][7] = o7;            \
    }                                                                        \
  }

  int c0 = split * (N_ / NSPLIT);
  const _Float16* bp = xt16 + (bbase + c0 + col) * 64 + quad * 8;
  const float* sp = sq + bbase + c0 + col;

  // prologue: load pair 0 (tiles 0,1)
  half8 B0 = *(const half8*)bp;
  half8 B1 = *(const half8*)(bp + 32);
  half8 C0 = *(const half8*)(bp + 1024);
  half8 C1 = *(const half8*)(bp + 1024 + 32);
  float s0 = sp[0], s1 = sp[16];

  const f32x4 z = {0.f, 0.f, 0.f, 0.f};
  // 64 pairs (128 tiles, 2048 candidates). Final iteration's prefetch reads
  // up to ~8KB past the panel; worst case (b=3,split=3) lands in y1 — ws
  // memory, never inserted (loop ends), harmless.
  for (int pr = 0; pr < 64; ++pr) {
    f32x4 aA = __builtin_amdgcn_mfma_f32_16x16x32_f16(A0, B0, z, 0, 0, 0);
    aA = __builtin_amdgcn_mfma_f32_16x16x32_f16(A1, B1, aA, 0, 0, 0);
    B0 = *(const half8*)(bp + 2048);            // prefetch next pair tile 0
    B1 = *(const half8*)(bp + 2048 + 32);
    f32x4 aB = __builtin_amdgcn_mfma_f32_16x16x32_f16(A0, C0, z, 0, 0, 0);
    aB = __builtin_amdgcn_mfma_f32_16x16x32_f16(A1, C1, aB, 0, 0, 0);
    C0 = *(const half8*)(bp + 3072);            // prefetch next pair tile 1
    C1 = *(const half8*)(bp + 3072 + 32);
    PAIR_INSERT(aA, aB, s0, s1, 2 * pr);
    s0 = sp[32]; s1 = sp[48];
    bp += 2048; sp += 32;
  }
#undef PAIR_INSERT

#pragma unroll
  for (int r = 0; r < 4; ++r) {
    int q = q0 + quad * 4 + r;
    int* o = pidx + (bbase + q) * NCAND + split * (16 * LCELL) + col * LCELL;
#pragma unroll
    for (int j = 0; j < LCELL; ++j) o[j] = dl[r][j];  // raw packed value
  }
}

// ---- Kernel 3: refinement v8 — one WAVE per point. With NSPLIT=4 each lane
// owns exactly one (split=lane>>4, col=lane&15) cell = 8 ALREADY-SORTED
// packed values (scan wrote them ascending; int order == (key,tile) order and
// the double conversion with ci in low mantissa bits is monotone). Stage 1:
// load 2x int4, reconstruct keys, self-exclude (one bubble pass restores
// sortedness after the single displacement). Stage 2: 32 approx pop-min
// steps (6-shfl f64 butterfly); popped candidate s -> lane s. Margin: key
// error <= ~0.1 (f16 MFMA + 8-bit mask) << rank-20..32 distance span ->
// true top-20 in approx-top-32. Stage 3: lanes 0..31 IN PARALLEL compute
// their candidate's full fp64 dot vs LDS-broadcast query row; exact key =
// sqd - 2*dot + 1024, index in mantissa. Stage 4: 20 pop-min emit indices.
__global__ __launch_bounds__(256) void refine_kernel(
    const float* __restrict__ xt, const double* __restrict__ sqd,
    const int* __restrict__ pidx, int* __restrict__ idxf) {
  __shared__ float qs[4][64];
  int tid = threadIdx.x;
  int wave = tid >> 6, lane = tid & 63;
  int p = blockIdx.x * 4 + wave;  // global point id
  int b = p >> 13;
  size_t bbase = (size_t)b * N_;
  int plocal = p & (N_ - 1);

  // stage query row into LDS (lanes 0..15 write 16B each)
  if (lane < 16) {
    ((f32x4*)qs[wave])[lane] = ((const f32x4*)(xt + (size_t)p * 64))[lane];
  }
  // stage 1: lane's cell = (split=lane>>4, col=lane&15): 8 sorted values
  const int* pi = pidx + (size_t)p * NCAND + lane * 8;
  int4 ca = *(const int4*)pi;
  int4 cb = *(const int4*)(pi + 4);
  int vs[8] = {ca.x, ca.y, ca.z, ca.w, cb.x, cb.y, cb.z, cb.w};
  int col = lane & 15, split = lane >> 4;
  double dl[8];
#pragma unroll
  for (int j = 0; j < 8; ++j) {
    int dlv = vs[j];
    int ci = ((dlv & 255) << 4) + col + split * (N_ / NSPLIT);
    float key = __int_as_float(dlv & ~255);  // positive
    long long bits =
        (__double_as_longlong((double)key) & ~0x1FFFLL) | (long long)ci;
    double v = __longlong_as_double(bits);
    if (ci == plocal) v = 1e300;  // self-exclusion
    dl[j] = v;
  }
  // one bubble pass: restores sortedness after the single 1e300 displacement
#pragma unroll
  for (int j = 0; j < 7; ++j) {
    double lo = fmin(dl[j], dl[j + 1]), hi = fmax(dl[j], dl[j + 1]);
    dl[j] = lo; dl[j + 1] = hi;
  }
  double vh = dl[0], h1 = dl[1], h2 = dl[2], h3 = dl[3],
         h4 = dl[4], h5 = dl[5], h6 = dl[6], h7 = dl[7];

  // stage 2: 32 approx pops; popped candidate s -> lane s
  int myci = 0;
#pragma unroll
  for (int s = 0; s < 32; ++s) {
    double m = vh;
    m = fmin(m, __shfl_xor(m, 1, 64));
    m = fmin(m, __shfl_xor(m, 2, 64));
    m = fmin(m, __shfl_xor(m, 4, 64));
    m = fmin(m, __shfl_xor(m, 8, 64));
    m = fmin(m, __shfl_xor(m, 16, 64));
    m = fmin(m, __shfl_xor(m, 32, 64));
    if (lane == s) myci = (int)(__double_as_longlong(m) & 0x1FFFLL);
    bool adv = (vh == m);  // unique keys: exactly one owner advances
    vh = adv ? h1 : vh;
    h1 = adv ? h2 : h1;
    h2 = adv ? h3 : h2;
    h3 = adv ? h4 : h3;
    h4 = adv ? h5 : h4;
    h5 = adv ? h6 : h5;
    h6 = adv ? h7 : h6;
    h7 = adv ? 1e300 : h7;
  }
  // stage 3: parallel exact fp64 keys on lanes 0..31
  double kv = 1e300;
  if (lane < 32) {
    const f32x4* cr = (const f32x4*)(xt + (bbase + myci) * 64);
    const f32x4* qr = (const f32x4*)qs[wave];
    double a0 = 0.0, a1 = 0.0, a2 = 0.0, a3 = 0.0;
#pragma unroll
    for (int t2 = 0; t2 < 16; ++t2) {
      f32x4 cv = cr[t2];
      f32x4 qv = qr[t2];  // ds_read_b128 broadcast
      a0 = fma((double)cv.x, (double)qv.x, a0);
      a1 = fma((double)cv.y, (double)qv.y, a1);
      a2 = fma((double)cv.z, (double)qv.z, a2);
      a3 = fma((double)cv.w, (double)qv.w, a3);
    }
    double dot = (a0 + a1) + (a2 + a3);
    double kd = fma(dot, -2.0, sqd[bbase + myci]) + 1024.0;
    kv = __longlong_as_double(
        (__double_as_longlong(kd) & ~0x1FFFLL) | (long long)myci);
  }
  // stage 4: 20 smallest exact keys (ascending, index tie-break)
  int* o = idxf + (size_t)p * K_;
#pragma unroll
  for (int s = 0; s < K_; ++s) {
    double m = kv;
    m = fmin(m, __shfl_xor(m, 1, 64));
    m = fmin(m, __shfl_xor(m, 2, 64));
    m = fmin(m, __shfl_xor(m, 4, 64));
    m = fmin(m, __shfl_xor(m, 8, 64));
    m = fmin(m, __shfl_xor(m, 16, 64));
    m = fmin(m, __shfl_xor(m, 32, 64));
    if (lane == 0) o[s] = (int)(__double_as_longlong(m) & 0x1FFFLL);
    kv = (kv == m) ? 1e300 : kv;
  }
}

// ---- Kernel 4: one WAVE per point. Lane (u=lane&15, jb=lane>>4); 5 rounds:
// lane loads 16B chunk u of neighbor jb+4r -> each 16-lane group reads a full
// 256B y1 row per instruction (no partial lines). max/min/sum/sumsq of the
// gathered y1 reduced across jb via shfl_xor(16,32); y2 applied once:
// max(h)=max(g)+y2, sum(h)=sum(g)+K*y2, sumsq(h)=sum(g^2)+2*y2*sum(g)+K*y2^2.
// 4 points per wave sequentially; BN sums -> LDS atomics -> 128 global/block.
__global__ __launch_bounds__(256) void stats_kernel(
    const float* __restrict__ y1, const float* __restrict__ y2,
    const int* __restrict__ idxf, float* __restrict__ maxh,
    float* __restrict__ minh, float* __restrict__ gsum,
    float* __restrict__ gsq) {
  __shared__ float lsum[64], lsq[64];
  int tid = threadIdx.x;
  if (tid < 64) { lsum[tid] = 0.f; lsq[tid] = 0.f; }
  __syncthreads();
  int wv = tid >> 6, lane = tid & 63;
  int u = lane & 15, jb = lane >> 4;
  int p0 = blockIdx.x * 16 + wv * 4;  // 16 contiguous points per block
  size_t nb = (size_t)((p0 >> 13) * N_);
  f32x4 css = {0.f, 0.f, 0.f, 0.f}, cqq = {0.f, 0.f, 0.f, 0.f};
#pragma unroll
  for (int it = 0; it < 4; ++it) {
    int p = p0 + it;
    int idxval = (lane < K_) ? idxf[(size_t)p * K_ + lane] : 0;
    int n0 = __shfl(idxval, jb, 64);
    int n1 = __shfl(idxval, jb + 4, 64);
    int n2 = __shfl(idxval, jb + 8, 64);
    int n3 = __shfl(idxval, jb + 12, 64);
    int n4 = __shfl(idxval, jb + 16, 64);
    f32x4 g0 = ((const f32x4*)(y1 + (nb + n0) * 64))[u];
    f32x4 g1 = ((const f32x4*)(y1 + (nb + n1) * 64))[u];
    f32x4 g2 = ((const f32x4*)(y1 + (nb + n2) * 64))[u];
    f32x4 g3 = ((const f32x4*)(y1 + (nb + n3) * 64))[u];
    f32x4 g4 = ((const f32x4*)(y1 + (nb + n4) * 64))[u];
    f32x4 mx = g0, mn = g0, sm = g0, s2 = g0 * g0;
    mx = max4(mx, g1); mn = min4(mn, g1); sm += g1; s2 += g1 * g1;
    mx = max4(mx, g2); mn = min4(mn, g2); sm += g2; s2 += g2 * g2;
    mx = max4(mx, g3); mn = min4(mn, g3); sm += g3; s2 += g3 * g3;
    mx = max4(mx, g4); mn = min4(mn, g4); sm += g4; s2 += g4 * g4;
#pragma unroll
    for (int c = 0; c < 4; ++c) {
      mx[c] = fmaxf(mx[c], __shfl_xor(mx[c], 16, 64));
      mx[c] = fmaxf(mx[c], __shfl_xor(mx[c], 32, 64));
      mn[c] = fminf(mn[c], __shfl_xor(mn[c], 16, 64));
      mn[c] = fminf(mn[c], __shfl_xor(mn[c], 32, 64));
      sm[c] += __shfl_xor(sm[c], 16, 64);
      sm[c] += __shfl_xor(sm[c], 32, 64);
      s2[c] += __shfl_xor(s2[c], 16, 64);
      s2[c] += __shfl_xor(s2[c], 32, 64);
    }
    if (jb == 0) {  // lanes 0..15: full 256B contiguous stores
      f32x4 y2c = ((const f32x4*)(y2 + (size_t)p * 64))[u];
      ((f32x4*)(maxh + (size_t)p * 64))[u] = mx + y2c;
      ((f32x4*)(minh + (size_t)p * 64))[u] = mn + y2c;
      css += sm + 20.0f * y2c;
      cqq += s2 + 2.0f * y2c * sm + 20.0f * y2c * y2c;
    }
  }
  if (jb == 0) {
#pragma unroll
    for (int c = 0; c < 4; ++c) {
      atomicAdd(&lsum[u * 4 + c], css[c]);
      atomicAdd(&lsq[u * 4 + c], cqq[c]);
    }
  }
  __syncthreads();
  if (tid < 64) {
    atomicAdd(&gsum[tid], lsum[tid]);
    atomicAdd(&gsq[tid], lsq[tid]);
  }
}

// ---- Kernel 5: affine + relu + max-over-k selection, transposed store ----
__global__ __launch_bounds__(256) void final_kernel(
    const float* __restrict__ maxh, const float* __restrict__ minh,
    const float* __restrict__ gsum, const float* __restrict__ gsq,
    const float* __restrict__ gamma, const float* __restrict__ beta,
    float* __restrict__ out) {
  __shared__ float sc[64], cc_[64];
  __shared__ float tile[64 * 65];
  int b = blockIdx.x >> 7;
  int n0 = (blockIdx.x & 127) * 64;
  int t = threadIdx.x;
  if (t < 64) {
    float mean = gsum[t] * (1.0f / CNT_TOTAL);
    float var = gsq[t] * (1.0f / CNT_TOTAL) - mean * mean;
    float s = gamma[t] * rsqrtf(var + BN_EPSF);
    sc[t] = s;
    cc_[t] = beta[t] - mean * s;
  }
  __syncthreads();
#pragma unroll
  for (int i = 0; i < 16; ++i) {
    int lin = i * 256 + t;
    int o = lin & 63, nl = lin >> 6;
    size_t off = ((size_t)(b * N_) + n0 + nl) * 64 + o;
    float s = sc[o];
    float v = (s >= 0.f) ? maxh[off] : minh[off];
    float val = fmaxf(fmaf(v, s, cc_[o]), 0.f);
    tile[o * 65 + nl] = val;
  }
  __syncthreads();
#pragma unroll
  for (int i = 0; i < 16; ++i) {
    int lin = i * 256 + t;
    int nl = lin & 63, o = lin >> 6;
    out[((size_t)(b * 64) + o) * N_ + n0 + nl] = tile[o * 65 + nl];
  }
}

extern "C" void kernel_launch(void* const* d_in, const int* in_sizes, int n_in,
                              void* d_out, int out_size, void* d_ws,
                              size_t ws_size, hipStream_t stream) {
  const float* x = (const float*)d_in[0];
  const float* W = (const float*)d_in[1];
  const float* gamma = (const float*)d_in[2];
  const float* beta = (const float*)d_in[3];
  float* out = (float*)d_out;

  char* ws = (char*)d_ws;
  size_t off = 0;
  auto alloc = [&](size_t bytes) {
    char* p = ws + off;
    off += (bytes + 255) & ~(size_t)255;
    return p;
  };
  float* xt = (float*)alloc((size_t)B_ * N_ * 64 * 4);
  _Float16* xt16 = (_Float16*)alloc((size_t)B_ * N_ * 64 * 2);
  float* y1 = (float*)alloc((size_t)B_ * N_ * 64 * 4);
  float* y2 = (float*)alloc((size_t)B_ * N_ * 64 * 4);
  float* sq = (float*)alloc((size_t)B_ * N_ * 4);
  double* sqd = (double*)alloc((size_t)B_ * N_ * 8);
  int* pidx = (int*)alloc((size_t)B_ * N_ * NCAND * 4);  // 67 MB
  float* maxh = (float*)alloc((size_t)B_ * N_ * 64 * 4);
  int* idxf = (int*)alloc((size_t)B_ * N_ * K_ * 4);
  float* gsum = (float*)alloc(256);
  float* gsq = (float*)alloc(256);
  // minh aliases pidx (pidx fully consumed by refine before stats runs)
  float* minh = (float*)pidx;

  hipMemsetAsync(gsum, 0, 256, stream);
  hipMemsetAsync(gsq, 0, 256, stream);

  prep_kernel<<<B_ * (N_ / 64), 256, 0, stream>>>(x, W, xt, xt16, sq, sqd,
                                                  y1, y2);
  knn_mfma_kernel<<<B_ * (N_ / 64) * NSPLIT, 256, 0, stream>>>(xt16, sq, pidx);
  refine_kernel<<<(B_ * N_) / 4, 256, 0, stream>>>(xt, sqd, pidx, idxf);
  stats_kernel<<<(B_ * N_) / 16, 256, 0, stream>>>(y1, y2, idxf, maxh, minh,
                                                   gsum, gsq);
  final_kernel<<<B_ * (N_ / 64), 256, 0, stream>>>(maxh, minh, gsum, gsq,
                                                   gamma, beta, out);
}

// Round 3
// 613.205 us; speedup vs baseline: 1.1044x; 1.1044x over previous
//
#include <hip/hip_runtime.h>

typedef _Float16 half8 __attribute__((ext_vector_type(8)));
typedef float f32x4 __attribute__((ext_vector_type(4)));

#define B_ 4
#define C_ 64
#define N_ 8192
#define K_ 20
#define LCELL 8                   // per-(split,class) sorted list depth
#define NSPLIT 2
#define NCAND (16 * LCELL * NSPLIT)  // 256 candidates per query into refine
#define CNT_TOTAL (B_ * N_ * K_)  // 655360
#define BN_EPSF 1e-5f

__device__ __forceinline__ f32x4 max4(f32x4 a, f32x4 b) {
  f32x4 r;
  r.x = fmaxf(a.x, b.x); r.y = fmaxf(a.y, b.y);
  r.z = fmaxf(a.z, b.z); r.w = fmaxf(a.w, b.w);
  return r;
}
__device__ __forceinline__ f32x4 min4(f32x4 a, f32x4 b) {
  f32x4 r;
  r.x = fminf(a.x, b.x); r.y = fminf(a.y, b.y);
  r.z = fminf(a.z, b.z); r.w = fminf(a.w, b.w);
  return r;
}

// ---- Kernel 1: transpose x -> xt (f32 + f16), per-point sq (f32+f64),
// y1 = xt*W1^T, y2 = xt*W2^T - y1. W row o==lane held in 128 VGPRs.
// sq is stored PRE-BIASED by +512 (knn key bias folded in; refine uses sqd).
__global__ __launch_bounds__(256) void prep_kernel(
    const float* __restrict__ x, const float* __restrict__ W,
    float* __restrict__ xt, _Float16* __restrict__ xt16,
    float* __restrict__ sq, double* __restrict__ sqd,
    float* __restrict__ y1, float* __restrict__ y2) {
  __shared__ float xs[64 * 68];  // [n][c], stride 68 (16B-aligned rows)
  int b = blockIdx.x >> 7;
  int n0 = (blockIdx.x & 127) * 64;
  int t = threadIdx.x;
  int lane = t & 63;
  int wv = t >> 6;
#pragma unroll
  for (int i = 0; i < 16; ++i) {
    int lin = i * 256 + t;
    int c = lin >> 6, j = lin & 63;
    xs[j * 68 + c] = x[((b * 64 + c) * N_) + n0 + j];
  }
  // W row o = lane into registers (L1/L2-hot, 32 KB total)
  float4 w1[16], w2[16];
  const float4* wr = (const float4*)(W + lane * 128);
#pragma unroll
  for (int u = 0; u < 16; ++u) {
    w1[u] = wr[u];
    w2[u] = wr[16 + u];
  }
  __syncthreads();
#pragma unroll 2
  for (int i = 0; i < 16; ++i) {
    int nl = i * 4 + wv;
    const float4* xr = (const float4*)&xs[nl * 68];
    float d1 = 0.f, d2 = 0.f;
#pragma unroll
    for (int u = 0; u < 16; ++u) {
      float4 xv = xr[u];
      d1 = fmaf(xv.x, w1[u].x, d1); d1 = fmaf(xv.y, w1[u].y, d1);
      d1 = fmaf(xv.z, w1[u].z, d1); d1 = fmaf(xv.w, w1[u].w, d1);
      d2 = fmaf(xv.x, w2[u].x, d2); d2 = fmaf(xv.y, w2[u].y, d2);
      d2 = fmaf(xv.z, w2[u].z, d2); d2 = fmaf(xv.w, w2[u].w, d2);
    }
    int n = n0 + nl;
    y1[((b * N_) + n) * 64 + lane] = d1;
    y2[((b * N_) + n) * 64 + lane] = d2 - d1;
  }
#pragma unroll
  for (int i = 0; i < 16; ++i) {
    int lin = i * 256 + t;
    int c = lin & 63, nl = lin >> 6;
    float v = xs[nl * 68 + c];
    size_t o = ((size_t)(b * N_) + n0 + nl) * 64 + c;
    xt[o] = v;
    xt16[o] = (_Float16)v;
  }
  if (t < 64) {
    float s = 0.f;
    double sd = 0.0;
#pragma unroll
    for (int c = 0; c < 64; ++c) {
      float v = xs[t * 68 + c];
      s = fmaf(v, v, s);
      sd = fma((double)v, (double)v, sd);
    }
    sq[b * N_ + n0 + t] = s + 512.0f;  // pre-biased for knn key
    sqd[b * N_ + n0 + t] = sd;
  }
}

// ---- Kernel 2: MFMA distance scan over one of 2 candidate splits (4096
// cands = 256 tiles = 128 pairs). R1 structure ((256,4), 2-deep ping-pong,
// pair-merge insert) + DE-PHASED CIRCULAR SCAN: each block starts at pair
// (qt*37)&127 and wraps. R0-R2 showed wall time is invariant to VALU count
// and wave count (every pipe <50%): all blocks marched the panel from tile 0
// in lockstep -> L2 served phase-locked bursts and waves stalled together.
// Rotation de-correlates the L2 response schedule so waves fill each
// other's gaps. Tile ids in the packed values are the TRUE tile indices, so
// the refine contract is unchanged.
// Packed value: (float_bits(sq512 - 2dot) & ~255) | tile_id(8b).
__global__ __launch_bounds__(256, 4) void knn_mfma_kernel(
    const _Float16* __restrict__ xt16, const float* __restrict__ sq,
    int* __restrict__ pidx) {
  int t = threadIdx.x;
  int wave = t >> 6;
  int lane = t & 63;
  int col = lane & 15;
  int quad = lane >> 4;
  int blk = blockIdx.x;
  int split = blk & 1;
  int qt = (blk >> 1) & 127;
  int b = blk >> 8;
  int q0 = qt * 64 + wave * 16;
  size_t bbase = (size_t)b * N_;

  // A fragments: A[m=col][k=quad*8+j] -> query row q0+col
  const _Float16* arow = xt16 + (bbase + q0 + col) * 64;
  half8 A0 = *(const half8*)(arow + quad * 8);
  half8 A1 = *(const half8*)(arow + 32 + quad * 8);

  int dl[4][LCELL];
#pragma unroll
  for (int r = 0; r < 4; ++r)
#pragma unroll
    for (int j = 0; j < LCELL; ++j) dl[r][j] = 0x7fffffff;

#define PAIR_INSERT(accX, accY, sA, sB, CTB)                                 \
  {                                                                          \
    const int ctb_ = (CTB);                                                  \
    _Pragma("unroll") for (int r = 0; r < 4; ++r) {                          \
      float kA = fmaf((accX)[r], -2.0f, (sA));                               \
      float kB = fmaf((accY)[r], -2.0f, (sB));                               \
      int va = (__float_as_int(kA) & ~255) | ctb_;                           \
      int vb = (__float_as_int(kB) & ~255) | (ctb_ + 1);                     \
      int lo = min(va, vb), hi = max(va, vb);                                \
      int o0 = min(dl[r][0], lo);                                            \
      int o1 = min(min(dl[r][1], max(dl[r][0], lo)), hi);                    \
      int o2 = min(min(dl[r][2], max(dl[r][1], lo)), max(dl[r][0], hi));     \
      int o3 = min(min(dl[r][3], max(dl[r][2], lo)), max(dl[r][1], hi));     \
      int o4 = min(min(dl[r][4], max(dl[r][3], lo)), max(dl[r][2], hi));     \
      int o5 = min(min(dl[r][5], max(dl[r][4], lo)), max(dl[r][3], hi));     \
      int o6 = min(min(dl[r][6], max(dl[r][5], lo)), max(dl[r][4], hi));     \
      int o7 = min(min(dl[r][7], max(dl[r][6], lo)), max(dl[r][5], hi));     \
      dl[r][0] = o0; dl[r][1] = o1; dl[r][2] = o2; dl[r][3] = o3;            \
      dl[r][4] = o4; dl[r][5] = o5; dl[r][6] = o6; dl[r][7] = o7;            \
    }                                                                        \
  }

  int c0 = split * (N_ / NSPLIT);
  const _Float16* base = xt16 + (bbase + c0 + col) * 64 + quad * 8;
  const float* sbase = sq + bbase + c0 + col;

  // de-phase: block-unique start pair, circular scan over 128 pairs
  int start = (qt * 37) & 127;
  int p0 = start;
  int p1 = (start + 1) & 127;

  // prologue: load pair p0 -> set0 (B,C), pair p1 -> set1 (D,E)
  const _Float16* t0p = base + (size_t)p0 * 2048;
  const _Float16* t1p = base + (size_t)p1 * 2048;
  half8 B0 = *(const half8*)t0p;
  half8 B1 = *(const half8*)(t0p + 32);
  half8 C0 = *(const half8*)(t0p + 1024);
  half8 C1 = *(const half8*)(t0p + 1024 + 32);
  half8 D0 = *(const half8*)t1p;
  half8 D1 = *(const half8*)(t1p + 32);
  half8 E0 = *(const half8*)(t1p + 1024);
  half8 E1 = *(const half8*)(t1p + 1024 + 32);
  float s0 = sbase[p0 * 32], s1 = sbase[p0 * 32 + 16];
  float t0 = sbase[p1 * 32], t1 = sbase[p1 * 32 + 16];

  const f32x4 z = {0.f, 0.f, 0.f, 0.f};
  // MFMA pair p0
  f32x4 pA = __builtin_amdgcn_mfma_f32_16x16x32_f16(A0, B0, z, 0, 0, 0);
  pA = __builtin_amdgcn_mfma_f32_16x16x32_f16(A1, B1, pA, 0, 0, 0);
  f32x4 pB = __builtin_amdgcn_mfma_f32_16x16x32_f16(A0, C0, z, 0, 0, 0);
  pB = __builtin_amdgcn_mfma_f32_16x16x32_f16(A1, C1, pB, 0, 0, 0);
  float ps0 = s0, ps1 = s1;
  int pct = 2 * p0;
  int pn = (p1 + 1) & 127;  // next pair to load

  for (int it = 0; it < 63; ++it) {
    // half A: load pair pn -> set0; MFMA set1 (pair p1); insert prev
    {
      const _Float16* np = base + (size_t)pn * 2048;
      B0 = *(const half8*)np;
      B1 = *(const half8*)(np + 32);
      C0 = *(const half8*)(np + 1024);
      C1 = *(const half8*)(np + 1024 + 32);
      s0 = sbase[pn * 32]; s1 = sbase[pn * 32 + 16];
    }
    p0 = pn; pn = (pn + 1) & 127;
    f32x4 cA = __builtin_amdgcn_mfma_f32_16x16x32_f16(A0, D0, z, 0, 0, 0);
    cA = __builtin_amdgcn_mfma_f32_16x16x32_f16(A1, D1, cA, 0, 0, 0);
    f32x4 cB = __builtin_amdgcn_mfma_f32_16x16x32_f16(A0, E0, z, 0, 0, 0);
    cB = __builtin_amdgcn_mfma_f32_16x16x32_f16(A1, E1, cB, 0, 0, 0);
    PAIR_INSERT(pA, pB, ps0, ps1, pct);
    pA = cA; pB = cB; ps0 = t0; ps1 = t1; pct = 2 * p1;

    // half B: load pair pn -> set1; MFMA set0 (pair p0); insert prev
    {
      const _Float16* np = base + (size_t)pn * 2048;
      D0 = *(const half8*)np;
      D1 = *(const half8*)(np + 32);
      E0 = *(const half8*)(np + 1024);
      E1 = *(const half8*)(np + 1024 + 32);
      t0 = sbase[pn * 32]; t1 = sbase[pn * 32 + 16];
    }
    p1 = pn; pn = (pn + 1) & 127;
    f32x4 dA = __builtin_amdgcn_mfma_f32_16x16x32_f16(A0, B0, z, 0, 0, 0);
    dA = __builtin_amdgcn_mfma_f32_16x16x32_f16(A1, B1, dA, 0, 0, 0);
    f32x4 dB = __builtin_amdgcn_mfma_f32_16x16x32_f16(A0, C0, z, 0, 0, 0);
    dB = __builtin_amdgcn_mfma_f32_16x16x32_f16(A1, C1, dB, 0, 0, 0);
    PAIR_INSERT(pA, pB, ps0, ps1, pct);
    pA = dA; pB = dB; ps0 = s0; ps1 = s1; pct = 2 * p0;
  }
  // epilogue: insert pair p0 (in pA/pB), then MFMA+insert pair p1 (set1)
  {
    f32x4 cA = __builtin_amdgcn_mfma_f32_16x16x32_f16(A0, D0, z, 0, 0, 0);
    cA = __builtin_amdgcn_mfma_f32_16x16x32_f16(A1, D1, cA, 0, 0, 0);
    f32x4 cB = __builtin_amdgcn_mfma_f32_16x16x32_f16(A0, E0, z, 0, 0, 0);
    cB = __builtin_amdgcn_mfma_f32_16x16x32_f16(A1, E1, cB, 0, 0, 0);
    PAIR_INSERT(pA, pB, ps0, ps1, pct);
    PAIR_INSERT(cA, cB, t0, t1, 2 * p1);
  }
#undef PAIR_INSERT

#pragma unroll
  for (int r = 0; r < 4; ++r) {
    int q = q0 + quad * 4 + r;
    int* o = pidx + (bbase + q) * NCAND + split * (16 * LCELL) + col * LCELL;
#pragma unroll
    for (int j = 0; j < LCELL; ++j) o[j] = dl[r][j];  // raw packed value
  }
}

// ---- Kernel 3: refinement v7 — one WAVE per point, key-reuse.
// Stage 1: lane loads its 4 raw packed scan values (int4); reconstructs
// (approx key, global index) from (value, slot): col=(slot>>3)&15,
// split=slot>>7, ci=((v&255)<<4)+col+split*4096. Packs unique doubles
// ((double)key with 13-bit index in zero mantissa bits), sort-4.
// Stage 2: 32 approx pop-min steps (6-shfl f64 butterfly, no memory);
// popped candidate s -> lane s. Margin: key error <= ~0.1 (f16 MFMA +
// 8-bit mask) << rank-20..32 distance span -> true top-20 in approx-top-32.
// Stage 3: lanes 0..31 IN PARALLEL compute their candidate's full fp64
// dot vs LDS-broadcast query row (64 f64 FMA, 4 accums); exact key =
// sqd - 2*dot + 1024, index in mantissa (math identical to passing rounds).
// Stage 4: 20 pop-min over exact keys emit indices (fp64 rank + idx tie).
__global__ __launch_bounds__(256) void refine_kernel(
    const float* __restrict__ xt, const double* __restrict__ sqd,
    const int* __restrict__ pidx, int* __restrict__ idxf) {
  __shared__ float qs[4][64];
  int tid = threadIdx.x;
  int wave = tid >> 6, lane = tid & 63;
  int p = blockIdx.x * 4 + wave;  // global point id
  int b = p >> 13;
  size_t bbase = (size_t)b * N_;
  int plocal = p & (N_ - 1);

  // stage query row into LDS (lanes 0..15 write 16B each)
  if (lane < 16) {
    ((f32x4*)qs[wave])[lane] = ((const f32x4*)(xt + (size_t)p * 64))[lane];
  }
  // stage 1: 4 packed values per lane -> unique double keys
  const int* pi = pidx + (size_t)p * NCAND + lane * 4;
  int4 cc = *(const int4*)pi;
  int vs[4] = {cc.x, cc.y, cc.z, cc.w};
  double dl[4];
#pragma unroll
  for (int j = 0; j < 4; ++j) {
    int slot = lane * 4 + j;
    int col = (slot >> 3) & 15;
    int split = slot >> 7;
    int dlv = vs[j];
    int ci = ((dlv & 255) << 4) + col + split * (N_ / NSPLIT);
    float key = __int_as_float(dlv & ~255);  // positive
    long long bits =
        (__double_as_longlong((double)key) & ~0x1FFFLL) | (long long)ci;
    double v = __longlong_as_double(bits);
    if (ci == plocal) v = 1e300;  // self-exclusion
    dl[j] = v;
  }
  {  // sort 4 ascending
    double lo, hi;
    lo = fmin(dl[0], dl[1]); hi = fmax(dl[0], dl[1]); dl[0] = lo; dl[1] = hi;
    lo = fmin(dl[2], dl[3]); hi = fmax(dl[2], dl[3]); dl[2] = lo; dl[3] = hi;
    lo = fmin(dl[0], dl[2]); hi = fmax(dl[0], dl[2]); dl[0] = lo; dl[2] = hi;
    lo = fmin(dl[1], dl[3]); hi = fmax(dl[1], dl[3]); dl[1] = lo; dl[3] = hi;
    lo = fmin(dl[1], dl[2]); hi = fmax(dl[1], dl[2]); dl[1] = lo; dl[2] = hi;
  }
  double vh = dl[0], h1 = dl[1], h2 = dl[2], h3 = dl[3];

  // stage 2: 32 approx pops; popped candidate s -> lane s
  int myci = 0;
#pragma unroll
  for (int s = 0; s < 32; ++s) {
    double m = vh;
    m = fmin(m, __shfl_xor(m, 1, 64));
    m = fmin(m, __shfl_xor(m, 2, 64));
    m = fmin(m, __shfl_xor(m, 4, 64));
    m = fmin(m, __shfl_xor(m, 8, 64));
    m = fmin(m, __shfl_xor(m, 16, 64));
    m = fmin(m, __shfl_xor(m, 32, 64));
    if (lane == s) myci = (int)(__double_as_longlong(m) & 0x1FFFLL);
    bool adv = (vh == m);  // unique keys: exactly one owner advances
    vh = adv ? h1 : vh;
    h1 = adv ? h2 : h1;
    h2 = adv ? h3 : h2;
    h3 = adv ? 1e300 : h3;
  }
  // stage 3: parallel exact fp64 keys on lanes 0..31
  double kv = 1e300;
  if (lane < 32) {
    const f32x4* cr = (const f32x4*)(xt + (bbase + myci) * 64);
    const f32x4* qr = (const f32x4*)qs[wave];
    double a0 = 0.0, a1 = 0.0, a2 = 0.0, a3 = 0.0;
#pragma unroll
    for (int t2 = 0; t2 < 16; ++t2) {
      f32x4 cv = cr[t2];
      f32x4 qv = qr[t2];  // ds_read_b128 broadcast
      a0 = fma((double)cv.x, (double)qv.x, a0);
      a1 = fma((double)cv.y, (double)qv.y, a1);
      a2 = fma((double)cv.z, (double)qv.z, a2);
      a3 = fma((double)cv.w, (double)qv.w, a3);
    }
    double dot = (a0 + a1) + (a2 + a3);
    double kd = fma(dot, -2.0, sqd[bbase + myci]) + 1024.0;
    kv = __longlong_as_double(
        (__double_as_longlong(kd) & ~0x1FFFLL) | (long long)myci);
  }
  // stage 4: 20 smallest exact keys (ascending, index tie-break)
  int* o = idxf + (size_t)p * K_;
#pragma unroll
  for (int s = 0; s < K_; ++s) {
    double m = kv;
    m = fmin(m, __shfl_xor(m, 1, 64));
    m = fmin(m, __shfl_xor(m, 2, 64));
    m = fmin(m, __shfl_xor(m, 4, 64));
    m = fmin(m, __shfl_xor(m, 8, 64));
    m = fmin(m, __shfl_xor(m, 16, 64));
    m = fmin(m, __shfl_xor(m, 32, 64));
    if (lane == 0) o[s] = (int)(__double_as_longlong(m) & 0x1FFFLL);
    kv = (kv == m) ? 1e300 : kv;
  }
}

// ---- Kernel 4: one WAVE per point. Lane (u=lane&15, jb=lane>>4); 5 rounds:
// lane loads 16B chunk u of neighbor jb+4r -> each 16-lane group reads a full
// 256B y1 row per instruction (no partial lines). max/min/sum/sumsq of the
// gathered y1 reduced across jb via shfl_xor(16,32); y2 applied once:
// max(h)=max(g)+y2, sum(h)=sum(g)+K*y2, sumsq(h)=sum(g^2)+2*y2*sum(g)+K*y2^2.
// 4 points per wave sequentially; BN sums -> LDS atomics -> 128 global/block.
__global__ __launch_bounds__(256) void stats_kernel(
    const float* __restrict__ y1, const float* __restrict__ y2,
    const int* __restrict__ idxf, float* __restrict__ maxh,
    float* __restrict__ minh, float* __restrict__ gsum,
    float* __restrict__ gsq) {
  __shared__ float lsum[64], lsq[64];
  int tid = threadIdx.x;
  if (tid < 64) { lsum[tid] = 0.f; lsq[tid] = 0.f; }
  __syncthreads();
  int wv = tid >> 6, lane = tid & 63;
  int u = lane & 15, jb = lane >> 4;
  int p0 = blockIdx.x * 16 + wv * 4;  // 16 contiguous points per block
  size_t nb = (size_t)((p0 >> 13) * N_);
  f32x4 css = {0.f, 0.f, 0.f, 0.f}, cqq = {0.f, 0.f, 0.f, 0.f};
#pragma unroll
  for (int it = 0; it < 4; ++it) {
    int p = p0 + it;
    int idxval = (lane < K_) ? idxf[(size_t)p * K_ + lane] : 0;
    int n0 = __shfl(idxval, jb, 64);
    int n1 = __shfl(idxval, jb + 4, 64);
    int n2 = __shfl(idxval, jb + 8, 64);
    int n3 = __shfl(idxval, jb + 12, 64);
    int n4 = __shfl(idxval, jb + 16, 64);
    f32x4 g0 = ((const f32x4*)(y1 + (nb + n0) * 64))[u];
    f32x4 g1 = ((const f32x4*)(y1 + (nb + n1) * 64))[u];
    f32x4 g2 = ((const f32x4*)(y1 + (nb + n2) * 64))[u];
    f32x4 g3 = ((const f32x4*)(y1 + (nb + n3) * 64))[u];
    f32x4 g4 = ((const f32x4*)(y1 + (nb + n4) * 64))[u];
    f32x4 mx = g0, mn = g0, sm = g0, s2 = g0 * g0;
    mx = max4(mx, g1); mn = min4(mn, g1); sm += g1; s2 += g1 * g1;
    mx = max4(mx, g2); mn = min4(mn, g2); sm += g2; s2 += g2 * g2;
    mx = max4(mx, g3); mn = min4(mn, g3); sm += g3; s2 += g3 * g3;
    mx = max4(mx, g4); mn = min4(mn, g4); sm += g4; s2 += g4 * g4;
#pragma unroll
    for (int c = 0; c < 4; ++c) {
      mx[c] = fmaxf(mx[c], __shfl_xor(mx[c], 16, 64));
      mx[c] = fmaxf(mx[c], __shfl_xor(mx[c], 32, 64));
      mn[c] = fminf(mn[c], __shfl_xor(mn[c], 16, 64));
      mn[c] = fminf(mn[c], __shfl_xor(mn[c], 32, 64));
      sm[c] += __shfl_xor(sm[c], 16, 64);
      sm[c] += __shfl_xor(sm[c], 32, 64);
      s2[c] += __shfl_xor(s2[c], 16, 64);
      s2[c] += __shfl_xor(s2[c], 32, 64);
    }
    if (jb == 0) {  // lanes 0..15: full 256B contiguous stores
      f32x4 y2c = ((const f32x4*)(y2 + (size_t)p * 64))[u];
      ((f32x4*)(maxh + (size_t)p * 64))[u] = mx + y2c;
      ((f32x4*)(minh + (size_t)p * 64))[u] = mn + y2c;
      css += sm + 20.0f * y2c;
      cqq += s2 + 2.0f * y2c * sm + 20.0f * y2c * y2c;
    }
  }
  if (jb == 0) {
#pragma unroll
    for (int c = 0; c < 4; ++c) {
      atomicAdd(&lsum[u * 4 + c], css[c]);
      atomicAdd(&lsq[u * 4 + c], cqq[c]);
    }
  }
  __syncthreads();
  if (tid < 64) {
    atomicAdd(&gsum[tid], lsum[tid]);
    atomicAdd(&gsq[tid], lsq[tid]);
  }
}

// ---- Kernel 5: affine + relu + max-over-k selection, transposed store ----
__global__ __launch_bounds__(256) void final_kernel(
    const float* __restrict__ maxh, const float* __restrict__ minh,
    const float* __restrict__ gsum, const float* __restrict__ gsq,
    const float* __restrict__ gamma, const float* __restrict__ beta,
    float* __restrict__ out) {
  __shared__ float sc[64], cc_[64];
  __shared__ float tile[64 * 65];
  int b = blockIdx.x >> 7;
  int n0 = (blockIdx.x & 127) * 64;
  int t = threadIdx.x;
  if (t < 64) {
    float mean = gsum[t] * (1.0f / CNT_TOTAL);
    float var = gsq[t] * (1.0f / CNT_TOTAL) - mean * mean;
    float s = gamma[t] * rsqrtf(var + BN_EPSF);
    sc[t] = s;
    cc_[t] = beta[t] - mean * s;
  }
  __syncthreads();
#pragma unroll
  for (int i = 0; i < 16; ++i) {
    int lin = i * 256 + t;
    int o = lin & 63, nl = lin >> 6;
    size_t off = ((size_t)(b * N_) + n0 + nl) * 64 + o;
    float s = sc[o];
    float v = (s >= 0.f) ? maxh[off] : minh[off];
    float val = fmaxf(fmaf(v, s, cc_[o]), 0.f);
    tile[o * 65 + nl] = val;
  }
  __syncthreads();
#pragma unroll
  for (int i = 0; i < 16; ++i) {
    int lin = i * 256 + t;
    int nl = lin & 63, o = lin >> 6;
    out[((size_t)(b * 64) + o) * N_ + n0 + nl] = tile[o * 65 + nl];
  }
}

extern "C" void kernel_launch(void* const* d_in, const int* in_sizes, int n_in,
                              void* d_out, int out_size, void* d_ws,
                              size_t ws_size, hipStream_t stream) {
  const float* x = (const float*)d_in[0];
  const float* W = (const float*)d_in[1];
  const float* gamma = (const float*)d_in[2];
  const float* beta = (const float*)d_in[3];
  float* out = (float*)d_out;

  char* ws = (char*)d_ws;
  size_t off = 0;
  auto alloc = [&](size_t bytes) {
    char* p = ws + off;
    off += (bytes + 255) & ~(size_t)255;
    return p;
  };
  float* xt = (float*)alloc((size_t)B_ * N_ * 64 * 4);
  _Float16* xt16 = (_Float16*)alloc((size_t)B_ * N_ * 64 * 2);
  float* y1 = (float*)alloc((size_t)B_ * N_ * 64 * 4);
  float* y2 = (float*)alloc((size_t)B_ * N_ * 64 * 4);
  float* sq = (float*)alloc((size_t)B_ * N_ * 4);
  double* sqd = (double*)alloc((size_t)B_ * N_ * 8);
  int* pidx = (int*)alloc((size_t)B_ * N_ * NCAND * 4);  // 33.5 MB
  float* maxh = (float*)alloc((size_t)B_ * N_ * 64 * 4);
  int* idxf = (int*)alloc((size_t)B_ * N_ * K_ * 4);
  float* gsum = (float*)alloc(256);
  float* gsq = (float*)alloc(256);
  // minh aliases pidx (pidx fully consumed by refine before stats runs)
  float* minh = (float*)pidx;

  hipMemsetAsync(gsum, 0, 256, stream);
  hipMemsetAsync(gsq, 0, 256, stream);

  prep_kernel<<<B_ * (N_ / 64), 256, 0, stream>>>(x, W, xt, xt16, sq, sqd,
                                                  y1, y2);
  knn_mfma_kernel<<<B_ * (N_ / 64) * NSPLIT, 256, 0, stream>>>(xt16, sq, pidx);
  refine_kernel<<<(B_ * N_) / 4, 256, 0, stream>>>(xt, sqd, pidx, idxf);
  stats_kernel<<<(B_ * N_) / 16, 256, 0, stream>>>(y1, y2, idxf, maxh, minh,
                                                   gsum, gsq);
  final_kernel<<<B_ * (N_ / 64), 256, 0, stream>>>(maxh, minh, gsum, gsq,
                                                   gamma, beta, out);
}

// Round 4
// 511.545 us; speedup vs baseline: 1.3239x; 1.1987x over previous
//
#include <hip/hip_runtime.h>

typedef _Float16 half8 __attribute__((ext_vector_type(8)));
typedef float f32x4 __attribute__((ext_vector_type(4)));

#define B_ 4
#define C_ 64
#define N_ 8192
#define K_ 20
#define LCELL 8                   // per-(split,class) sorted list depth
#define NSPLIT 2
#define NCAND (16 * LCELL * NSPLIT)  // 256 candidates per query into refine
#define CNT_TOTAL (B_ * N_ * K_)  // 655360
#define BN_EPSF 1e-5f

__device__ __forceinline__ f32x4 max4(f32x4 a, f32x4 b) {
  f32x4 r;
  r.x = fmaxf(a.x, b.x); r.y = fmaxf(a.y, b.y);
  r.z = fmaxf(a.z, b.z); r.w = fmaxf(a.w, b.w);
  return r;
}
__device__ __forceinline__ f32x4 min4(f32x4 a, f32x4 b) {
  f32x4 r;
  r.x = fminf(a.x, b.x); r.y = fminf(a.y, b.y);
  r.z = fminf(a.z, b.z); r.w = fminf(a.w, b.w);
  return r;
}

// ---- Kernel 1: transpose x -> xt (f32 + f16), per-point sq (f32+f64),
// y1 = xt*W1^T, y2 = xt*W2^T - y1. W row o==lane held in 128 VGPRs.
// sq is stored PRE-BIASED by +512 (knn key bias folded in; refine uses sqd).
__global__ __launch_bounds__(256) void prep_kernel(
    const float* __restrict__ x, const float* __restrict__ W,
    float* __restrict__ xt, _Float16* __restrict__ xt16,
    float* __restrict__ sq, double* __restrict__ sqd,
    float* __restrict__ y1, float* __restrict__ y2) {
  __shared__ float xs[64 * 68];  // [n][c], stride 68 (16B-aligned rows)
  int b = blockIdx.x >> 7;
  int n0 = (blockIdx.x & 127) * 64;
  int t = threadIdx.x;
  int lane = t & 63;
  int wv = t >> 6;
#pragma unroll
  for (int i = 0; i < 16; ++i) {
    int lin = i * 256 + t;
    int c = lin >> 6, j = lin & 63;
    xs[j * 68 + c] = x[((b * 64 + c) * N_) + n0 + j];
  }
  // W row o = lane into registers (L1/L2-hot, 32 KB total)
  float4 w1[16], w2[16];
  const float4* wr = (const float4*)(W + lane * 128);
#pragma unroll
  for (int u = 0; u < 16; ++u) {
    w1[u] = wr[u];
    w2[u] = wr[16 + u];
  }
  __syncthreads();
#pragma unroll 2
  for (int i = 0; i < 16; ++i) {
    int nl = i * 4 + wv;
    const float4* xr = (const float4*)&xs[nl * 68];
    float d1 = 0.f, d2 = 0.f;
#pragma unroll
    for (int u = 0; u < 16; ++u) {
      float4 xv = xr[u];
      d1 = fmaf(xv.x, w1[u].x, d1); d1 = fmaf(xv.y, w1[u].y, d1);
      d1 = fmaf(xv.z, w1[u].z, d1); d1 = fmaf(xv.w, w1[u].w, d1);
      d2 = fmaf(xv.x, w2[u].x, d2); d2 = fmaf(xv.y, w2[u].y, d2);
      d2 = fmaf(xv.z, w2[u].z, d2); d2 = fmaf(xv.w, w2[u].w, d2);
    }
    int n = n0 + nl;
    y1[((b * N_) + n) * 64 + lane] = d1;
    y2[((b * N_) + n) * 64 + lane] = d2 - d1;
  }
#pragma unroll
  for (int i = 0; i < 16; ++i) {
    int lin = i * 256 + t;
    int c = lin & 63, nl = lin >> 6;
    float v = xs[nl * 68 + c];
    size_t o = ((size_t)(b * N_) + n0 + nl) * 64 + c;
    xt[o] = v;
    xt16[o] = (_Float16)v;
  }
  if (t < 64) {
    float s = 0.f;
    double sd = 0.0;
#pragma unroll
    for (int c = 0; c < 64; ++c) {
      float v = xs[t * 68 + c];
      s = fmaf(v, v, s);
      sd = fma((double)v, (double)v, sd);
    }
    sq[b * N_ + n0 + t] = s + 512.0f;  // pre-biased for knn key
    sqd[b * N_ + n0 + t] = sd;
  }
}

// ---- Kernel 2: MFMA distance scan, LDS-staged v4.
// R0-R3 evidence: wall time invariant to VALU count (R1), wave count (R2),
// and scan phase (R3 null) -> per-wave exposed VMEM latency at 4 waves/SIMD,
// with all 4 waves redundantly streaming the SAME 512KB panel (4x VMEM).
// Fix: cooperative reg->LDS staging of 64-cand chunks (each wave stages its
// 16-cand tile: 2 coalesced dwordx4 + 1 sq float per lane), double-buffered,
// one __syncthreads per chunk. Consume path is pure LDS (ds_read_b128 +
// MFMA + pair-merge insert): short-latency, high-throughput. VMEM instrs
// drop ~7x, global bytes 4x. Row stride 144B -> uniform bank spread
// ((row+e)%8 groups) for both ds_write and ds_read.
// Packed value: (float_bits(sq512 - 2dot) & ~255) | tile_id(8b). Refine
// contract unchanged.
__global__ __launch_bounds__(256, 4) void knn_mfma_kernel(
    const _Float16* __restrict__ xt16, const float* __restrict__ sq,
    int* __restrict__ pidx) {
  __shared__ alignas(16) char bufB[2][9216];  // 4 tiles * 16 rows * 144B
  __shared__ float bufS[2][64];
  int t = threadIdx.x;
  int wave = t >> 6;
  int lane = t & 63;
  int col = lane & 15;
  int quad = lane >> 4;
  int blk = blockIdx.x;
  int split = blk & 1;
  int qt = (blk >> 1) & 127;
  int b = blk >> 8;
  int q0 = qt * 64 + wave * 16;
  size_t bbase = (size_t)b * N_;

  // A fragments: A[m=col][k=quad*8+j] -> query row q0+col
  const _Float16* arow = xt16 + (bbase + q0 + col) * 64;
  half8 A0 = *(const half8*)(arow + quad * 8);
  half8 A1 = *(const half8*)(arow + 32 + quad * 8);

  int dl[4][LCELL];
#pragma unroll
  for (int r = 0; r < 4; ++r)
#pragma unroll
    for (int j = 0; j < LCELL; ++j) dl[r][j] = 0x7fffffff;

#define PAIR_INSERT(accX, accY, sA, sB, CTB)                                 \
  {                                                                          \
    const int ctb_ = (CTB);                                                  \
    _Pragma("unroll") for (int r = 0; r < 4; ++r) {                          \
      float kA = fmaf((accX)[r], -2.0f, (sA));                               \
      float kB = fmaf((accY)[r], -2.0f, (sB));                               \
      int va = (__float_as_int(kA) & ~255) | ctb_;                           \
      int vb = (__float_as_int(kB) & ~255) | (ctb_ + 1);                     \
      int lo = min(va, vb), hi = max(va, vb);                                \
      int o0 = min(dl[r][0], lo);                                            \
      int o1 = min(min(dl[r][1], max(dl[r][0], lo)), hi);                    \
      int o2 = min(min(dl[r][2], max(dl[r][1], lo)), max(dl[r][0], hi));     \
      int o3 = min(min(dl[r][3], max(dl[r][2], lo)), max(dl[r][1], hi));     \
      int o4 = min(min(dl[r][4], max(dl[r][3], lo)), max(dl[r][2], hi));     \
      int o5 = min(min(dl[r][5], max(dl[r][4], lo)), max(dl[r][3], hi));     \
      int o6 = min(min(dl[r][6], max(dl[r][5], lo)), max(dl[r][4], hi));     \
      int o7 = min(min(dl[r][7], max(dl[r][6], lo)), max(dl[r][5], hi));     \
      dl[r][0] = o0; dl[r][1] = o1; dl[r][2] = o2; dl[r][3] = o3;            \
      dl[r][4] = o4; dl[r][5] = o5; dl[r][6] = o6; dl[r][7] = o7;            \
    }                                                                        \
  }

  int c0 = split * (N_ / NSPLIT);
  const _Float16* gpanel = xt16 + (bbase + c0) * 64;
  const float* spanel = sq + bbase + c0;

  int r0 = lane >> 3, e0 = lane & 7;  // lane's staged (row, 16B-chunk)

  int4 rA0, rA1, rB0, rB1;
  float sA = 0.f, sB = 0.f;

  // wave stages tile `wave` of each chunk; lane loads rows r0 and r0+8,
  // 16B chunk e0 -> contiguous 1KB per instruction (addr = base + lane*16B)
#define LOADR(Ra, Rb, Sv, CH)                                              \
  {                                                                        \
    const _Float16* gt = gpanel + ((size_t)(CH)*64 + wave * 16) * 64;      \
    Ra = *(const int4*)(gt + lane * 8);                                    \
    Rb = *(const int4*)(gt + 512 + lane * 8);                              \
    Sv = spanel[(CH)*64 + wave * 16 + col];                                \
  }
#define WRITEB(BUF, Ra, Rb, Sv)                                            \
  {                                                                        \
    char* lt = &bufB[BUF][wave * 2304];                                    \
    *(int4*)(lt + r0 * 144 + e0 * 16) = Ra;                                \
    *(int4*)(lt + (r0 + 8) * 144 + e0 * 16) = Rb;                          \
    if (lane < 16) bufS[BUF][wave * 16 + lane] = Sv;                       \
  }
#define CONSUME(BUF, CH)                                                   \
  {                                                                        \
    const char* lb = bufB[BUF];                                            \
    const float* sb = bufS[BUF];                                           \
    const f32x4 z = {0.f, 0.f, 0.f, 0.f};                                  \
    half8 F0 = *(const half8*)(lb + 0 * 2304 + col * 144 + quad * 16);     \
    half8 F1 = *(const half8*)(lb + 0 * 2304 + col * 144 + (4 + quad) * 16); \
    half8 G0 = *(const half8*)(lb + 1 * 2304 + col * 144 + quad * 16);     \
    half8 G1 = *(const half8*)(lb + 1 * 2304 + col * 144 + (4 + quad) * 16); \
    f32x4 a0 = __builtin_amdgcn_mfma_f32_16x16x32_f16(A0, F0, z, 0, 0, 0); \
    a0 = __builtin_amdgcn_mfma_f32_16x16x32_f16(A1, F1, a0, 0, 0, 0);      \
    f32x4 a1 = __builtin_amdgcn_mfma_f32_16x16x32_f16(A0, G0, z, 0, 0, 0); \
    a1 = __builtin_amdgcn_mfma_f32_16x16x32_f16(A1, G1, a1, 0, 0, 0);      \
    half8 H0 = *(const half8*)(lb + 2 * 2304 + col * 144 + quad * 16);     \
    half8 H1 = *(const half8*)(lb + 2 * 2304 + col * 144 + (4 + quad) * 16); \
    half8 I0 = *(const half8*)(lb + 3 * 2304 + col * 144 + quad * 16);     \
    half8 I1 = *(const half8*)(lb + 3 * 2304 + col * 144 + (4 + quad) * 16); \
    f32x4 a2 = __builtin_amdgcn_mfma_f32_16x16x32_f16(A0, H0, z, 0, 0, 0); \
    a2 = __builtin_amdgcn_mfma_f32_16x16x32_f16(A1, H1, a2, 0, 0, 0);      \
    f32x4 a3 = __builtin_amdgcn_mfma_f32_16x16x32_f16(A0, I0, z, 0, 0, 0); \
    a3 = __builtin_amdgcn_mfma_f32_16x16x32_f16(A1, I1, a3, 0, 0, 0);      \
    float s0 = sb[col], s1 = sb[16 + col];                                 \
    float s2 = sb[32 + col], s3 = sb[48 + col];                            \
    PAIR_INSERT(a0, a1, s0, s1, (CH)*4);                                   \
    PAIR_INSERT(a2, a3, s2, s3, (CH)*4 + 2);                               \
  }

  // prologue: chunk0 -> buf0, chunk1 -> regs
  LOADR(rA0, rA1, sA, 0);
  LOADR(rB0, rB1, sB, 1);
  WRITEB(0, rA0, rA1, sA);
  __syncthreads();

  for (int ch = 0; ch < 64; ch += 2) {
    // even half: buf0 = chunk ch (ready); rB = chunk ch+1
    if (ch + 2 < 64) LOADR(rA0, rA1, sA, ch + 2);
    WRITEB(1, rB0, rB1, sB);  // buf1 <- chunk ch+1 (buf1 fully consumed @ ch-1)
    CONSUME(0, ch);
    __syncthreads();
    // odd half: buf1 = chunk ch+1 (ready); rA = chunk ch+2
    if (ch + 3 < 64) LOADR(rB0, rB1, sB, ch + 3);
    if (ch + 2 < 64) WRITEB(0, rA0, rA1, sA);
    CONSUME(1, ch + 1);
    __syncthreads();
  }
#undef PAIR_INSERT
#undef LOADR
#undef WRITEB
#undef CONSUME

#pragma unroll
  for (int r = 0; r < 4; ++r) {
    int q = q0 + quad * 4 + r;
    int* o = pidx + (bbase + q) * NCAND + split * (16 * LCELL) + col * LCELL;
#pragma unroll
    for (int j = 0; j < LCELL; ++j) o[j] = dl[r][j];  // raw packed value
  }
}

// ---- Kernel 3: refinement v7 — one WAVE per point, key-reuse.
// Stage 1: lane loads its 4 raw packed scan values (int4); reconstructs
// (approx key, global index) from (value, slot): col=(slot>>3)&15,
// split=slot>>7, ci=((v&255)<<4)+col+split*4096. Packs unique doubles
// ((double)key with 13-bit index in zero mantissa bits), sort-4.
// Stage 2: 32 approx pop-min steps (6-shfl f64 butterfly, no memory);
// popped candidate s -> lane s. Margin: key error <= ~0.1 (f16 MFMA +
// 8-bit mask) << rank-20..32 distance span -> true top-20 in approx-top-32.
// Stage 3: lanes 0..31 IN PARALLEL compute their candidate's full fp64
// dot vs LDS-broadcast query row (64 f64 FMA, 4 accums); exact key =
// sqd - 2*dot + 1024, index in mantissa (math identical to passing rounds).
// Stage 4: 20 pop-min over exact keys emit indices (fp64 rank + idx tie).
__global__ __launch_bounds__(256) void refine_kernel(
    const float* __restrict__ xt, const double* __restrict__ sqd,
    const int* __restrict__ pidx, int* __restrict__ idxf) {
  __shared__ float qs[4][64];
  int tid = threadIdx.x;
  int wave = tid >> 6, lane = tid & 63;
  int p = blockIdx.x * 4 + wave;  // global point id
  int b = p >> 13;
  size_t bbase = (size_t)b * N_;
  int plocal = p & (N_ - 1);

  // stage query row into LDS (lanes 0..15 write 16B each)
  if (lane < 16) {
    ((f32x4*)qs[wave])[lane] = ((const f32x4*)(xt + (size_t)p * 64))[lane];
  }
  // stage 1: 4 packed values per lane -> unique double keys
  const int* pi = pidx + (size_t)p * NCAND + lane * 4;
  int4 cc = *(const int4*)pi;
  int vs[4] = {cc.x, cc.y, cc.z, cc.w};
  double dl[4];
#pragma unroll
  for (int j = 0; j < 4; ++j) {
    int slot = lane * 4 + j;
    int col = (slot >> 3) & 15;
    int split = slot >> 7;
    int dlv = vs[j];
    int ci = ((dlv & 255) << 4) + col + split * (N_ / NSPLIT);
    float key = __int_as_float(dlv & ~255);  // positive
    long long bits =
        (__double_as_longlong((double)key) & ~0x1FFFLL) | (long long)ci;
    double v = __longlong_as_double(bits);
    if (ci == plocal) v = 1e300;  // self-exclusion
    dl[j] = v;
  }
  {  // sort 4 ascending
    double lo, hi;
    lo = fmin(dl[0], dl[1]); hi = fmax(dl[0], dl[1]); dl[0] = lo; dl[1] = hi;
    lo = fmin(dl[2], dl[3]); hi = fmax(dl[2], dl[3]); dl[2] = lo; dl[3] = hi;
    lo = fmin(dl[0], dl[2]); hi = fmax(dl[0], dl[2]); dl[0] = lo; dl[2] = hi;
    lo = fmin(dl[1], dl[3]); hi = fmax(dl[1], dl[3]); dl[1] = lo; dl[3] = hi;
    lo = fmin(dl[1], dl[2]); hi = fmax(dl[1], dl[2]); dl[1] = lo; dl[2] = hi;
  }
  double vh = dl[0], h1 = dl[1], h2 = dl[2], h3 = dl[3];

  // stage 2: 32 approx pops; popped candidate s -> lane s
  int myci = 0;
#pragma unroll
  for (int s = 0; s < 32; ++s) {
    double m = vh;
    m = fmin(m, __shfl_xor(m, 1, 64));
    m = fmin(m, __shfl_xor(m, 2, 64));
    m = fmin(m, __shfl_xor(m, 4, 64));
    m = fmin(m, __shfl_xor(m, 8, 64));
    m = fmin(m, __shfl_xor(m, 16, 64));
    m = fmin(m, __shfl_xor(m, 32, 64));
    if (lane == s) myci = (int)(__double_as_longlong(m) & 0x1FFFLL);
    bool adv = (vh == m);  // unique keys: exactly one owner advances
    vh = adv ? h1 : vh;
    h1 = adv ? h2 : h1;
    h2 = adv ? h3 : h2;
    h3 = adv ? 1e300 : h3;
  }
  // stage 3: parallel exact fp64 keys on lanes 0..31
  double kv = 1e300;
  if (lane < 32) {
    const f32x4* cr = (const f32x4*)(xt + (bbase + myci) * 64);
    const f32x4* qr = (const f32x4*)qs[wave];
    double a0 = 0.0, a1 = 0.0, a2 = 0.0, a3 = 0.0;
#pragma unroll
    for (int t2 = 0; t2 < 16; ++t2) {
      f32x4 cv = cr[t2];
      f32x4 qv = qr[t2];  // ds_read_b128 broadcast
      a0 = fma((double)cv.x, (double)qv.x, a0);
      a1 = fma((double)cv.y, (double)qv.y, a1);
      a2 = fma((double)cv.z, (double)qv.z, a2);
      a3 = fma((double)cv.w, (double)qv.w, a3);
    }
    double dot = (a0 + a1) + (a2 + a3);
    double kd = fma(dot, -2.0, sqd[bbase + myci]) + 1024.0;
    kv = __longlong_as_double(
        (__double_as_longlong(kd) & ~0x1FFFLL) | (long long)myci);
  }
  // stage 4: 20 smallest exact keys (ascending, index tie-break)
  int* o = idxf + (size_t)p * K_;
#pragma unroll
  for (int s = 0; s < K_; ++s) {
    double m = kv;
    m = fmin(m, __shfl_xor(m, 1, 64));
    m = fmin(m, __shfl_xor(m, 2, 64));
    m = fmin(m, __shfl_xor(m, 4, 64));
    m = fmin(m, __shfl_xor(m, 8, 64));
    m = fmin(m, __shfl_xor(m, 16, 64));
    m = fmin(m, __shfl_xor(m, 32, 64));
    if (lane == 0) o[s] = (int)(__double_as_longlong(m) & 0x1FFFLL);
    kv = (kv == m) ? 1e300 : kv;
  }
}

// ---- Kernel 4: one WAVE per point. Lane (u=lane&15, jb=lane>>4); 5 rounds:
// lane loads 16B chunk u of neighbor jb+4r -> each 16-lane group reads a full
// 256B y1 row per instruction (no partial lines). max/min/sum/sumsq of the
// gathered y1 reduced across jb via shfl_xor(16,32); y2 applied once:
// max(h)=max(g)+y2, sum(h)=sum(g)+K*y2, sumsq(h)=sum(g^2)+2*y2*sum(g)+K*y2^2.
// 4 points per wave sequentially; BN sums -> LDS atomics -> 128 global/block.
__global__ __launch_bounds__(256) void stats_kernel(
    const float* __restrict__ y1, const float* __restrict__ y2,
    const int* __restrict__ idxf, float* __restrict__ maxh,
    float* __restrict__ minh, float* __restrict__ gsum,
    float* __restrict__ gsq) {
  __shared__ float lsum[64], lsq[64];
  int tid = threadIdx.x;
  if (tid < 64) { lsum[tid] = 0.f; lsq[tid] = 0.f; }
  __syncthreads();
  int wv = tid >> 6, lane = tid & 63;
  int u = lane & 15, jb = lane >> 4;
  int p0 = blockIdx.x * 16 + wv * 4;  // 16 contiguous points per block
  size_t nb = (size_t)((p0 >> 13) * N_);
  f32x4 css = {0.f, 0.f, 0.f, 0.f}, cqq = {0.f, 0.f, 0.f, 0.f};
#pragma unroll
  for (int it = 0; it < 4; ++it) {
    int p = p0 + it;
    int idxval = (lane < K_) ? idxf[(size_t)p * K_ + lane] : 0;
    int n0 = __shfl(idxval, jb, 64);
    int n1 = __shfl(idxval, jb + 4, 64);
    int n2 = __shfl(idxval, jb + 8, 64);
    int n3 = __shfl(idxval, jb + 12, 64);
    int n4 = __shfl(idxval, jb + 16, 64);
    f32x4 g0 = ((const f32x4*)(y1 + (nb + n0) * 64))[u];
    f32x4 g1 = ((const f32x4*)(y1 + (nb + n1) * 64))[u];
    f32x4 g2 = ((const f32x4*)(y1 + (nb + n2) * 64))[u];
    f32x4 g3 = ((const f32x4*)(y1 + (nb + n3) * 64))[u];
    f32x4 g4 = ((const f32x4*)(y1 + (nb + n4) * 64))[u];
    f32x4 mx = g0, mn = g0, sm = g0, s2 = g0 * g0;
    mx = max4(mx, g1); mn = min4(mn, g1); sm += g1; s2 += g1 * g1;
    mx = max4(mx, g2); mn = min4(mn, g2); sm += g2; s2 += g2 * g2;
    mx = max4(mx, g3); mn = min4(mn, g3); sm += g3; s2 += g3 * g3;
    mx = max4(mx, g4); mn = min4(mn, g4); sm += g4; s2 += g4 * g4;
#pragma unroll
    for (int c = 0; c < 4; ++c) {
      mx[c] = fmaxf(mx[c], __shfl_xor(mx[c], 16, 64));
      mx[c] = fmaxf(mx[c], __shfl_xor(mx[c], 32, 64));
      mn[c] = fminf(mn[c], __shfl_xor(mn[c], 16, 64));
      mn[c] = fminf(mn[c], __shfl_xor(mn[c], 32, 64));
      sm[c] += __shfl_xor(sm[c], 16, 64);
      sm[c] += __shfl_xor(sm[c], 32, 64);
      s2[c] += __shfl_xor(s2[c], 16, 64);
      s2[c] += __shfl_xor(s2[c], 32, 64);
    }
    if (jb == 0) {  // lanes 0..15: full 256B contiguous stores
      f32x4 y2c = ((const f32x4*)(y2 + (size_t)p * 64))[u];
      ((f32x4*)(maxh + (size_t)p * 64))[u] = mx + y2c;
      ((f32x4*)(minh + (size_t)p * 64))[u] = mn + y2c;
      css += sm + 20.0f * y2c;
      cqq += s2 + 2.0f * y2c * sm + 20.0f * y2c * y2c;
    }
  }
  if (jb == 0) {
#pragma unroll
    for (int c = 0; c < 4; ++c) {
      atomicAdd(&lsum[u * 4 + c], css[c]);
      atomicAdd(&lsq[u * 4 + c], cqq[c]);
    }
  }
  __syncthreads();
  if (tid < 64) {
    atomicAdd(&gsum[tid], lsum[tid]);
    atomicAdd(&gsq[tid], lsq[tid]);
  }
}

// ---- Kernel 5: affine + relu + max-over-k selection, transposed store ----
__global__ __launch_bounds__(256) void final_kernel(
    const float* __restrict__ maxh, const float* __restrict__ minh,
    const float* __restrict__ gsum, const float* __restrict__ gsq,
    const float* __restrict__ gamma, const float* __restrict__ beta,
    float* __restrict__ out) {
  __shared__ float sc[64], cc_[64];
  __shared__ float tile[64 * 65];
  int b = blockIdx.x >> 7;
  int n0 = (blockIdx.x & 127) * 64;
  int t = threadIdx.x;
  if (t < 64) {
    float mean = gsum[t] * (1.0f / CNT_TOTAL);
    float var = gsq[t] * (1.0f / CNT_TOTAL) - mean * mean;
    float s = gamma[t] * rsqrtf(var + BN_EPSF);
    sc[t] = s;
    cc_[t] = beta[t] - mean * s;
  }
  __syncthreads();
#pragma unroll
  for (int i = 0; i < 16; ++i) {
    int lin = i * 256 + t;
    int o = lin & 63, nl = lin >> 6;
    size_t off = ((size_t)(b * N_) + n0 + nl) * 64 + o;
    float s = sc[o];
    float v = (s >= 0.f) ? maxh[off] : minh[off];
    float val = fmaxf(fmaf(v, s, cc_[o]), 0.f);
    tile[o * 65 + nl] = val;
  }
  __syncthreads();
#pragma unroll
  for (int i = 0; i < 16; ++i) {
    int lin = i * 256 + t;
    int nl = lin & 63, o = lin >> 6;
    out[((size_t)(b * 64) + o) * N_ + n0 + nl] = tile[o * 65 + nl];
  }
}

extern "C" void kernel_launch(void* const* d_in, const int* in_sizes, int n_in,
                              void* d_out, int out_size, void* d_ws,
                              size_t ws_size, hipStream_t stream) {
  const float* x = (const float*)d_in[0];
  const float* W = (const float*)d_in[1];
  const float* gamma = (const float*)d_in[2];
  const float* beta = (const float*)d_in[3];
  float* out = (float*)d_out;

  char* ws = (char*)d_ws;
  size_t off = 0;
  auto alloc = [&](size_t bytes) {
    char* p = ws + off;
    off += (bytes + 255) & ~(size_t)255;
    return p;
  };
  float* xt = (float*)alloc((size_t)B_ * N_ * 64 * 4);
  _Float16* xt16 = (_Float16*)alloc((size_t)B_ * N_ * 64 * 2);
  float* y1 = (float*)alloc((size_t)B_ * N_ * 64 * 4);
  float* y2 = (float*)alloc((size_t)B_ * N_ * 64 * 4);
  float* sq = (float*)alloc((size_t)B_ * N_ * 4);
  double* sqd = (double*)alloc((size_t)B_ * N_ * 8);
  int* pidx = (int*)alloc((size_t)B_ * N_ * NCAND * 4);  // 33.5 MB
  float* maxh = (float*)alloc((size_t)B_ * N_ * 64 * 4);
  int* idxf = (int*)alloc((size_t)B_ * N_ * K_ * 4);
  float* gsum = (float*)alloc(256);
  float* gsq = (float*)alloc(256);
  // minh aliases pidx (pidx fully consumed by refine before stats runs)
  float* minh = (float*)pidx;

  hipMemsetAsync(gsum, 0, 256, stream);
  hipMemsetAsync(gsq, 0, 256, stream);

  prep_kernel<<<B_ * (N_ / 64), 256, 0, stream>>>(x, W, xt, xt16, sq, sqd,
                                                  y1, y2);
  knn_mfma_kernel<<<B_ * (N_ / 64) * NSPLIT, 256, 0, stream>>>(xt16, sq, pidx);
  refine_kernel<<<(B_ * N_) / 4, 256, 0, stream>>>(xt, sqd, pidx, idxf);
  stats_kernel<<<(B_ * N_) / 16, 256, 0, stream>>>(y1, y2, idxf, maxh, minh,
                                                   gsum, gsq);
  final_kernel<<<B_ * (N_ / 64), 256, 0, stream>>>(maxh, minh, gsum, gsq,
                                                   gamma, beta, out);
}

// Round 5
// 381.703 us; speedup vs baseline: 1.7743x; 1.3402x over previous
//
#include <hip/hip_runtime.h>

typedef _Float16 half8 __attribute__((ext_vector_type(8)));
typedef float f32x4 __attribute__((ext_vector_type(4)));

#define B_ 4
#define C_ 64
#define N_ 8192
#define K_ 20
#define LCELL 8                   // per-(split,class) sorted list depth
#define NSPLIT 2
#define NCAND (16 * LCELL * NSPLIT)  // 256 candidates per query into refine
#define CNT_TOTAL (B_ * N_ * K_)  // 655360
#define BN_EPSF 1e-5f

__device__ __forceinline__ f32x4 max4(f32x4 a, f32x4 b) {
  f32x4 r;
  r.x = fmaxf(a.x, b.x); r.y = fmaxf(a.y, b.y);
  r.z = fmaxf(a.z, b.z); r.w = fmaxf(a.w, b.w);
  return r;
}
__device__ __forceinline__ f32x4 min4(f32x4 a, f32x4 b) {
  f32x4 r;
  r.x = fminf(a.x, b.x); r.y = fminf(a.y, b.y);
  r.z = fminf(a.z, b.z); r.w = fminf(a.w, b.w);
  return r;
}

// ---- Kernel 1: transpose x -> xt (f32 + f16), per-point sq (f32+f64),
// y1 = xt*W1^T, y2 = xt*W2^T - y1. W row o==lane held in 128 VGPRs.
// sq is stored PRE-BIASED by +512 (knn key bias folded in; refine uses sqd).
__global__ __launch_bounds__(256) void prep_kernel(
    const float* __restrict__ x, const float* __restrict__ W,
    float* __restrict__ xt, _Float16* __restrict__ xt16,
    float* __restrict__ sq, double* __restrict__ sqd,
    float* __restrict__ y1, float* __restrict__ y2) {
  __shared__ float xs[64 * 68];  // [n][c], stride 68 (16B-aligned rows)
  int b = blockIdx.x >> 7;
  int n0 = (blockIdx.x & 127) * 64;
  int t = threadIdx.x;
  int lane = t & 63;
  int wv = t >> 6;
#pragma unroll
  for (int i = 0; i < 16; ++i) {
    int lin = i * 256 + t;
    int c = lin >> 6, j = lin & 63;
    xs[j * 68 + c] = x[((b * 64 + c) * N_) + n0 + j];
  }
  // W row o = lane into registers (L1/L2-hot, 32 KB total)
  float4 w1[16], w2[16];
  const float4* wr = (const float4*)(W + lane * 128);
#pragma unroll
  for (int u = 0; u < 16; ++u) {
    w1[u] = wr[u];
    w2[u] = wr[16 + u];
  }
  __syncthreads();
#pragma unroll 2
  for (int i = 0; i < 16; ++i) {
    int nl = i * 4 + wv;
    const float4* xr = (const float4*)&xs[nl * 68];
    float d1 = 0.f, d2 = 0.f;
#pragma unroll
    for (int u = 0; u < 16; ++u) {
      float4 xv = xr[u];
      d1 = fmaf(xv.x, w1[u].x, d1); d1 = fmaf(xv.y, w1[u].y, d1);
      d1 = fmaf(xv.z, w1[u].z, d1); d1 = fmaf(xv.w, w1[u].w, d1);
      d2 = fmaf(xv.x, w2[u].x, d2); d2 = fmaf(xv.y, w2[u].y, d2);
      d2 = fmaf(xv.z, w2[u].z, d2); d2 = fmaf(xv.w, w2[u].w, d2);
    }
    int n = n0 + nl;
    y1[((b * N_) + n) * 64 + lane] = d1;
    y2[((b * N_) + n) * 64 + lane] = d2 - d1;
  }
#pragma unroll
  for (int i = 0; i < 16; ++i) {
    int lin = i * 256 + t;
    int c = lin & 63, nl = lin >> 6;
    float v = xs[nl * 68 + c];
    size_t o = ((size_t)(b * N_) + n0 + nl) * 64 + c;
    xt[o] = v;
    xt16[o] = (_Float16)v;
  }
  if (t < 64) {
    float s = 0.f;
    double sd = 0.0;
#pragma unroll
    for (int c = 0; c < 64; ++c) {
      float v = xs[t * 68 + c];
      s = fmaf(v, v, s);
      sd = fma((double)v, (double)v, sd);
    }
    sq[b * N_ + n0 + t] = s + 512.0f;  // pre-biased for knn key
    sqd[b * N_ + n0 + t] = sd;
  }
}

// ---- Kernel 2: MFMA distance scan, LDS-staged v4 (unchanged from R4 win).
// Cooperative reg->LDS staging of 64-cand chunks, double-buffered, one
// __syncthreads per chunk; consume path pure LDS (ds_read_b128 + MFMA +
// pair-merge insert). Packed value: (float_bits(sq512-2dot) & ~255)|tile(8b).
__global__ __launch_bounds__(256, 4) void knn_mfma_kernel(
    const _Float16* __restrict__ xt16, const float* __restrict__ sq,
    int* __restrict__ pidx) {
  __shared__ alignas(16) char bufB[2][9216];  // 4 tiles * 16 rows * 144B
  __shared__ float bufS[2][64];
  int t = threadIdx.x;
  int wave = t >> 6;
  int lane = t & 63;
  int col = lane & 15;
  int quad = lane >> 4;
  int blk = blockIdx.x;
  int split = blk & 1;
  int qt = (blk >> 1) & 127;
  int b = blk >> 8;
  int q0 = qt * 64 + wave * 16;
  size_t bbase = (size_t)b * N_;

  // A fragments: A[m=col][k=quad*8+j] -> query row q0+col
  const _Float16* arow = xt16 + (bbase + q0 + col) * 64;
  half8 A0 = *(const half8*)(arow + quad * 8);
  half8 A1 = *(const half8*)(arow + 32 + quad * 8);

  int dl[4][LCELL];
#pragma unroll
  for (int r = 0; r < 4; ++r)
#pragma unroll
    for (int j = 0; j < LCELL; ++j) dl[r][j] = 0x7fffffff;

#define PAIR_INSERT(accX, accY, sA, sB, CTB)                                 \
  {                                                                          \
    const int ctb_ = (CTB);                                                  \
    _Pragma("unroll") for (int r = 0; r < 4; ++r) {                          \
      float kA = fmaf((accX)[r], -2.0f, (sA));                               \
      float kB = fmaf((accY)[r], -2.0f, (sB));                               \
      int va = (__float_as_int(kA) & ~255) | ctb_;                           \
      int vb = (__float_as_int(kB) & ~255) | (ctb_ + 1);                     \
      int lo = min(va, vb), hi = max(va, vb);                                \
      int o0 = min(dl[r][0], lo);                                            \
      int o1 = min(min(dl[r][1], max(dl[r][0], lo)), hi);                    \
      int o2 = min(min(dl[r][2], max(dl[r][1], lo)), max(dl[r][0], hi));     \
      int o3 = min(min(dl[r][3], max(dl[r][2], lo)), max(dl[r][1], hi));     \
      int o4 = min(min(dl[r][4], max(dl[r][3], lo)), max(dl[r][2], hi));     \
      int o5 = min(min(dl[r][5], max(dl[r][4], lo)), max(dl[r][3], hi));     \
      int o6 = min(min(dl[r][6], max(dl[r][5], lo)), max(dl[r][4], hi));     \
      int o7 = min(min(dl[r][7], max(dl[r][6], lo)), max(dl[r][5], hi));     \
      dl[r][0] = o0; dl[r][1] = o1; dl[r][2] = o2; dl[r][3] = o3;            \
      dl[r][4] = o4; dl[r][5] = o5; dl[r][6] = o6; dl[r][7] = o7;            \
    }                                                                        \
  }

  int c0 = split * (N_ / NSPLIT);
  const _Float16* gpanel = xt16 + (bbase + c0) * 64;
  const float* spanel = sq + bbase + c0;

  int r0 = lane >> 3, e0 = lane & 7;  // lane's staged (row, 16B-chunk)

  int4 rA0, rA1, rB0, rB1;
  float sA = 0.f, sB = 0.f;

#define LOADR(Ra, Rb, Sv, CH)                                              \
  {                                                                        \
    const _Float16* gt = gpanel + ((size_t)(CH)*64 + wave * 16) * 64;      \
    Ra = *(const int4*)(gt + lane * 8);                                    \
    Rb = *(const int4*)(gt + 512 + lane * 8);                              \
    Sv = spanel[(CH)*64 + wave * 16 + col];                                \
  }
#define WRITEB(BUF, Ra, Rb, Sv)                                            \
  {                                                                        \
    char* lt = &bufB[BUF][wave * 2304];                                    \
    *(int4*)(lt + r0 * 144 + e0 * 16) = Ra;                                \
    *(int4*)(lt + (r0 + 8) * 144 + e0 * 16) = Rb;                          \
    if (lane < 16) bufS[BUF][wave * 16 + lane] = Sv;                       \
  }
#define CONSUME(BUF, CH)                                                   \
  {                                                                        \
    const char* lb = bufB[BUF];                                            \
    const float* sb = bufS[BUF];                                           \
    const f32x4 z = {0.f, 0.f, 0.f, 0.f};                                  \
    half8 F0 = *(const half8*)(lb + 0 * 2304 + col * 144 + quad * 16);     \
    half8 F1 = *(const half8*)(lb + 0 * 2304 + col * 144 + (4 + quad) * 16); \
    half8 G0 = *(const half8*)(lb + 1 * 2304 + col * 144 + quad * 16);     \
    half8 G1 = *(const half8*)(lb + 1 * 2304 + col * 144 + (4 + quad) * 16); \
    f32x4 a0 = __builtin_amdgcn_mfma_f32_16x16x32_f16(A0, F0, z, 0, 0, 0); \
    a0 = __builtin_amdgcn_mfma_f32_16x16x32_f16(A1, F1, a0, 0, 0, 0);      \
    f32x4 a1 = __builtin_amdgcn_mfma_f32_16x16x32_f16(A0, G0, z, 0, 0, 0); \
    a1 = __builtin_amdgcn_mfma_f32_16x16x32_f16(A1, G1, a1, 0, 0, 0);      \
    half8 H0 = *(const half8*)(lb + 2 * 2304 + col * 144 + quad * 16);     \
    half8 H1 = *(const half8*)(lb + 2 * 2304 + col * 144 + (4 + quad) * 16); \
    half8 I0 = *(const half8*)(lb + 3 * 2304 + col * 144 + quad * 16);     \
    half8 I1 = *(const half8*)(lb + 3 * 2304 + col * 144 + (4 + quad) * 16); \
    f32x4 a2 = __builtin_amdgcn_mfma_f32_16x16x32_f16(A0, H0, z, 0, 0, 0); \
    a2 = __builtin_amdgcn_mfma_f32_16x16x32_f16(A1, H1, a2, 0, 0, 0);      \
    f32x4 a3 = __builtin_amdgcn_mfma_f32_16x16x32_f16(A0, I0, z, 0, 0, 0); \
    a3 = __builtin_amdgcn_mfma_f32_16x16x32_f16(A1, I1, a3, 0, 0, 0);      \
    float s0 = sb[col], s1 = sb[16 + col];                                 \
    float s2 = sb[32 + col], s3 = sb[48 + col];                            \
    PAIR_INSERT(a0, a1, s0, s1, (CH)*4);                                   \
    PAIR_INSERT(a2, a3, s2, s3, (CH)*4 + 2);                               \
  }

  // prologue: chunk0 -> buf0, chunk1 -> regs
  LOADR(rA0, rA1, sA, 0);
  LOADR(rB0, rB1, sB, 1);
  WRITEB(0, rA0, rA1, sA);
  __syncthreads();

  for (int ch = 0; ch < 64; ch += 2) {
    if (ch + 2 < 64) LOADR(rA0, rA1, sA, ch + 2);
    WRITEB(1, rB0, rB1, sB);
    CONSUME(0, ch);
    __syncthreads();
    if (ch + 3 < 64) LOADR(rB0, rB1, sB, ch + 3);
    if (ch + 2 < 64) WRITEB(0, rA0, rA1, sA);
    CONSUME(1, ch + 1);
    __syncthreads();
  }
#undef PAIR_INSERT
#undef LOADR
#undef WRITEB
#undef CONSUME

#pragma unroll
  for (int r = 0; r < 4; ++r) {
    int q = q0 + quad * 4 + r;
    int* o = pidx + (bbase + q) * NCAND + split * (16 * LCELL) + col * LCELL;
#pragma unroll
    for (int j = 0; j < LCELL; ++j) o[j] = dl[r][j];  // raw packed value
  }
}

// ---- Kernel 3: refinement v8 — chain-cut. One WAVE per point.
// R4 counters: VALUBusy 34%, MFMA 0, HBM 2% -> serial-dependency-bound
// (52 sequential f64 butterfly pops = ~300-level dependent chain).
// v8: (a) stage-2 pops on 32-bit ints (the raw packed values, order-
// preserving); ties resolved by __ballot + first-owner; owner writes its
// reconstructed ci to per-wave LDS slot s (index transport decoupled from
// the key). (b) stage 3 splits each candidate row across lane pairs
// (s, s+32): 8x f32x4 + 32 f64 FMA each, combined by one shfl_xor(32).
// (c) stage 4 replaced by rank-count: 32 exact f64 keys (unique via idx in
// mantissa) in LDS; each lane counts smaller keys (broadcast ds_read_b64,
// no serial chain) and stores o[rank]=ci when rank<20. Ordering semantics
// identical (fp64 key + index tie-break).
__global__ __launch_bounds__(256) void refine_kernel(
    const float* __restrict__ xt, const double* __restrict__ sqd,
    const int* __restrict__ pidx, int* __restrict__ idxf) {
  __shared__ float qs[4][64];
  __shared__ int slds[4][32];
  __shared__ double klds[4][32];
  int tid = threadIdx.x;
  int wave = tid >> 6, lane = tid & 63;
  int p = blockIdx.x * 4 + wave;  // global point id
  int b = p >> 13;
  size_t bbase = (size_t)b * N_;
  int plocal = p & (N_ - 1);

  // stage query row into LDS (lanes 0..15 write 16B each)
  if (lane < 16) {
    ((f32x4*)qs[wave])[lane] = ((const f32x4*)(xt + (size_t)p * 64))[lane];
  }
  // stage 1: lane's 4 packed values (already sorted: even lane = elems 0..3
  // of its cell's sorted-8, odd lane = elems 4..7). colsplit is per-lane
  // constant: col=(lane>>1)&15, split=lane>>5.
  const int* pi = pidx + (size_t)p * NCAND + lane * 4;
  int4 cc = *(const int4*)pi;
  int colsplit = ((lane >> 1) & 15) + (lane >> 5) * (N_ / NSPLIT);
  int v0 = cc.x, v1 = cc.y, v2 = cc.z, v3 = cc.w;
  if ((((v0 & 255) << 4) + colsplit) == plocal) v0 = 0x7fffffff;
  if ((((v1 & 255) << 4) + colsplit) == plocal) v1 = 0x7fffffff;
  if ((((v2 & 255) << 4) + colsplit) == plocal) v2 = 0x7fffffff;
  if ((((v3 & 255) << 4) + colsplit) == plocal) v3 = 0x7fffffff;
  {  // single forward bubble: restores sortedness after the one displacement
    int lo, hi;
    lo = min(v0, v1); hi = max(v0, v1); v0 = lo; v1 = hi;
    lo = min(v1, v2); hi = max(v1, v2); v1 = lo; v2 = hi;
    lo = min(v2, v3); hi = max(v2, v3); v2 = lo; v3 = hi;
  }
  int vh = v0, h1 = v1, h2 = v2, h3 = v3;

  // stage 2: 32 int pops; popped owner writes its ci to slds[s]
  unsigned long long mylt = (1ull << lane) - 1;
  int* sl = slds[wave];
#pragma unroll
  for (int s = 0; s < 32; ++s) {
    int m = vh;
    m = min(m, __shfl_xor(m, 1, 64));
    m = min(m, __shfl_xor(m, 2, 64));
    m = min(m, __shfl_xor(m, 4, 64));
    m = min(m, __shfl_xor(m, 8, 64));
    m = min(m, __shfl_xor(m, 16, 64));
    m = min(m, __shfl_xor(m, 32, 64));
    bool eq = (vh == m);
    unsigned long long bal = __ballot(eq);
    if (eq && ((bal & mylt) == 0)) {  // first owner pops
      sl[s] = ((vh & 255) << 4) + colsplit;
      vh = h1; h1 = h2; h2 = h3; h3 = 0x7fffffff;
    }
  }

  // stage 3: lane pair (s, s+32) computes candidate s's exact fp64 dot,
  // 32 dims each, combined via shfl_xor(32).
  int ci = sl[lane & 31];
  int half = lane >> 5;
  const f32x4* cr = (const f32x4*)(xt + (bbase + ci) * 64) + half * 8;
  const f32x4* qr = (const f32x4*)qs[wave] + half * 8;
  double a0 = 0.0, a1 = 0.0, a2 = 0.0, a3 = 0.0;
#pragma unroll
  for (int t2 = 0; t2 < 8; ++t2) {
    f32x4 cv = cr[t2];
    f32x4 qv = qr[t2];
    a0 = fma((double)cv.x, (double)qv.x, a0);
    a1 = fma((double)cv.y, (double)qv.y, a1);
    a2 = fma((double)cv.z, (double)qv.z, a2);
    a3 = fma((double)cv.w, (double)qv.w, a3);
  }
  double dot = (a0 + a1) + (a2 + a3);
  dot += __shfl_xor(dot, 32, 64);
  double kv = 1e300;
  if (lane < 32) {
    double kd = fma(dot, -2.0, sqd[bbase + ci]) + 1024.0;
    kv = __longlong_as_double(
        (__double_as_longlong(kd) & ~0x1FFFLL) | (long long)ci);
    klds[wave][lane] = kv;
  }

  // stage 4: rank-count over 32 unique exact keys; store o[rank]=ci
  if (lane < 32) {
    const double* kl = klds[wave];
    int c0 = 0, c1 = 0, c2 = 0, c3 = 0;
#pragma unroll
    for (int t2 = 0; t2 < 32; t2 += 4) {
      c0 += (kl[t2] < kv) ? 1 : 0;
      c1 += (kl[t2 + 1] < kv) ? 1 : 0;
      c2 += (kl[t2 + 2] < kv) ? 1 : 0;
      c3 += (kl[t2 + 3] < kv) ? 1 : 0;
    }
    int rank = (c0 + c1) + (c2 + c3);
    if (rank < K_) idxf[(size_t)p * K_ + rank] = ci;
  }
}

// ---- Kernel 4: one WAVE per point. Lane (u=lane&15, jb=lane>>4); 5 rounds:
// lane loads 16B chunk u of neighbor jb+4r -> each 16-lane group reads a full
// 256B y1 row per instruction (no partial lines). max/min/sum/sumsq of the
// gathered y1 reduced across jb via shfl_xor(16,32); y2 applied once:
// max(h)=max(g)+y2, sum(h)=sum(g)+K*y2, sumsq(h)=sum(g^2)+2*y2*sum(g)+K*y2^2.
// 4 points per wave sequentially; BN sums -> LDS atomics -> 128 global/block.
__global__ __launch_bounds__(256) void stats_kernel(
    const float* __restrict__ y1, const float* __restrict__ y2,
    const int* __restrict__ idxf, float* __restrict__ maxh,
    float* __restrict__ minh, float* __restrict__ gsum,
    float* __restrict__ gsq) {
  __shared__ float lsum[64], lsq[64];
  int tid = threadIdx.x;
  if (tid < 64) { lsum[tid] = 0.f; lsq[tid] = 0.f; }
  __syncthreads();
  int wv = tid >> 6, lane = tid & 63;
  int u = lane & 15, jb = lane >> 4;
  int p0 = blockIdx.x * 16 + wv * 4;  // 16 contiguous points per block
  size_t nb = (size_t)((p0 >> 13) * N_);
  f32x4 css = {0.f, 0.f, 0.f, 0.f}, cqq = {0.f, 0.f, 0.f, 0.f};
#pragma unroll
  for (int it = 0; it < 4; ++it) {
    int p = p0 + it;
    int idxval = (lane < K_) ? idxf[(size_t)p * K_ + lane] : 0;
    int n0 = __shfl(idxval, jb, 64);
    int n1 = __shfl(idxval, jb + 4, 64);
    int n2 = __shfl(idxval, jb + 8, 64);
    int n3 = __shfl(idxval, jb + 12, 64);
    int n4 = __shfl(idxval, jb + 16, 64);
    f32x4 g0 = ((const f32x4*)(y1 + (nb + n0) * 64))[u];
    f32x4 g1 = ((const f32x4*)(y1 + (nb + n1) * 64))[u];
    f32x4 g2 = ((const f32x4*)(y1 + (nb + n2) * 64))[u];
    f32x4 g3 = ((const f32x4*)(y1 + (nb + n3) * 64))[u];
    f32x4 g4 = ((const f32x4*)(y1 + (nb + n4) * 64))[u];
    f32x4 mx = g0, mn = g0, sm = g0, s2 = g0 * g0;
    mx = max4(mx, g1); mn = min4(mn, g1); sm += g1; s2 += g1 * g1;
    mx = max4(mx, g2); mn = min4(mn, g2); sm += g2; s2 += g2 * g2;
    mx = max4(mx, g3); mn = min4(mn, g3); sm += g3; s2 += g3 * g3;
    mx = max4(mx, g4); mn = min4(mn, g4); sm += g4; s2 += g4 * g4;
#pragma unroll
    for (int c = 0; c < 4; ++c) {
      mx[c] = fmaxf(mx[c], __shfl_xor(mx[c], 16, 64));
      mx[c] = fmaxf(mx[c], __shfl_xor(mx[c], 32, 64));
      mn[c] = fminf(mn[c], __shfl_xor(mn[c], 16, 64));
      mn[c] = fminf(mn[c], __shfl_xor(mn[c], 32, 64));
      sm[c] += __shfl_xor(sm[c], 16, 64);
      sm[c] += __shfl_xor(sm[c], 32, 64);
      s2[c] += __shfl_xor(s2[c], 16, 64);
      s2[c] += __shfl_xor(s2[c], 32, 64);
    }
    if (jb == 0) {  // lanes 0..15: full 256B contiguous stores
      f32x4 y2c = ((const f32x4*)(y2 + (size_t)p * 64))[u];
      ((f32x4*)(maxh + (size_t)p * 64))[u] = mx + y2c;
      ((f32x4*)(minh + (size_t)p * 64))[u] = mn + y2c;
      css += sm + 20.0f * y2c;
      cqq += s2 + 2.0f * y2c * sm + 20.0f * y2c * y2c;
    }
  }
  if (jb == 0) {
#pragma unroll
    for (int c = 0; c < 4; ++c) {
      atomicAdd(&lsum[u * 4 + c], css[c]);
      atomicAdd(&lsq[u * 4 + c], cqq[c]);
    }
  }
  __syncthreads();
  if (tid < 64) {
    atomicAdd(&gsum[tid], lsum[tid]);
    atomicAdd(&gsq[tid], lsq[tid]);
  }
}

// ---- Kernel 5: affine + relu + max-over-k selection, transposed store ----
__global__ __launch_bounds__(256) void final_kernel(
    const float* __restrict__ maxh, const float* __restrict__ minh,
    const float* __restrict__ gsum, const float* __restrict__ gsq,
    const float* __restrict__ gamma, const float* __restrict__ beta,
    float* __restrict__ out) {
  __shared__ float sc[64], cc_[64];
  __shared__ float tile[64 * 65];
  int b = blockIdx.x >> 7;
  int n0 = (blockIdx.x & 127) * 64;
  int t = threadIdx.x;
  if (t < 64) {
    float mean = gsum[t] * (1.0f / CNT_TOTAL);
    float var = gsq[t] * (1.0f / CNT_TOTAL) - mean * mean;
    float s = gamma[t] * rsqrtf(var + BN_EPSF);
    sc[t] = s;
    cc_[t] = beta[t] - mean * s;
  }
  __syncthreads();
#pragma unroll
  for (int i = 0; i < 16; ++i) {
    int lin = i * 256 + t;
    int o = lin & 63, nl = lin >> 6;
    size_t off = ((size_t)(b * N_) + n0 + nl) * 64 + o;
    float s = sc[o];
    float v = (s >= 0.f) ? maxh[off] : minh[off];
    float val = fmaxf(fmaf(v, s, cc_[o]), 0.f);
    tile[o * 65 + nl] = val;
  }
  __syncthreads();
#pragma unroll
  for (int i = 0; i < 16; ++i) {
    int lin = i * 256 + t;
    int nl = lin & 63, o = lin >> 6;
    out[((size_t)(b * 64) + o) * N_ + n0 + nl] = tile[o * 65 + nl];
  }
}

extern "C" void kernel_launch(void* const* d_in, const int* in_sizes, int n_in,
                              void* d_out, int out_size, void* d_ws,
                              size_t ws_size, hipStream_t stream) {
  const float* x = (const float*)d_in[0];
  const float* W = (const float*)d_in[1];
  const float* gamma = (const float*)d_in[2];
  const float* beta = (const float*)d_in[3];
  float* out = (float*)d_out;

  char* ws = (char*)d_ws;
  size_t off = 0;
  auto alloc = [&](size_t bytes) {
    char* p = ws + off;
    off += (bytes + 255) & ~(size_t)255;
    return p;
  };
  float* xt = (float*)alloc((size_t)B_ * N_ * 64 * 4);
  _Float16* xt16 = (_Float16*)alloc((size_t)B_ * N_ * 64 * 2);
  float* y1 = (float*)alloc((size_t)B_ * N_ * 64 * 4);
  float* y2 = (float*)alloc((size_t)B_ * N_ * 64 * 4);
  float* sq = (float*)alloc((size_t)B_ * N_ * 4);
  double* sqd = (double*)alloc((size_t)B_ * N_ * 8);
  int* pidx = (int*)alloc((size_t)B_ * N_ * NCAND * 4);  // 33.5 MB
  float* maxh = (float*)alloc((size_t)B_ * N_ * 64 * 4);
  int* idxf = (int*)alloc((size_t)B_ * N_ * K_ * 4);
  float* gsum = (float*)alloc(256);
  float* gsq = (float*)alloc(256);
  // minh aliases pidx (pidx fully consumed by refine before stats runs)
  float* minh = (float*)pidx;

  hipMemsetAsync(gsum, 0, 256, stream);
  hipMemsetAsync(gsq, 0, 256, stream);

  prep_kernel<<<B_ * (N_ / 64), 256, 0, stream>>>(x, W, xt, xt16, sq, sqd,
                                                  y1, y2);
  knn_mfma_kernel<<<B_ * (N_ / 64) * NSPLIT, 256, 0, stream>>>(xt16, sq, pidx);
  refine_kernel<<<(B_ * N_) / 4, 256, 0, stream>>>(xt, sqd, pidx, idxf);
  stats_kernel<<<(B_ * N_) / 16, 256, 0, stream>>>(y1, y2, idxf, maxh, minh,
                                                   gsum, gsq);
  final_kernel<<<B_ * (N_ / 64), 256, 0, stream>>>(maxh, minh, gsum, gsq,
                                                   gamma, beta, out);
}

// Round 6
// 378.470 us; speedup vs baseline: 1.7894x; 1.0085x over previous
//
#include <hip/hip_runtime.h>

typedef _Float16 half8 __attribute__((ext_vector_type(8)));
typedef float f32x4 __attribute__((ext_vector_type(4)));

#define B_ 4
#define C_ 64
#define N_ 8192
#define K_ 20
#define LCELL 8                   // per-(split,class) sorted list depth
#define NSPLIT 4
#define NCAND (16 * LCELL * NSPLIT)  // 512 candidates per query into refine
#define CNT_TOTAL (B_ * N_ * K_)  // 655360
#define BN_EPSF 1e-5f

__device__ __forceinline__ f32x4 max4(f32x4 a, f32x4 b) {
  f32x4 r;
  r.x = fmaxf(a.x, b.x); r.y = fmaxf(a.y, b.y);
  r.z = fmaxf(a.z, b.z); r.w = fmaxf(a.w, b.w);
  return r;
}
__device__ __forceinline__ f32x4 min4(f32x4 a, f32x4 b) {
  f32x4 r;
  r.x = fminf(a.x, b.x); r.y = fminf(a.y, b.y);
  r.z = fminf(a.z, b.z); r.w = fminf(a.w, b.w);
  return r;
}

// ---- Kernel 1: transpose x -> xt (f32 + f16), per-point sq (f32+f64),
// y1 = xt*W1^T, y2 = xt*W2^T - y1. W row o==lane held in 128 VGPRs.
// sq is stored PRE-BIASED by +512 (knn key bias folded in; refine uses sqd).
__global__ __launch_bounds__(256) void prep_kernel(
    const float* __restrict__ x, const float* __restrict__ W,
    float* __restrict__ xt, _Float16* __restrict__ xt16,
    float* __restrict__ sq, double* __restrict__ sqd,
    float* __restrict__ y1, float* __restrict__ y2) {
  __shared__ float xs[64 * 68];  // [n][c], stride 68 (16B-aligned rows)
  int b = blockIdx.x >> 7;
  int n0 = (blockIdx.x & 127) * 64;
  int t = threadIdx.x;
  int lane = t & 63;
  int wv = t >> 6;
#pragma unroll
  for (int i = 0; i < 16; ++i) {
    int lin = i * 256 + t;
    int c = lin >> 6, j = lin & 63;
    xs[j * 68 + c] = x[((b * 64 + c) * N_) + n0 + j];
  }
  // W row o = lane into registers (L1/L2-hot, 32 KB total)
  float4 w1[16], w2[16];
  const float4* wr = (const float4*)(W + lane * 128);
#pragma unroll
  for (int u = 0; u < 16; ++u) {
    w1[u] = wr[u];
    w2[u] = wr[16 + u];
  }
  __syncthreads();
#pragma unroll 2
  for (int i = 0; i < 16; ++i) {
    int nl = i * 4 + wv;
    const float4* xr = (const float4*)&xs[nl * 68];
    float d1 = 0.f, d2 = 0.f;
#pragma unroll
    for (int u = 0; u < 16; ++u) {
      float4 xv = xr[u];
      d1 = fmaf(xv.x, w1[u].x, d1); d1 = fmaf(xv.y, w1[u].y, d1);
      d1 = fmaf(xv.z, w1[u].z, d1); d1 = fmaf(xv.w, w1[u].w, d1);
      d2 = fmaf(xv.x, w2[u].x, d2); d2 = fmaf(xv.y, w2[u].y, d2);
      d2 = fmaf(xv.z, w2[u].z, d2); d2 = fmaf(xv.w, w2[u].w, d2);
    }
    int n = n0 + nl;
    y1[((b * N_) + n) * 64 + lane] = d1;
    y2[((b * N_) + n) * 64 + lane] = d2 - d1;
  }
#pragma unroll
  for (int i = 0; i < 16; ++i) {
    int lin = i * 256 + t;
    int c = lin & 63, nl = lin >> 6;
    float v = xs[nl * 68 + c];
    size_t o = ((size_t)(b * N_) + n0 + nl) * 64 + c;
    xt[o] = v;
    xt16[o] = (_Float16)v;
  }
  if (t < 64) {
    float s = 0.f;
    double sd = 0.0;
#pragma unroll
    for (int c = 0; c < 64; ++c) {
      float v = xs[t * 68 + c];
      s = fmaf(v, v, s);
      sd = fma((double)v, (double)v, sd);
    }
    sq[b * N_ + n0 + t] = s + 512.0f;  // pre-biased for knn key
    sqd[b * N_ + n0 + t] = sd;
  }
}

// ---- Kernel 2: MFMA distance scan, LDS-staged v5. NSPLIT=4: grid 2048
// blocks = 8 blocks/CU (R5 showed 18.9KB LDS / 52 VGPR allow it; grid was
// the only occupancy limiter at 4 blocks/CU, VALUBusy 72%). Per-block panel
// = 2048 cands = 32 chunks; total work invariant; 8 waves/SIMD hide the
// per-chunk stage latency + barrier drain. Launch bounds stay (256,4) —
// R2's regression was register starvation from (256,6), not NSPLIT.
// Cooperative reg->LDS staging of 64-cand chunks, double-buffered, one
// __syncthreads per chunk half; consume path pure LDS (ds_read_b128 + MFMA
// + pair-merge insert). Packed value: (float_bits(sq512-2dot)&~255)|tile
// (7b tile id, 0..127 within split).
__global__ __launch_bounds__(256, 4) void knn_mfma_kernel(
    const _Float16* __restrict__ xt16, const float* __restrict__ sq,
    int* __restrict__ pidx) {
  __shared__ alignas(16) char bufB[2][9216];  // 4 tiles * 16 rows * 144B
  __shared__ float bufS[2][64];
  int t = threadIdx.x;
  int wave = t >> 6;
  int lane = t & 63;
  int col = lane & 15;
  int quad = lane >> 4;
  int blk = blockIdx.x;
  int split = blk & 3;
  int qt = (blk >> 2) & 127;
  int b = blk >> 9;
  int q0 = qt * 64 + wave * 16;
  size_t bbase = (size_t)b * N_;

  // A fragments: A[m=col][k=quad*8+j] -> query row q0+col
  const _Float16* arow = xt16 + (bbase + q0 + col) * 64;
  half8 A0 = *(const half8*)(arow + quad * 8);
  half8 A1 = *(const half8*)(arow + 32 + quad * 8);

  int dl[4][LCELL];
#pragma unroll
  for (int r = 0; r < 4; ++r)
#pragma unroll
    for (int j = 0; j < LCELL; ++j) dl[r][j] = 0x7fffffff;

#define PAIR_INSERT(accX, accY, sA, sB, CTB)                                 \
  {                                                                          \
    const int ctb_ = (CTB);                                                  \
    _Pragma("unroll") for (int r = 0; r < 4; ++r) {                          \
      float kA = fmaf((accX)[r], -2.0f, (sA));                               \
      float kB = fmaf((accY)[r], -2.0f, (sB));                               \
      int va = (__float_as_int(kA) & ~255) | ctb_;                           \
      int vb = (__float_as_int(kB) & ~255) | (ctb_ + 1);                     \
      int lo = min(va, vb), hi = max(va, vb);                                \
      int o0 = min(dl[r][0], lo);                                            \
      int o1 = min(min(dl[r][1], max(dl[r][0], lo)), hi);                    \
      int o2 = min(min(dl[r][2], max(dl[r][1], lo)), max(dl[r][0], hi));     \
      int o3 = min(min(dl[r][3], max(dl[r][2], lo)), max(dl[r][1], hi));     \
      int o4 = min(min(dl[r][4], max(dl[r][3], lo)), max(dl[r][2], hi));     \
      int o5 = min(min(dl[r][5], max(dl[r][4], lo)), max(dl[r][3], hi));     \
      int o6 = min(min(dl[r][6], max(dl[r][5], lo)), max(dl[r][4], hi));     \
      int o7 = min(min(dl[r][7], max(dl[r][6], lo)), max(dl[r][5], hi));     \
      dl[r][0] = o0; dl[r][1] = o1; dl[r][2] = o2; dl[r][3] = o3;            \
      dl[r][4] = o4; dl[r][5] = o5; dl[r][6] = o6; dl[r][7] = o7;            \
    }                                                                        \
  }

  int c0 = split * (N_ / NSPLIT);
  const _Float16* gpanel = xt16 + (bbase + c0) * 64;
  const float* spanel = sq + bbase + c0;

  int r0 = lane >> 3, e0 = lane & 7;  // lane's staged (row, 16B-chunk)

  int4 rA0, rA1, rB0, rB1;
  float sA = 0.f, sB = 0.f;

#define LOADR(Ra, Rb, Sv, CH)                                              \
  {                                                                        \
    const _Float16* gt = gpanel + ((size_t)(CH)*64 + wave * 16) * 64;      \
    Ra = *(const int4*)(gt + lane * 8);                                    \
    Rb = *(const int4*)(gt + 512 + lane * 8);                              \
    Sv = spanel[(CH)*64 + wave * 16 + col];                                \
  }
#define WRITEB(BUF, Ra, Rb, Sv)                                            \
  {                                                                        \
    char* lt = &bufB[BUF][wave * 2304];                                    \
    *(int4*)(lt + r0 * 144 + e0 * 16) = Ra;                                \
    *(int4*)(lt + (r0 + 8) * 144 + e0 * 16) = Rb;                          \
    if (lane < 16) bufS[BUF][wave * 16 + lane] = Sv;                       \
  }
#define CONSUME(BUF, CH)                                                   \
  {                                                                        \
    const char* lb = bufB[BUF];                                            \
    const float* sb = bufS[BUF];                                           \
    const f32x4 z = {0.f, 0.f, 0.f, 0.f};                                  \
    half8 F0 = *(const half8*)(lb + 0 * 2304 + col * 144 + quad * 16);     \
    half8 F1 = *(const half8*)(lb + 0 * 2304 + col * 144 + (4 + quad) * 16); \
    half8 G0 = *(const half8*)(lb + 1 * 2304 + col * 144 + quad * 16);     \
    half8 G1 = *(const half8*)(lb + 1 * 2304 + col * 144 + (4 + quad) * 16); \
    f32x4 a0 = __builtin_amdgcn_mfma_f32_16x16x32_f16(A0, F0, z, 0, 0, 0); \
    a0 = __builtin_amdgcn_mfma_f32_16x16x32_f16(A1, F1, a0, 0, 0, 0);      \
    f32x4 a1 = __builtin_amdgcn_mfma_f32_16x16x32_f16(A0, G0, z, 0, 0, 0); \
    a1 = __builtin_amdgcn_mfma_f32_16x16x32_f16(A1, G1, a1, 0, 0, 0);      \
    half8 H0 = *(const half8*)(lb + 2 * 2304 + col * 144 + quad * 16);     \
    half8 H1 = *(const half8*)(lb + 2 * 2304 + col * 144 + (4 + quad) * 16); \
    half8 I0 = *(const half8*)(lb + 3 * 2304 + col * 144 + quad * 16);     \
    half8 I1 = *(const half8*)(lb + 3 * 2304 + col * 144 + (4 + quad) * 16); \
    f32x4 a2 = __builtin_amdgcn_mfma_f32_16x16x32_f16(A0, H0, z, 0, 0, 0); \
    a2 = __builtin_amdgcn_mfma_f32_16x16x32_f16(A1, H1, a2, 0, 0, 0);      \
    f32x4 a3 = __builtin_amdgcn_mfma_f32_16x16x32_f16(A0, I0, z, 0, 0, 0); \
    a3 = __builtin_amdgcn_mfma_f32_16x16x32_f16(A1, I1, a3, 0, 0, 0);      \
    float s0 = sb[col], s1 = sb[16 + col];                                 \
    float s2 = sb[32 + col], s3 = sb[48 + col];                            \
    PAIR_INSERT(a0, a1, s0, s1, (CH)*4);                                   \
    PAIR_INSERT(a2, a3, s2, s3, (CH)*4 + 2);                               \
  }

  // prologue: chunk0 -> buf0, chunk1 -> regs
  LOADR(rA0, rA1, sA, 0);
  LOADR(rB0, rB1, sB, 1);
  WRITEB(0, rA0, rA1, sA);
  __syncthreads();

  for (int ch = 0; ch < 32; ch += 2) {
    if (ch + 2 < 32) LOADR(rA0, rA1, sA, ch + 2);
    WRITEB(1, rB0, rB1, sB);
    CONSUME(0, ch);
    __syncthreads();
    if (ch + 3 < 32) LOADR(rB0, rB1, sB, ch + 3);
    if (ch + 2 < 32) WRITEB(0, rA0, rA1, sA);
    CONSUME(1, ch + 1);
    __syncthreads();
  }
#undef PAIR_INSERT
#undef LOADR
#undef WRITEB
#undef CONSUME

#pragma unroll
  for (int r = 0; r < 4; ++r) {
    int q = q0 + quad * 4 + r;
    int* o = pidx + (bbase + q) * NCAND + split * (16 * LCELL) + col * LCELL;
#pragma unroll
    for (int j = 0; j < LCELL; ++j) o[j] = dl[r][j];  // raw packed value
  }
}

// ---- Kernel 3: refinement v9 — chain-cut, NCAND=512. One WAVE per point.
// Each lane owns one (split=lane>>4, col=lane&15) cell = 8 ALREADY-SORTED
// packed values. Stage 1: load 2x int4, self-exclude (single displacement ->
// one 7-step bubble pass restores sortedness). Stage 2: 32 int pops (6-shfl
// min butterfly); ties resolved by __ballot + first-owner; owner writes its
// reconstructed ci to per-wave LDS slot s. Stage 3: lane pair (s, s+32)
// computes candidate s's exact fp64 dot (32 dims each, combined via one
// shfl_xor(32)). Stage 4: rank-count over 32 unique exact f64 keys in LDS
// (idx in mantissa); o[rank]=ci when rank<20. Ordering semantics: fp64 key
// + index tie-break, identical to the passing rounds.
__global__ __launch_bounds__(256) void refine_kernel(
    const float* __restrict__ xt, const double* __restrict__ sqd,
    const int* __restrict__ pidx, int* __restrict__ idxf) {
  __shared__ float qs[4][64];
  __shared__ int slds[4][32];
  __shared__ double klds[4][32];
  int tid = threadIdx.x;
  int wave = tid >> 6, lane = tid & 63;
  int p = blockIdx.x * 4 + wave;  // global point id
  int b = p >> 13;
  size_t bbase = (size_t)b * N_;
  int plocal = p & (N_ - 1);

  // stage query row into LDS (lanes 0..15 write 16B each)
  if (lane < 16) {
    ((f32x4*)qs[wave])[lane] = ((const f32x4*)(xt + (size_t)p * 64))[lane];
  }
  // stage 1: lane's cell (split=lane>>4, col=lane&15): 8 sorted values
  const int* pi = pidx + (size_t)p * NCAND + lane * 8;
  int4 ca = *(const int4*)pi;
  int4 cb = *(const int4*)(pi + 4);
  int colsplit = (lane & 15) + (lane >> 4) * (N_ / NSPLIT);
  int v0 = ca.x, v1 = ca.y, v2 = ca.z, v3 = ca.w;
  int v4 = cb.x, v5 = cb.y, v6 = cb.z, v7 = cb.w;
  if ((((v0 & 255) << 4) + colsplit) == plocal) v0 = 0x7fffffff;
  if ((((v1 & 255) << 4) + colsplit) == plocal) v1 = 0x7fffffff;
  if ((((v2 & 255) << 4) + colsplit) == plocal) v2 = 0x7fffffff;
  if ((((v3 & 255) << 4) + colsplit) == plocal) v3 = 0x7fffffff;
  if ((((v4 & 255) << 4) + colsplit) == plocal) v4 = 0x7fffffff;
  if ((((v5 & 255) << 4) + colsplit) == plocal) v5 = 0x7fffffff;
  if ((((v6 & 255) << 4) + colsplit) == plocal) v6 = 0x7fffffff;
  if ((((v7 & 255) << 4) + colsplit) == plocal) v7 = 0x7fffffff;
  {  // single forward bubble: restores sortedness after the one displacement
    int lo, hi;
    lo = min(v0, v1); hi = max(v0, v1); v0 = lo; v1 = hi;
    lo = min(v1, v2); hi = max(v1, v2); v1 = lo; v2 = hi;
    lo = min(v2, v3); hi = max(v2, v3); v2 = lo; v3 = hi;
    lo = min(v3, v4); hi = max(v3, v4); v3 = lo; v4 = hi;
    lo = min(v4, v5); hi = max(v4, v5); v4 = lo; v5 = hi;
    lo = min(v5, v6); hi = max(v5, v6); v5 = lo; v6 = hi;
    lo = min(v6, v7); hi = max(v6, v7); v6 = lo; v7 = hi;
  }
  int vh = v0, h1 = v1, h2 = v2, h3 = v3, h4 = v4, h5 = v5, h6 = v6,
      h7 = v7;

  // stage 2: 32 int pops; popped owner writes its ci to slds[s]
  unsigned long long mylt = (1ull << lane) - 1;
  int* sl = slds[wave];
#pragma unroll
  for (int s = 0; s < 32; ++s) {
    int m = vh;
    m = min(m, __shfl_xor(m, 1, 64));
    m = min(m, __shfl_xor(m, 2, 64));
    m = min(m, __shfl_xor(m, 4, 64));
    m = min(m, __shfl_xor(m, 8, 64));
    m = min(m, __shfl_xor(m, 16, 64));
    m = min(m, __shfl_xor(m, 32, 64));
    bool eq = (vh == m);
    unsigned long long bal = __ballot(eq);
    if (eq && ((bal & mylt) == 0)) {  // first owner pops
      sl[s] = ((vh & 255) << 4) + colsplit;
      vh = h1; h1 = h2; h2 = h3; h3 = h4; h4 = h5; h5 = h6; h6 = h7;
      h7 = 0x7fffffff;
    }
  }

  // stage 3: lane pair (s, s+32) computes candidate s's exact fp64 dot,
  // 32 dims each, combined via shfl_xor(32).
  int ci = sl[lane & 31];
  int half = lane >> 5;
  const f32x4* cr = (const f32x4*)(xt + (bbase + ci) * 64) + half * 8;
  const f32x4* qr = (const f32x4*)qs[wave] + half * 8;
  double a0 = 0.0, a1 = 0.0, a2 = 0.0, a3 = 0.0;
#pragma unroll
  for (int t2 = 0; t2 < 8; ++t2) {
    f32x4 cv = cr[t2];
    f32x4 qv = qr[t2];
    a0 = fma((double)cv.x, (double)qv.x, a0);
    a1 = fma((double)cv.y, (double)qv.y, a1);
    a2 = fma((double)cv.z, (double)qv.z, a2);
    a3 = fma((double)cv.w, (double)qv.w, a3);
  }
  double dot = (a0 + a1) + (a2 + a3);
  dot += __shfl_xor(dot, 32, 64);
  double kv = 1e300;
  if (lane < 32) {
    double kd = fma(dot, -2.0, sqd[bbase + ci]) + 1024.0;
    kv = __longlong_as_double(
        (__double_as_longlong(kd) & ~0x1FFFLL) | (long long)ci);
    klds[wave][lane] = kv;
  }

  // stage 4: rank-count over 32 unique exact keys; store o[rank]=ci
  if (lane < 32) {
    const double* kl = klds[wave];
    int c0 = 0, c1 = 0, c2 = 0, c3 = 0;
#pragma unroll
    for (int t2 = 0; t2 < 32; t2 += 4) {
      c0 += (kl[t2] < kv) ? 1 : 0;
      c1 += (kl[t2 + 1] < kv) ? 1 : 0;
      c2 += (kl[t2 + 2] < kv) ? 1 : 0;
      c3 += (kl[t2 + 3] < kv) ? 1 : 0;
    }
    int rank = (c0 + c1) + (c2 + c3);
    if (rank < K_) idxf[(size_t)p * K_ + rank] = ci;
  }
}

// ---- Kernel 4: one WAVE per point. Lane (u=lane&15, jb=lane>>4); 5 rounds:
// lane loads 16B chunk u of neighbor jb+4r -> each 16-lane group reads a full
// 256B y1 row per instruction (no partial lines). max/min/sum/sumsq of the
// gathered y1 reduced across jb via shfl_xor(16,32); y2 applied once:
// max(h)=max(g)+y2, sum(h)=sum(g)+K*y2, sumsq(h)=sum(g^2)+2*y2*sum(g)+K*y2^2.
// 4 points per wave sequentially; BN sums -> LDS atomics -> 128 global/block.
__global__ __launch_bounds__(256) void stats_kernel(
    const float* __restrict__ y1, const float* __restrict__ y2,
    const int* __restrict__ idxf, float* __restrict__ maxh,
    float* __restrict__ minh, float* __restrict__ gsum,
    float* __restrict__ gsq) {
  __shared__ float lsum[64], lsq[64];
  int tid = threadIdx.x;
  if (tid < 64) { lsum[tid] = 0.f; lsq[tid] = 0.f; }
  __syncthreads();
  int wv = tid >> 6, lane = tid & 63;
  int u = lane & 15, jb = lane >> 4;
  int p0 = blockIdx.x * 16 + wv * 4;  // 16 contiguous points per block
  size_t nb = (size_t)((p0 >> 13) * N_);
  f32x4 css = {0.f, 0.f, 0.f, 0.f}, cqq = {0.f, 0.f, 0.f, 0.f};
#pragma unroll
  for (int it = 0; it < 4; ++it) {
    int p = p0 + it;
    int idxval = (lane < K_) ? idxf[(size_t)p * K_ + lane] : 0;
    int n0 = __shfl(idxval, jb, 64);
    int n1 = __shfl(idxval, jb + 4, 64);
    int n2 = __shfl(idxval, jb + 8, 64);
    int n3 = __shfl(idxval, jb + 12, 64);
    int n4 = __shfl(idxval, jb + 16, 64);
    f32x4 g0 = ((const f32x4*)(y1 + (nb + n0) * 64))[u];
    f32x4 g1 = ((const f32x4*)(y1 + (nb + n1) * 64))[u];
    f32x4 g2 = ((const f32x4*)(y1 + (nb + n2) * 64))[u];
    f32x4 g3 = ((const f32x4*)(y1 + (nb + n3) * 64))[u];
    f32x4 g4 = ((const f32x4*)(y1 + (nb + n4) * 64))[u];
    f32x4 mx = g0, mn = g0, sm = g0, s2 = g0 * g0;
    mx = max4(mx, g1); mn = min4(mn, g1); sm += g1; s2 += g1 * g1;
    mx = max4(mx, g2); mn = min4(mn, g2); sm += g2; s2 += g2 * g2;
    mx = max4(mx, g3); mn = min4(mn, g3); sm += g3; s2 += g3 * g3;
    mx = max4(mx, g4); mn = min4(mn, g4); sm += g4; s2 += g4 * g4;
#pragma unroll
    for (int c = 0; c < 4; ++c) {
      mx[c] = fmaxf(mx[c], __shfl_xor(mx[c], 16, 64));
      mx[c] = fmaxf(mx[c], __shfl_xor(mx[c], 32, 64));
      mn[c] = fminf(mn[c], __shfl_xor(mn[c], 16, 64));
      mn[c] = fminf(mn[c], __shfl_xor(mn[c], 32, 64));
      sm[c] += __shfl_xor(sm[c], 16, 64);
      sm[c] += __shfl_xor(sm[c], 32, 64);
      s2[c] += __shfl_xor(s2[c], 16, 64);
      s2[c] += __shfl_xor(s2[c], 32, 64);
    }
    if (jb == 0) {  // lanes 0..15: full 256B contiguous stores
      f32x4 y2c = ((const f32x4*)(y2 + (size_t)p * 64))[u];
      ((f32x4*)(maxh + (size_t)p * 64))[u] = mx + y2c;
      ((f32x4*)(minh + (size_t)p * 64))[u] = mn + y2c;
      css += sm + 20.0f * y2c;
      cqq += s2 + 2.0f * y2c * sm + 20.0f * y2c * y2c;
    }
  }
  if (jb == 0) {
#pragma unroll
    for (int c = 0; c < 4; ++c) {
      atomicAdd(&lsum[u * 4 + c], css[c]);
      atomicAdd(&lsq[u * 4 + c], cqq[c]);
    }
  }
  __syncthreads();
  if (tid < 64) {
    atomicAdd(&gsum[tid], lsum[tid]);
    atomicAdd(&gsq[tid], lsq[tid]);
  }
}

// ---- Kernel 5: affine + relu + max-over-k selection, transposed store ----
__global__ __launch_bounds__(256) void final_kernel(
    const float* __restrict__ maxh, const float* __restrict__ minh,
    const float* __restrict__ gsum, const float* __restrict__ gsq,
    const float* __restrict__ gamma, const float* __restrict__ beta,
    float* __restrict__ out) {
  __shared__ float sc[64], cc_[64];
  __shared__ float tile[64 * 65];
  int b = blockIdx.x >> 7;
  int n0 = (blockIdx.x & 127) * 64;
  int t = threadIdx.x;
  if (t < 64) {
    float mean = gsum[t] * (1.0f / CNT_TOTAL);
    float var = gsq[t] * (1.0f / CNT_TOTAL) - mean * mean;
    float s = gamma[t] * rsqrtf(var + BN_EPSF);
    sc[t] = s;
    cc_[t] = beta[t] - mean * s;
  }
  __syncthreads();
#pragma unroll
  for (int i = 0; i < 16; ++i) {
    int lin = i * 256 + t;
    int o = lin & 63, nl = lin >> 6;
    size_t off = ((size_t)(b * N_) + n0 + nl) * 64 + o;
    float s = sc[o];
    float v = (s >= 0.f) ? maxh[off] : minh[off];
    float val = fmaxf(fmaf(v, s, cc_[o]), 0.f);
    tile[o * 65 + nl] = val;
  }
  __syncthreads();
#pragma unroll
  for (int i = 0; i < 16; ++i) {
    int lin = i * 256 + t;
    int nl = lin & 63, o = lin >> 6;
    out[((size_t)(b * 64) + o) * N_ + n0 + nl] = tile[o * 65 + nl];
  }
}

extern "C" void kernel_launch(void* const* d_in, const int* in_sizes, int n_in,
                              void* d_out, int out_size, void* d_ws,
                              size_t ws_size, hipStream_t stream) {
  const float* x = (const float*)d_in[0];
  const float* W = (const float*)d_in[1];
  const float* gamma = (const float*)d_in[2];
  const float* beta = (const float*)d_in[3];
  float* out = (float*)d_out;

  char* ws = (char*)d_ws;
  size_t off = 0;
  auto alloc = [&](size_t bytes) {
    char* p = ws + off;
    off += (bytes + 255) & ~(size_t)255;
    return p;
  };
  float* xt = (float*)alloc((size_t)B_ * N_ * 64 * 4);
  _Float16* xt16 = (_Float16*)alloc((size_t)B_ * N_ * 64 * 2);
  float* y1 = (float*)alloc((size_t)B_ * N_ * 64 * 4);
  float* y2 = (float*)alloc((size_t)B_ * N_ * 64 * 4);
  float* sq = (float*)alloc((size_t)B_ * N_ * 4);
  double* sqd = (double*)alloc((size_t)B_ * N_ * 8);
  int* pidx = (int*)alloc((size_t)B_ * N_ * NCAND * 4);  // 67 MB
  float* maxh = (float*)alloc((size_t)B_ * N_ * 64 * 4);
  int* idxf = (int*)alloc((size_t)B_ * N_ * K_ * 4);
  float* gsum = (float*)alloc(256);
  float* gsq = (float*)alloc(256);
  // minh aliases pidx (pidx fully consumed by refine before stats runs)
  float* minh = (float*)pidx;

  hipMemsetAsync(gsum, 0, 256, stream);
  hipMemsetAsync(gsq, 0, 256, stream);

  prep_kernel<<<B_ * (N_ / 64), 256, 0, stream>>>(x, W, xt, xt16, sq, sqd,
                                                  y1, y2);
  knn_mfma_kernel<<<B_ * (N_ / 64) * NSPLIT, 256, 0, stream>>>(xt16, sq, pidx);
  refine_kernel<<<(B_ * N_) / 4, 256, 0, stream>>>(xt, sqd, pidx, idxf);
  stats_kernel<<<(B_ * N_) / 16, 256, 0, stream>>>(y1, y2, idxf, maxh, minh,
                                                   gsum, gsq);
  final_kernel<<<B_ * (N_ / 64), 256, 0, stream>>>(maxh, minh, gsum, gsq,
                                                   gamma, beta, out);
}

// Round 7
// 373.232 us; speedup vs baseline: 1.8145x; 1.0140x over previous
//
#include <hip/hip_runtime.h>

typedef _Float16 half8 __attribute__((ext_vector_type(8)));
typedef float f32x4 __attribute__((ext_vector_type(4)));

#define B_ 4
#define C_ 64
#define N_ 8192
#define K_ 20
#define LCELL 8                   // per-(split,class) sorted list depth
#define NSPLIT 4
#define NCAND (16 * LCELL * NSPLIT)  // 512 candidates per query into refine
#define CNT_TOTAL (B_ * N_ * K_)  // 655360
#define BN_EPSF 1e-5f

__device__ __forceinline__ f32x4 max4(f32x4 a, f32x4 b) {
  f32x4 r;
  r.x = fmaxf(a.x, b.x); r.y = fmaxf(a.y, b.y);
  r.z = fmaxf(a.z, b.z); r.w = fmaxf(a.w, b.w);
  return r;
}
__device__ __forceinline__ f32x4 min4(f32x4 a, f32x4 b) {
  f32x4 r;
  r.x = fminf(a.x, b.x); r.y = fminf(a.y, b.y);
  r.z = fminf(a.z, b.z); r.w = fminf(a.w, b.w);
  return r;
}

// ---- Kernel 1: transpose x -> xt (f32 + f16), per-point sq (f32+f64),
// y1 = xt*W1^T, y2 = xt*W2^T - y1. W row o==lane held in 128 VGPRs.
// sq is stored PRE-BIASED by +512 (knn key bias folded in; refine uses sqd).
__global__ __launch_bounds__(256) void prep_kernel(
    const float* __restrict__ x, const float* __restrict__ W,
    float* __restrict__ xt, _Float16* __restrict__ xt16,
    float* __restrict__ sq, double* __restrict__ sqd,
    float* __restrict__ y1, float* __restrict__ y2) {
  __shared__ float xs[64 * 68];  // [n][c], stride 68 (16B-aligned rows)
  int b = blockIdx.x >> 7;
  int n0 = (blockIdx.x & 127) * 64;
  int t = threadIdx.x;
  int lane = t & 63;
  int wv = t >> 6;
#pragma unroll
  for (int i = 0; i < 16; ++i) {
    int lin = i * 256 + t;
    int c = lin >> 6, j = lin & 63;
    xs[j * 68 + c] = x[((b * 64 + c) * N_) + n0 + j];
  }
  // W row o = lane into registers (L1/L2-hot, 32 KB total)
  float4 w1[16], w2[16];
  const float4* wr = (const float4*)(W + lane * 128);
#pragma unroll
  for (int u = 0; u < 16; ++u) {
    w1[u] = wr[u];
    w2[u] = wr[16 + u];
  }
  __syncthreads();
#pragma unroll 2
  for (int i = 0; i < 16; ++i) {
    int nl = i * 4 + wv;
    const float4* xr = (const float4*)&xs[nl * 68];
    float d1 = 0.f, d2 = 0.f;
#pragma unroll
    for (int u = 0; u < 16; ++u) {
      float4 xv = xr[u];
      d1 = fmaf(xv.x, w1[u].x, d1); d1 = fmaf(xv.y, w1[u].y, d1);
      d1 = fmaf(xv.z, w1[u].z, d1); d1 = fmaf(xv.w, w1[u].w, d1);
      d2 = fmaf(xv.x, w2[u].x, d2); d2 = fmaf(xv.y, w2[u].y, d2);
      d2 = fmaf(xv.z, w2[u].z, d2); d2 = fmaf(xv.w, w2[u].w, d2);
    }
    int n = n0 + nl;
    y1[((b * N_) + n) * 64 + lane] = d1;
    y2[((b * N_) + n) * 64 + lane] = d2 - d1;
  }
#pragma unroll
  for (int i = 0; i < 16; ++i) {
    int lin = i * 256 + t;
    int c = lin & 63, nl = lin >> 6;
    float v = xs[nl * 68 + c];
    size_t o = ((size_t)(b * N_) + n0 + nl) * 64 + c;
    xt[o] = v;
    xt16[o] = (_Float16)v;
  }
  if (t < 64) {
    float s = 0.f;
    double sd = 0.0;
#pragma unroll
    for (int c = 0; c < 64; ++c) {
      float v = xs[t * 68 + c];
      s = fmaf(v, v, s);
      sd = fma((double)v, (double)v, sd);
    }
    sq[b * N_ + n0 + t] = s + 512.0f;  // pre-biased for knn key
    sqd[b * N_ + n0 + t] = sd;
  }
}

// ---- Kernel 2: MFMA distance scan, LDS-staged v5 (unchanged from R6).
// VALU-throughput-bound per R5/R6 A/B: duration = totalVALU/busy; grid and
// occupancy changes are neutral. Cooperative reg->LDS staging of 64-cand
// chunks, double-buffered; consume path pure LDS (ds_read_b128 + MFMA +
// pair-merge insert). Packed value: (float_bits(sq512-2dot)&~255)|tile(7b).
__global__ __launch_bounds__(256, 4) void knn_mfma_kernel(
    const _Float16* __restrict__ xt16, const float* __restrict__ sq,
    int* __restrict__ pidx) {
  __shared__ alignas(16) char bufB[2][9216];  // 4 tiles * 16 rows * 144B
  __shared__ float bufS[2][64];
  int t = threadIdx.x;
  int wave = t >> 6;
  int lane = t & 63;
  int col = lane & 15;
  int quad = lane >> 4;
  int blk = blockIdx.x;
  int split = blk & 3;
  int qt = (blk >> 2) & 127;
  int b = blk >> 9;
  int q0 = qt * 64 + wave * 16;
  size_t bbase = (size_t)b * N_;

  // A fragments: A[m=col][k=quad*8+j] -> query row q0+col
  const _Float16* arow = xt16 + (bbase + q0 + col) * 64;
  half8 A0 = *(const half8*)(arow + quad * 8);
  half8 A1 = *(const half8*)(arow + 32 + quad * 8);

  int dl[4][LCELL];
#pragma unroll
  for (int r = 0; r < 4; ++r)
#pragma unroll
    for (int j = 0; j < LCELL; ++j) dl[r][j] = 0x7fffffff;

#define PAIR_INSERT(accX, accY, sA, sB, CTB)                                 \
  {                                                                          \
    const int ctb_ = (CTB);                                                  \
    _Pragma("unroll") for (int r = 0; r < 4; ++r) {                          \
      float kA = fmaf((accX)[r], -2.0f, (sA));                               \
      float kB = fmaf((accY)[r], -2.0f, (sB));                               \
      int va = (__float_as_int(kA) & ~255) | ctb_;                           \
      int vb = (__float_as_int(kB) & ~255) | (ctb_ + 1);                     \
      int lo = min(va, vb), hi = max(va, vb);                                \
      int o0 = min(dl[r][0], lo);                                            \
      int o1 = min(min(dl[r][1], max(dl[r][0], lo)), hi);                    \
      int o2 = min(min(dl[r][2], max(dl[r][1], lo)), max(dl[r][0], hi));     \
      int o3 = min(min(dl[r][3], max(dl[r][2], lo)), max(dl[r][1], hi));     \
      int o4 = min(min(dl[r][4], max(dl[r][3], lo)), max(dl[r][2], hi));     \
      int o5 = min(min(dl[r][5], max(dl[r][4], lo)), max(dl[r][3], hi));     \
      int o6 = min(min(dl[r][6], max(dl[r][5], lo)), max(dl[r][4], hi));     \
      int o7 = min(min(dl[r][7], max(dl[r][6], lo)), max(dl[r][5], hi));     \
      dl[r][0] = o0; dl[r][1] = o1; dl[r][2] = o2; dl[r][3] = o3;            \
      dl[r][4] = o4; dl[r][5] = o5; dl[r][6] = o6; dl[r][7] = o7;            \
    }                                                                        \
  }

  int c0 = split * (N_ / NSPLIT);
  const _Float16* gpanel = xt16 + (bbase + c0) * 64;
  const float* spanel = sq + bbase + c0;

  int r0 = lane >> 3, e0 = lane & 7;  // lane's staged (row, 16B-chunk)

  int4 rA0, rA1, rB0, rB1;
  float sA = 0.f, sB = 0.f;

#define LOADR(Ra, Rb, Sv, CH)                                              \
  {                                                                        \
    const _Float16* gt = gpanel + ((size_t)(CH)*64 + wave * 16) * 64;      \
    Ra = *(const int4*)(gt + lane * 8);                                    \
    Rb = *(const int4*)(gt + 512 + lane * 8);                              \
    Sv = spanel[(CH)*64 + wave * 16 + col];                                \
  }
#define WRITEB(BUF, Ra, Rb, Sv)                                            \
  {                                                                        \
    char* lt = &bufB[BUF][wave * 2304];                                    \
    *(int4*)(lt + r0 * 144 + e0 * 16) = Ra;                                \
    *(int4*)(lt + (r0 + 8) * 144 + e0 * 16) = Rb;                          \
    if (lane < 16) bufS[BUF][wave * 16 + lane] = Sv;                       \
  }
#define CONSUME(BUF, CH)                                                   \
  {                                                                        \
    const char* lb = bufB[BUF];                                            \
    const float* sb = bufS[BUF];                                           \
    const f32x4 z = {0.f, 0.f, 0.f, 0.f};                                  \
    half8 F0 = *(const half8*)(lb + 0 * 2304 + col * 144 + quad * 16);     \
    half8 F1 = *(const half8*)(lb + 0 * 2304 + col * 144 + (4 + quad) * 16); \
    half8 G0 = *(const half8*)(lb + 1 * 2304 + col * 144 + quad * 16);     \
    half8 G1 = *(const half8*)(lb + 1 * 2304 + col * 144 + (4 + quad) * 16); \
    f32x4 a0 = __builtin_amdgcn_mfma_f32_16x16x32_f16(A0, F0, z, 0, 0, 0); \
    a0 = __builtin_amdgcn_mfma_f32_16x16x32_f16(A1, F1, a0, 0, 0, 0);      \
    f32x4 a1 = __builtin_amdgcn_mfma_f32_16x16x32_f16(A0, G0, z, 0, 0, 0); \
    a1 = __builtin_amdgcn_mfma_f32_16x16x32_f16(A1, G1, a1, 0, 0, 0);      \
    half8 H0 = *(const half8*)(lb + 2 * 2304 + col * 144 + quad * 16);     \
    half8 H1 = *(const half8*)(lb + 2 * 2304 + col * 144 + (4 + quad) * 16); \
    half8 I0 = *(const half8*)(lb + 3 * 2304 + col * 144 + quad * 16);     \
    half8 I1 = *(const half8*)(lb + 3 * 2304 + col * 144 + (4 + quad) * 16); \
    f32x4 a2 = __builtin_amdgcn_mfma_f32_16x16x32_f16(A0, H0, z, 0, 0, 0); \
    a2 = __builtin_amdgcn_mfma_f32_16x16x32_f16(A1, H1, a2, 0, 0, 0);      \
    f32x4 a3 = __builtin_amdgcn_mfma_f32_16x16x32_f16(A0, I0, z, 0, 0, 0); \
    a3 = __builtin_amdgcn_mfma_f32_16x16x32_f16(A1, I1, a3, 0, 0, 0);      \
    float s0 = sb[col], s1 = sb[16 + col];                                 \
    float s2 = sb[32 + col], s3 = sb[48 + col];                            \
    PAIR_INSERT(a0, a1, s0, s1, (CH)*4);                                   \
    PAIR_INSERT(a2, a3, s2, s3, (CH)*4 + 2);                               \
  }

  // prologue: chunk0 -> buf0, chunk1 -> regs
  LOADR(rA0, rA1, sA, 0);
  LOADR(rB0, rB1, sB, 1);
  WRITEB(0, rA0, rA1, sA);
  __syncthreads();

  for (int ch = 0; ch < 32; ch += 2) {
    if (ch + 2 < 32) LOADR(rA0, rA1, sA, ch + 2);
    WRITEB(1, rB0, rB1, sB);
    CONSUME(0, ch);
    __syncthreads();
    if (ch + 3 < 32) LOADR(rB0, rB1, sB, ch + 3);
    if (ch + 2 < 32) WRITEB(0, rA0, rA1, sA);
    CONSUME(1, ch + 1);
    __syncthreads();
  }
#undef PAIR_INSERT
#undef LOADR
#undef WRITEB
#undef CONSUME

#pragma unroll
  for (int r = 0; r < 4; ++r) {
    int q = q0 + quad * 4 + r;
    int* o = pidx + (bbase + q) * NCAND + split * (16 * LCELL) + col * LCELL;
#pragma unroll
    for (int j = 0; j < LCELL; ++j) o[j] = dl[r][j];  // raw packed value
  }
}

// ---- Kernel 3: refinement v10 — TWO points per wave (ILP vs latency).
// R4 profile: VALUBusy 34%, MFMA 0, HBM 2% -> the 32 sequential pop-min
// steps (6-deep shfl chains, ~200cy exposed latency each) dominate. v10
// interleaves two INDEPENDENT pop chains (points pA, pB) in one wave: B's
// butterfly issues while A's is in flight -> exposed latency ~halves, and
// wave count halves. Stage 3 now uses all 64 lanes (lane<32 -> A cand,
// lane>=32 -> B cand, full 64-dim fp64 dot each). Stage 4 rank-count per
// half. Semantics per point identical to v9 (fp64 key + idx tie-break).
__global__ __launch_bounds__(256) void refine_kernel(
    const float* __restrict__ xt, const double* __restrict__ sqd,
    const int* __restrict__ pidx, int* __restrict__ idxf) {
  __shared__ float qs[4][2][64];
  __shared__ int slds[4][2][32];
  __shared__ double klds[4][2][32];
  int tid = threadIdx.x;
  int wave = tid >> 6, lane = tid & 63;
  int pA = blockIdx.x * 8 + wave * 2;  // even global point id
  int pB = pA + 1;
  int b = pA >> 13;  // pA,pB share batch (8-aligned block of points)
  size_t bbase = (size_t)b * N_;
  int plA = pA & (N_ - 1), plB = pB & (N_ - 1);

  // stage both query rows into LDS (lanes 0..15 -> A, 16..31 -> B)
  if (lane < 16) {
    ((f32x4*)qs[wave][0])[lane] = ((const f32x4*)(xt + (size_t)pA * 64))[lane];
  } else if (lane < 32) {
    int l = lane - 16;
    ((f32x4*)qs[wave][1])[l] = ((const f32x4*)(xt + (size_t)pB * 64))[l];
  }

  // stage 1: lane's cell (split=lane>>4, col=lane&15): 8 sorted values per
  // point. Self-exclude (single displacement -> one bubble pass each).
  const int* piA = pidx + (size_t)pA * NCAND + lane * 8;
  const int* piB = pidx + (size_t)pB * NCAND + lane * 8;
  int4 ca0 = *(const int4*)piA;
  int4 ca1 = *(const int4*)(piA + 4);
  int4 cb0 = *(const int4*)piB;
  int4 cb1 = *(const int4*)(piB + 4);
  int colsplit = (lane & 15) + (lane >> 4) * (N_ / NSPLIT);

  int uA0 = ca0.x, uA1 = ca0.y, uA2 = ca0.z, uA3 = ca0.w;
  int uA4 = ca1.x, uA5 = ca1.y, uA6 = ca1.z, uA7 = ca1.w;
  int uB0 = cb0.x, uB1 = cb0.y, uB2 = cb0.z, uB3 = cb0.w;
  int uB4 = cb1.x, uB5 = cb1.y, uB6 = cb1.z, uB7 = cb1.w;
#define EXCL(v, pl) if (((((v)&255) << 4) + colsplit) == (pl)) (v) = 0x7fffffff;
  EXCL(uA0, plA) EXCL(uA1, plA) EXCL(uA2, plA) EXCL(uA3, plA)
  EXCL(uA4, plA) EXCL(uA5, plA) EXCL(uA6, plA) EXCL(uA7, plA)
  EXCL(uB0, plB) EXCL(uB1, plB) EXCL(uB2, plB) EXCL(uB3, plB)
  EXCL(uB4, plB) EXCL(uB5, plB) EXCL(uB6, plB) EXCL(uB7, plB)
#undef EXCL
#define BUB(a, b_) { int lo_ = min(a, b_), hi_ = max(a, b_); a = lo_; b_ = hi_; }
  BUB(uA0, uA1) BUB(uA1, uA2) BUB(uA2, uA3) BUB(uA3, uA4)
  BUB(uA4, uA5) BUB(uA5, uA6) BUB(uA6, uA7)
  BUB(uB0, uB1) BUB(uB1, uB2) BUB(uB2, uB3) BUB(uB3, uB4)
  BUB(uB4, uB5) BUB(uB5, uB6) BUB(uB6, uB7)
#undef BUB

  // stage 2: 32 pops per chain, interleaved (independent -> ILP)
  unsigned long long mylt = (1ull << lane) - 1;
  int* slA = slds[wave][0];
  int* slB = slds[wave][1];
#pragma unroll
  for (int s = 0; s < 32; ++s) {
    int mA = uA0, mB = uB0;
    mA = min(mA, __shfl_xor(mA, 1, 64));
    mB = min(mB, __shfl_xor(mB, 1, 64));
    mA = min(mA, __shfl_xor(mA, 2, 64));
    mB = min(mB, __shfl_xor(mB, 2, 64));
    mA = min(mA, __shfl_xor(mA, 4, 64));
    mB = min(mB, __shfl_xor(mB, 4, 64));
    mA = min(mA, __shfl_xor(mA, 8, 64));
    mB = min(mB, __shfl_xor(mB, 8, 64));
    mA = min(mA, __shfl_xor(mA, 16, 64));
    mB = min(mB, __shfl_xor(mB, 16, 64));
    mA = min(mA, __shfl_xor(mA, 32, 64));
    mB = min(mB, __shfl_xor(mB, 32, 64));
    bool eqA = (uA0 == mA);
    bool eqB = (uB0 == mB);
    unsigned long long balA = __ballot(eqA);
    unsigned long long balB = __ballot(eqB);
    if (eqA && ((balA & mylt) == 0)) {  // first owner pops chain A
      slA[s] = ((uA0 & 255) << 4) + colsplit;
      uA0 = uA1; uA1 = uA2; uA2 = uA3; uA3 = uA4; uA4 = uA5; uA5 = uA6;
      uA6 = uA7; uA7 = 0x7fffffff;
    }
    if (eqB && ((balB & mylt) == 0)) {  // first owner pops chain B
      slB[s] = ((uB0 & 255) << 4) + colsplit;
      uB0 = uB1; uB1 = uB2; uB2 = uB3; uB3 = uB4; uB4 = uB5; uB5 = uB6;
      uB6 = uB7; uB7 = 0x7fffffff;
    }
  }

  // stage 3: lane<32 -> point A candidate lane; lane>=32 -> point B
  // candidate lane-32. Full 64-dim fp64 dot per lane (4 accums).
  int half = lane >> 5;
  int s32 = lane & 31;
  int ci = slds[wave][half][s32];
  const f32x4* cr = (const f32x4*)(xt + (bbase + ci) * 64);
  const f32x4* qr = (const f32x4*)qs[wave][half];
  double a0 = 0.0, a1 = 0.0, a2 = 0.0, a3 = 0.0;
#pragma unroll
  for (int t2 = 0; t2 < 16; ++t2) {
    f32x4 cv = cr[t2];
    f32x4 qv = qr[t2];  // ds_read_b128 broadcast within each half
    a0 = fma((double)cv.x, (double)qv.x, a0);
    a1 = fma((double)cv.y, (double)qv.y, a1);
    a2 = fma((double)cv.z, (double)qv.z, a2);
    a3 = fma((double)cv.w, (double)qv.w, a3);
  }
  double dot = (a0 + a1) + (a2 + a3);
  double kd = fma(dot, -2.0, sqd[bbase + ci]) + 1024.0;
  double kv = __longlong_as_double(
      (__double_as_longlong(kd) & ~0x1FFFLL) | (long long)ci);
  klds[wave][half][s32] = kv;

  // stage 4: rank-count over own half's 32 unique exact keys
  {
    const double* kl = klds[wave][half];
    int c0 = 0, c1 = 0, c2 = 0, c3 = 0;
#pragma unroll
    for (int t2 = 0; t2 < 32; t2 += 4) {
      c0 += (kl[t2] < kv) ? 1 : 0;
      c1 += (kl[t2 + 1] < kv) ? 1 : 0;
      c2 += (kl[t2 + 2] < kv) ? 1 : 0;
      c3 += (kl[t2 + 3] < kv) ? 1 : 0;
    }
    int rank = (c0 + c1) + (c2 + c3);
    int pdst = half ? pB : pA;
    if (rank < K_) idxf[(size_t)pdst * K_ + rank] = ci;
  }
}

// ---- Kernel 4: one WAVE per point. Lane (u=lane&15, jb=lane>>4); 5 rounds:
// lane loads 16B chunk u of neighbor jb+4r -> each 16-lane group reads a full
// 256B y1 row per instruction (no partial lines). max/min/sum/sumsq of the
// gathered y1 reduced across jb via shfl_xor(16,32); y2 applied once:
// max(h)=max(g)+y2, sum(h)=sum(g)+K*y2, sumsq(h)=sum(g^2)+2*y2*sum(g)+K*y2^2.
// 4 points per wave sequentially; BN sums -> LDS atomics -> 128 global/block.
__global__ __launch_bounds__(256) void stats_kernel(
    const float* __restrict__ y1, const float* __restrict__ y2,
    const int* __restrict__ idxf, float* __restrict__ maxh,
    float* __restrict__ minh, float* __restrict__ gsum,
    float* __restrict__ gsq) {
  __shared__ float lsum[64], lsq[64];
  int tid = threadIdx.x;
  if (tid < 64) { lsum[tid] = 0.f; lsq[tid] = 0.f; }
  __syncthreads();
  int wv = tid >> 6, lane = tid & 63;
  int u = lane & 15, jb = lane >> 4;
  int p0 = blockIdx.x * 16 + wv * 4;  // 16 contiguous points per block
  size_t nb = (size_t)((p0 >> 13) * N_);
  f32x4 css = {0.f, 0.f, 0.f, 0.f}, cqq = {0.f, 0.f, 0.f, 0.f};
#pragma unroll
  for (int it = 0; it < 4; ++it) {
    int p = p0 + it;
    int idxval = (lane < K_) ? idxf[(size_t)p * K_ + lane] : 0;
    int n0 = __shfl(idxval, jb, 64);
    int n1 = __shfl(idxval, jb + 4, 64);
    int n2 = __shfl(idxval, jb + 8, 64);
    int n3 = __shfl(idxval, jb + 12, 64);
    int n4 = __shfl(idxval, jb + 16, 64);
    f32x4 g0 = ((const f32x4*)(y1 + (nb + n0) * 64))[u];
    f32x4 g1 = ((const f32x4*)(y1 + (nb + n1) * 64))[u];
    f32x4 g2 = ((const f32x4*)(y1 + (nb + n2) * 64))[u];
    f32x4 g3 = ((const f32x4*)(y1 + (nb + n3) * 64))[u];
    f32x4 g4 = ((const f32x4*)(y1 + (nb + n4) * 64))[u];
    f32x4 mx = g0, mn = g0, sm = g0, s2 = g0 * g0;
    mx = max4(mx, g1); mn = min4(mn, g1); sm += g1; s2 += g1 * g1;
    mx = max4(mx, g2); mn = min4(mn, g2); sm += g2; s2 += g2 * g2;
    mx = max4(mx, g3); mn = min4(mn, g3); sm += g3; s2 += g3 * g3;
    mx = max4(mx, g4); mn = min4(mn, g4); sm += g4; s2 += g4 * g4;
#pragma unroll
    for (int c = 0; c < 4; ++c) {
      mx[c] = fmaxf(mx[c], __shfl_xor(mx[c], 16, 64));
      mx[c] = fmaxf(mx[c], __shfl_xor(mx[c], 32, 64));
      mn[c] = fminf(mn[c], __shfl_xor(mn[c], 16, 64));
      mn[c] = fminf(mn[c], __shfl_xor(mn[c], 32, 64));
      sm[c] += __shfl_xor(sm[c], 16, 64);
      sm[c] += __shfl_xor(sm[c], 32, 64);
      s2[c] += __shfl_xor(s2[c], 16, 64);
      s2[c] += __shfl_xor(s2[c], 32, 64);
    }
    if (jb == 0) {  // lanes 0..15: full 256B contiguous stores
      f32x4 y2c = ((const f32x4*)(y2 + (size_t)p * 64))[u];
      ((f32x4*)(maxh + (size_t)p * 64))[u] = mx + y2c;
      ((f32x4*)(minh + (size_t)p * 64))[u] = mn + y2c;
      css += sm + 20.0f * y2c;
      cqq += s2 + 2.0f * y2c * sm + 20.0f * y2c * y2c;
    }
  }
  if (jb == 0) {
#pragma unroll
    for (int c = 0; c < 4; ++c) {
      atomicAdd(&lsum[u * 4 + c], css[c]);
      atomicAdd(&lsq[u * 4 + c], cqq[c]);
    }
  }
  __syncthreads();
  if (tid < 64) {
    atomicAdd(&gsum[tid], lsum[tid]);
    atomicAdd(&gsq[tid], lsq[tid]);
  }
}

// ---- Kernel 5: affine + relu + max-over-k selection, transposed store ----
__global__ __launch_bounds__(256) void final_kernel(
    const float* __restrict__ maxh, const float* __restrict__ minh,
    const float* __restrict__ gsum, const float* __restrict__ gsq,
    const float* __restrict__ gamma, const float* __restrict__ beta,
    float* __restrict__ out) {
  __shared__ float sc[64], cc_[64];
  __shared__ float tile[64 * 65];
  int b = blockIdx.x >> 7;
  int n0 = (blockIdx.x & 127) * 64;
  int t = threadIdx.x;
  if (t < 64) {
    float mean = gsum[t] * (1.0f / CNT_TOTAL);
    float var = gsq[t] * (1.0f / CNT_TOTAL) - mean * mean;
    float s = gamma[t] * rsqrtf(var + BN_EPSF);
    sc[t] = s;
    cc_[t] = beta[t] - mean * s;
  }
  __syncthreads();
#pragma unroll
  for (int i = 0; i < 16; ++i) {
    int lin = i * 256 + t;
    int o = lin & 63, nl = lin >> 6;
    size_t off = ((size_t)(b * N_) + n0 + nl) * 64 + o;
    float s = sc[o];
    float v = (s >= 0.f) ? maxh[off] : minh[off];
    float val = fmaxf(fmaf(v, s, cc_[o]), 0.f);
    tile[o * 65 + nl] = val;
  }
  __syncthreads();
#pragma unroll
  for (int i = 0; i < 16; ++i) {
    int lin = i * 256 + t;
    int nl = lin & 63, o = lin >> 6;
    out[((size_t)(b * 64) + o) * N_ + n0 + nl] = tile[o * 65 + nl];
  }
}

extern "C" void kernel_launch(void* const* d_in, const int* in_sizes, int n_in,
                              void* d_out, int out_size, void* d_ws,
                              size_t ws_size, hipStream_t stream) {
  const float* x = (const float*)d_in[0];
  const float* W = (const float*)d_in[1];
  const float* gamma = (const float*)d_in[2];
  const float* beta = (const float*)d_in[3];
  float* out = (float*)d_out;

  char* ws = (char*)d_ws;
  size_t off = 0;
  auto alloc = [&](size_t bytes) {
    char* p = ws + off;
    off += (bytes + 255) & ~(size_t)255;
    return p;
  };
  float* xt = (float*)alloc((size_t)B_ * N_ * 64 * 4);
  _Float16* xt16 = (_Float16*)alloc((size_t)B_ * N_ * 64 * 2);
  float* y1 = (float*)alloc((size_t)B_ * N_ * 64 * 4);
  float* y2 = (float*)alloc((size_t)B_ * N_ * 64 * 4);
  float* sq = (float*)alloc((size_t)B_ * N_ * 4);
  double* sqd = (double*)alloc((size_t)B_ * N_ * 8);
  int* pidx = (int*)alloc((size_t)B_ * N_ * NCAND * 4);  // 67 MB
  float* maxh = (float*)alloc((size_t)B_ * N_ * 64 * 4);
  int* idxf = (int*)alloc((size_t)B_ * N_ * K_ * 4);
  float* gsum = (float*)alloc(256);
  float* gsq = (float*)alloc(256);
  // minh aliases pidx (pidx fully consumed by refine before stats runs)
  float* minh = (float*)pidx;

  hipMemsetAsync(gsum, 0, 256, stream);
  hipMemsetAsync(gsq, 0, 256, stream);

  prep_kernel<<<B_ * (N_ / 64), 256, 0, stream>>>(x, W, xt, xt16, sq, sqd,
                                                  y1, y2);
  knn_mfma_kernel<<<B_ * (N_ / 64) * NSPLIT, 256, 0, stream>>>(xt16, sq, pidx);
  refine_kernel<<<(B_ * N_) / 8, 256, 0, stream>>>(xt, sqd, pidx, idxf);
  stats_kernel<<<(B_ * N_) / 16, 256, 0, stream>>>(y1, y2, idxf, maxh, minh,
                                                   gsum, gsq);
  final_kernel<<<B_ * (N_ / 64), 256, 0, stream>>>(maxh, minh, gsum, gsq,
                                                   gamma, beta, out);
}

// Round 8
// 357.431 us; speedup vs baseline: 1.8948x; 1.0442x over previous
//
#include <hip/hip_runtime.h>

typedef _Float16 half8 __attribute__((ext_vector_type(8)));
typedef float f32x4 __attribute__((ext_vector_type(4)));

#define B_ 4
#define C_ 64
#define N_ 8192
#define K_ 20
#define LCELL 8                   // per-(split,class) sorted list depth
#define NSPLIT 4
#define NCAND (16 * LCELL * NSPLIT)  // 512 candidates per query into refine
#define CNT_TOTAL (B_ * N_ * K_)  // 655360
#define BN_EPSF 1e-5f

__device__ __forceinline__ f32x4 max4(f32x4 a, f32x4 b) {
  f32x4 r;
  r.x = fmaxf(a.x, b.x); r.y = fmaxf(a.y, b.y);
  r.z = fmaxf(a.z, b.z); r.w = fmaxf(a.w, b.w);
  return r;
}
__device__ __forceinline__ f32x4 min4(f32x4 a, f32x4 b) {
  f32x4 r;
  r.x = fminf(a.x, b.x); r.y = fminf(a.y, b.y);
  r.z = fminf(a.z, b.z); r.w = fminf(a.w, b.w);
  return r;
}

// wave-wide i32 min: 4x DPP row_ror (VALU, no DS pipe) + ds_swizzle xor16 +
// shfl_xor 32. Chain latency ~half of the 6-deep ds_bpermute butterfly.
__device__ __forceinline__ int wave_min_i32(int m) {
  m = min(m, __builtin_amdgcn_update_dpp(m, m, 0x121, 0xf, 0xf, true));
  m = min(m, __builtin_amdgcn_update_dpp(m, m, 0x122, 0xf, 0xf, true));
  m = min(m, __builtin_amdgcn_update_dpp(m, m, 0x124, 0xf, 0xf, true));
  m = min(m, __builtin_amdgcn_update_dpp(m, m, 0x128, 0xf, 0xf, true));
  m = min(m, __builtin_amdgcn_ds_swizzle(m, 0x401F));  // xor 16
  m = min(m, __shfl_xor(m, 32, 64));                   // xor 32
  return m;
}

// ---- Kernel 1: transpose x -> xt (f32 + f16), per-point sq (f32+f64),
// y1 = xt*W1^T, y2 = xt*W2^T - y1. W row o==lane held in 128 VGPRs.
// sq is stored PRE-BIASED by +512 (knn key bias folded in; refine uses sqd).
__global__ __launch_bounds__(256) void prep_kernel(
    const float* __restrict__ x, const float* __restrict__ W,
    float* __restrict__ xt, _Float16* __restrict__ xt16,
    float* __restrict__ sq, double* __restrict__ sqd,
    float* __restrict__ y1, float* __restrict__ y2) {
  __shared__ float xs[64 * 68];  // [n][c], stride 68 (16B-aligned rows)
  int b = blockIdx.x >> 7;
  int n0 = (blockIdx.x & 127) * 64;
  int t = threadIdx.x;
  int lane = t & 63;
  int wv = t >> 6;
#pragma unroll
  for (int i = 0; i < 16; ++i) {
    int lin = i * 256 + t;
    int c = lin >> 6, j = lin & 63;
    xs[j * 68 + c] = x[((b * 64 + c) * N_) + n0 + j];
  }
  // W row o = lane into registers (L1/L2-hot, 32 KB total)
  float4 w1[16], w2[16];
  const float4* wr = (const float4*)(W + lane * 128);
#pragma unroll
  for (int u = 0; u < 16; ++u) {
    w1[u] = wr[u];
    w2[u] = wr[16 + u];
  }
  __syncthreads();
#pragma unroll 2
  for (int i = 0; i < 16; ++i) {
    int nl = i * 4 + wv;
    const float4* xr = (const float4*)&xs[nl * 68];
    float d1 = 0.f, d2 = 0.f;
#pragma unroll
    for (int u = 0; u < 16; ++u) {
      float4 xv = xr[u];
      d1 = fmaf(xv.x, w1[u].x, d1); d1 = fmaf(xv.y, w1[u].y, d1);
      d1 = fmaf(xv.z, w1[u].z, d1); d1 = fmaf(xv.w, w1[u].w, d1);
      d2 = fmaf(xv.x, w2[u].x, d2); d2 = fmaf(xv.y, w2[u].y, d2);
      d2 = fmaf(xv.z, w2[u].z, d2); d2 = fmaf(xv.w, w2[u].w, d2);
    }
    int n = n0 + nl;
    y1[((b * N_) + n) * 64 + lane] = d1;
    y2[((b * N_) + n) * 64 + lane] = d2 - d1;
  }
#pragma unroll
  for (int i = 0; i < 16; ++i) {
    int lin = i * 256 + t;
    int c = lin & 63, nl = lin >> 6;
    float v = xs[nl * 68 + c];
    size_t o = ((size_t)(b * N_) + n0 + nl) * 64 + c;
    xt[o] = v;
    xt16[o] = (_Float16)v;
  }
  if (t < 64) {
    float s = 0.f;
    double sd = 0.0;
#pragma unroll
    for (int c = 0; c < 64; ++c) {
      float v = xs[t * 68 + c];
      s = fmaf(v, v, s);
      sd = fma((double)v, (double)v, sd);
    }
    sq[b * N_ + n0 + t] = s + 512.0f;  // pre-biased for knn key
    sqd[b * N_ + n0 + t] = sd;
  }
}

// ---- Kernel 2: MFMA distance scan, LDS-staged v6 = v5 + insert-skip guard.
// Per row r, the 21-op merge network is skipped when min(va,vb) >= dl[r][7]
// (no list change possible). Saving is wave-granular (s_cbranch_execz):
// P(all 64 lanes skip) ~ e^(-1024/t) -> ~25-30% of inserts skipped in the
// scan's second half. Otherwise identical to R6's VALU-bound structure.
__global__ __launch_bounds__(256, 4) void knn_mfma_kernel(
    const _Float16* __restrict__ xt16, const float* __restrict__ sq,
    int* __restrict__ pidx) {
  __shared__ alignas(16) char bufB[2][9216];  // 4 tiles * 16 rows * 144B
  __shared__ float bufS[2][64];
  int t = threadIdx.x;
  int wave = t >> 6;
  int lane = t & 63;
  int col = lane & 15;
  int quad = lane >> 4;
  int blk = blockIdx.x;
  int split = blk & 3;
  int qt = (blk >> 2) & 127;
  int b = blk >> 9;
  int q0 = qt * 64 + wave * 16;
  size_t bbase = (size_t)b * N_;

  // A fragments: A[m=col][k=quad*8+j] -> query row q0+col
  const _Float16* arow = xt16 + (bbase + q0 + col) * 64;
  half8 A0 = *(const half8*)(arow + quad * 8);
  half8 A1 = *(const half8*)(arow + 32 + quad * 8);

  int dl[4][LCELL];
#pragma unroll
  for (int r = 0; r < 4; ++r)
#pragma unroll
    for (int j = 0; j < LCELL; ++j) dl[r][j] = 0x7fffffff;

#define PAIR_INSERT(accX, accY, sA, sB, CTB)                                 \
  {                                                                          \
    const int ctb_ = (CTB);                                                  \
    _Pragma("unroll") for (int r = 0; r < 4; ++r) {                          \
      float kA = fmaf((accX)[r], -2.0f, (sA));                               \
      float kB = fmaf((accY)[r], -2.0f, (sB));                               \
      int va = (__float_as_int(kA) & ~255) | ctb_;                           \
      int vb = (__float_as_int(kB) & ~255) | (ctb_ + 1);                     \
      int lo = min(va, vb), hi = max(va, vb);                                \
      if (lo < dl[r][7]) {                                                   \
        int o0 = min(dl[r][0], lo);                                          \
        int o1 = min(min(dl[r][1], max(dl[r][0], lo)), hi);                  \
        int o2 = min(min(dl[r][2], max(dl[r][1], lo)), max(dl[r][0], hi));   \
        int o3 = min(min(dl[r][3], max(dl[r][2], lo)), max(dl[r][1], hi));   \
        int o4 = min(min(dl[r][4], max(dl[r][3], lo)), max(dl[r][2], hi));   \
        int o5 = min(min(dl[r][5], max(dl[r][4], lo)), max(dl[r][3], hi));   \
        int o6 = min(min(dl[r][6], max(dl[r][5], lo)), max(dl[r][4], hi));   \
        int o7 = min(min(dl[r][7], max(dl[r][6], lo)), max(dl[r][5], hi));   \
        dl[r][0] = o0; dl[r][1] = o1; dl[r][2] = o2; dl[r][3] = o3;          \
        dl[r][4] = o4; dl[r][5] = o5; dl[r][6] = o6; dl[r][7] = o7;          \
      }                                                                      \
    }                                                                        \
  }

  int c0 = split * (N_ / NSPLIT);
  const _Float16* gpanel = xt16 + (bbase + c0) * 64;
  const float* spanel = sq + bbase + c0;

  int r0 = lane >> 3, e0 = lane & 7;  // lane's staged (row, 16B-chunk)

  int4 rA0, rA1, rB0, rB1;
  float sA = 0.f, sB = 0.f;

#define LOADR(Ra, Rb, Sv, CH)                                              \
  {                                                                        \
    const _Float16* gt = gpanel + ((size_t)(CH)*64 + wave * 16) * 64;      \
    Ra = *(const int4*)(gt + lane * 8);                                    \
    Rb = *(const int4*)(gt + 512 + lane * 8);                              \
    Sv = spanel[(CH)*64 + wave * 16 + col];                                \
  }
#define WRITEB(BUF, Ra, Rb, Sv)                                            \
  {                                                                        \
    char* lt = &bufB[BUF][wave * 2304];                                    \
    *(int4*)(lt + r0 * 144 + e0 * 16) = Ra;                                \
    *(int4*)(lt + (r0 + 8) * 144 + e0 * 16) = Rb;                          \
    if (lane < 16) bufS[BUF][wave * 16 + lane] = Sv;                       \
  }
#define CONSUME(BUF, CH)                                                   \
  {                                                                        \
    const char* lb = bufB[BUF];                                            \
    const float* sb = bufS[BUF];                                           \
    const f32x4 z = {0.f, 0.f, 0.f, 0.f};                                  \
    half8 F0 = *(const half8*)(lb + 0 * 2304 + col * 144 + quad * 16);     \
    half8 F1 = *(const half8*)(lb + 0 * 2304 + col * 144 + (4 + quad) * 16); \
    half8 G0 = *(const half8*)(lb + 1 * 2304 + col * 144 + quad * 16);     \
    half8 G1 = *(const half8*)(lb + 1 * 2304 + col * 144 + (4 + quad) * 16); \
    f32x4 a0 = __builtin_amdgcn_mfma_f32_16x16x32_f16(A0, F0, z, 0, 0, 0); \
    a0 = __builtin_amdgcn_mfma_f32_16x16x32_f16(A1, F1, a0, 0, 0, 0);      \
    f32x4 a1 = __builtin_amdgcn_mfma_f32_16x16x32_f16(A0, G0, z, 0, 0, 0); \
    a1 = __builtin_amdgcn_mfma_f32_16x16x32_f16(A1, G1, a1, 0, 0, 0);      \
    half8 H0 = *(const half8*)(lb + 2 * 2304 + col * 144 + quad * 16);     \
    half8 H1 = *(const half8*)(lb + 2 * 2304 + col * 144 + (4 + quad) * 16); \
    half8 I0 = *(const half8*)(lb + 3 * 2304 + col * 144 + quad * 16);     \
    half8 I1 = *(const half8*)(lb + 3 * 2304 + col * 144 + (4 + quad) * 16); \
    f32x4 a2 = __builtin_amdgcn_mfma_f32_16x16x32_f16(A0, H0, z, 0, 0, 0); \
    a2 = __builtin_amdgcn_mfma_f32_16x16x32_f16(A1, H1, a2, 0, 0, 0);      \
    f32x4 a3 = __builtin_amdgcn_mfma_f32_16x16x32_f16(A0, I0, z, 0, 0, 0); \
    a3 = __builtin_amdgcn_mfma_f32_16x16x32_f16(A1, I1, a3, 0, 0, 0);      \
    float s0 = sb[col], s1 = sb[16 + col];                                 \
    float s2 = sb[32 + col], s3 = sb[48 + col];                            \
    PAIR_INSERT(a0, a1, s0, s1, (CH)*4);                                   \
    PAIR_INSERT(a2, a3, s2, s3, (CH)*4 + 2);                               \
  }

  // prologue: chunk0 -> buf0, chunk1 -> regs
  LOADR(rA0, rA1, sA, 0);
  LOADR(rB0, rB1, sB, 1);
  WRITEB(0, rA0, rA1, sA);
  __syncthreads();

  for (int ch = 0; ch < 32; ch += 2) {
    if (ch + 2 < 32) LOADR(rA0, rA1, sA, ch + 2);
    WRITEB(1, rB0, rB1, sB);
    CONSUME(0, ch);
    __syncthreads();
    if (ch + 3 < 32) LOADR(rB0, rB1, sB, ch + 3);
    if (ch + 2 < 32) WRITEB(0, rA0, rA1, sA);
    CONSUME(1, ch + 1);
    __syncthreads();
  }
#undef PAIR_INSERT
#undef LOADR
#undef WRITEB
#undef CONSUME

#pragma unroll
  for (int r = 0; r < 4; ++r) {
    int q = q0 + quad * 4 + r;
    int* o = pidx + (bbase + q) * NCAND + split * (16 * LCELL) + col * LCELL;
#pragma unroll
    for (int j = 0; j < LCELL; ++j) o[j] = dl[r][j];  // raw packed value
  }
}

// ---- Kernel 3: refinement v11 — short-chain pops. Two points per wave.
// v8-v10 ablations: DS-count 3x cut (null), load 2x (null), 2-chain ILP
// (-5us) -> bottleneck is the pop's dependent 6-deep ds_bpermute chain plus
// the divergent LDS-write blocks that serialize the two chains. v11:
// (a) min-reduce via 4x DPP row_ror (VALU, ~4cy fwd) + ds_swizzle(xor16) +
// shfl_xor(32): chain ~half the latency, 6->2 DS ops; (b) slds ELIMINATED:
// owner's colsplit is a pure function of its lane id, so every lane decodes
// the popped ci from ballot (ctz) and lane s / s+32 captures it in a
// register — no divergent write block between the A and B chains, so they
// truly interleave. Stages 1/3/4 unchanged from v10.
__global__ __launch_bounds__(256) void refine_kernel(
    const float* __restrict__ xt, const double* __restrict__ sqd,
    const int* __restrict__ pidx, int* __restrict__ idxf) {
  __shared__ float qs[4][2][64];
  __shared__ double klds[4][2][32];
  int tid = threadIdx.x;
  int wave = tid >> 6, lane = tid & 63;
  int pA = blockIdx.x * 8 + wave * 2;  // even global point id
  int pB = pA + 1;
  int b = pA >> 13;  // pA,pB share batch (8-aligned block of points)
  size_t bbase = (size_t)b * N_;
  int plA = pA & (N_ - 1), plB = pB & (N_ - 1);

  // stage both query rows into LDS (lanes 0..15 -> A, 16..31 -> B)
  if (lane < 16) {
    ((f32x4*)qs[wave][0])[lane] = ((const f32x4*)(xt + (size_t)pA * 64))[lane];
  } else if (lane < 32) {
    int l = lane - 16;
    ((f32x4*)qs[wave][1])[l] = ((const f32x4*)(xt + (size_t)pB * 64))[l];
  }

  // stage 1: lane's cell (split=lane>>4, col=lane&15): 8 sorted values per
  // point. Self-exclude (single displacement -> one bubble pass each).
  const int* piA = pidx + (size_t)pA * NCAND + lane * 8;
  const int* piB = pidx + (size_t)pB * NCAND + lane * 8;
  int4 ca0 = *(const int4*)piA;
  int4 ca1 = *(const int4*)(piA + 4);
  int4 cb0 = *(const int4*)piB;
  int4 cb1 = *(const int4*)(piB + 4);
  int colsplit = (lane & 15) + (lane >> 4) * (N_ / NSPLIT);

  int uA0 = ca0.x, uA1 = ca0.y, uA2 = ca0.z, uA3 = ca0.w;
  int uA4 = ca1.x, uA5 = ca1.y, uA6 = ca1.z, uA7 = ca1.w;
  int uB0 = cb0.x, uB1 = cb0.y, uB2 = cb0.z, uB3 = cb0.w;
  int uB4 = cb1.x, uB5 = cb1.y, uB6 = cb1.z, uB7 = cb1.w;
#define EXCL(v, pl) if (((((v)&255) << 4) + colsplit) == (pl)) (v) = 0x7fffffff;
  EXCL(uA0, plA) EXCL(uA1, plA) EXCL(uA2, plA) EXCL(uA3, plA)
  EXCL(uA4, plA) EXCL(uA5, plA) EXCL(uA6, plA) EXCL(uA7, plA)
  EXCL(uB0, plB) EXCL(uB1, plB) EXCL(uB2, plB) EXCL(uB3, plB)
  EXCL(uB4, plB) EXCL(uB5, plB) EXCL(uB6, plB) EXCL(uB7, plB)
#undef EXCL
#define BUB(a, b_) { int lo_ = min(a, b_), hi_ = max(a, b_); a = lo_; b_ = hi_; }
  BUB(uA0, uA1) BUB(uA1, uA2) BUB(uA2, uA3) BUB(uA3, uA4)
  BUB(uA4, uA5) BUB(uA5, uA6) BUB(uA6, uA7)
  BUB(uB0, uB1) BUB(uB1, uB2) BUB(uB2, uB3) BUB(uB3, uB4)
  BUB(uB4, uB5) BUB(uB5, uB6) BUB(uB6, uB7)
#undef BUB

  // stage 2: 32 pops per chain, interleaved; ci decoded from ballot (no LDS)
  unsigned long long mylt = (1ull << lane) - 1;
  int myci = 0;
#pragma unroll
  for (int s = 0; s < 32; ++s) {
    int mA = wave_min_i32(uA0);
    int mB = wave_min_i32(uB0);
    bool eqA = (uA0 == mA);
    bool eqB = (uB0 == mB);
    unsigned long long balA = __ballot(eqA);
    unsigned long long balB = __ballot(eqB);
    int ownA = (int)__builtin_ctzll(balA);
    int ownB = (int)__builtin_ctzll(balB);
    int ciA = ((mA & 255) << 4) + (ownA & 15) + (ownA >> 4) * (N_ / NSPLIT);
    int ciB = ((mB & 255) << 4) + (ownB & 15) + (ownB >> 4) * (N_ / NSPLIT);
    if (lane == s) myci = ciA;
    if (lane == s + 32) myci = ciB;
    bool advA = eqA && ((balA & mylt) == 0);  // first owner pops chain A
    bool advB = eqB && ((balB & mylt) == 0);
    uA0 = advA ? uA1 : uA0; uA1 = advA ? uA2 : uA1;
    uA2 = advA ? uA3 : uA2; uA3 = advA ? uA4 : uA3;
    uA4 = advA ? uA5 : uA4; uA5 = advA ? uA6 : uA5;
    uA6 = advA ? uA7 : uA6; uA7 = advA ? 0x7fffffff : uA7;
    uB0 = advB ? uB1 : uB0; uB1 = advB ? uB2 : uB1;
    uB2 = advB ? uB3 : uB2; uB3 = advB ? uB4 : uB3;
    uB4 = advB ? uB5 : uB4; uB5 = advB ? uB6 : uB5;
    uB6 = advB ? uB7 : uB6; uB7 = advB ? 0x7fffffff : uB7;
  }

  // stage 3: lane<32 -> point A candidate lane; lane>=32 -> point B
  // candidate lane-32. Full 64-dim fp64 dot per lane (4 accums).
  int half = lane >> 5;
  int s32 = lane & 31;
  int ci = myci;
  const f32x4* cr = (const f32x4*)(xt + (bbase + ci) * 64);
  const f32x4* qr = (const f32x4*)qs[wave][half];
  double a0 = 0.0, a1 = 0.0, a2 = 0.0, a3 = 0.0;
#pragma unroll
  for (int t2 = 0; t2 < 16; ++t2) {
    f32x4 cv = cr[t2];
    f32x4 qv = qr[t2];  // ds_read_b128 broadcast within each half
    a0 = fma((double)cv.x, (double)qv.x, a0);
    a1 = fma((double)cv.y, (double)qv.y, a1);
    a2 = fma((double)cv.z, (double)qv.z, a2);
    a3 = fma((double)cv.w, (double)qv.w, a3);
  }
  double dot = (a0 + a1) + (a2 + a3);
  double kd = fma(dot, -2.0, sqd[bbase + ci]) + 1024.0;
  double kv = __longlong_as_double(
      (__double_as_longlong(kd) & ~0x1FFFLL) | (long long)ci);
  klds[wave][half][s32] = kv;

  // stage 4: rank-count over own half's 32 unique exact keys
  {
    const double* kl = klds[wave][half];
    int c0 = 0, c1 = 0, c2 = 0, c3 = 0;
#pragma unroll
    for (int t2 = 0; t2 < 32; t2 += 4) {
      c0 += (kl[t2] < kv) ? 1 : 0;
      c1 += (kl[t2 + 1] < kv) ? 1 : 0;
      c2 += (kl[t2 + 2] < kv) ? 1 : 0;
      c3 += (kl[t2 + 3] < kv) ? 1 : 0;
    }
    int rank = (c0 + c1) + (c2 + c3);
    int pdst = half ? pB : pA;
    if (rank < K_) idxf[(size_t)pdst * K_ + rank] = ci;
  }
}

// ---- Kernel 4: one WAVE per point. Lane (u=lane&15, jb=lane>>4); 5 rounds:
// lane loads 16B chunk u of neighbor jb+4r -> each 16-lane group reads a full
// 256B y1 row per instruction (no partial lines). max/min/sum/sumsq of the
// gathered y1 reduced across jb via shfl_xor(16,32); y2 applied once:
// max(h)=max(g)+y2, sum(h)=sum(g)+K*y2, sumsq(h)=sum(g^2)+2*y2*sum(g)+K*y2^2.
// 4 points per wave sequentially; BN sums -> LDS atomics -> 128 global/block.
__global__ __launch_bounds__(256) void stats_kernel(
    const float* __restrict__ y1, const float* __restrict__ y2,
    const int* __restrict__ idxf, float* __restrict__ maxh,
    float* __restrict__ minh, float* __restrict__ gsum,
    float* __restrict__ gsq) {
  __shared__ float lsum[64], lsq[64];
  int tid = threadIdx.x;
  if (tid < 64) { lsum[tid] = 0.f; lsq[tid] = 0.f; }
  __syncthreads();
  int wv = tid >> 6, lane = tid & 63;
  int u = lane & 15, jb = lane >> 4;
  int p0 = blockIdx.x * 16 + wv * 4;  // 16 contiguous points per block
  size_t nb = (size_t)((p0 >> 13) * N_);
  f32x4 css = {0.f, 0.f, 0.f, 0.f}, cqq = {0.f, 0.f, 0.f, 0.f};
#pragma unroll
  for (int it = 0; it < 4; ++it) {
    int p = p0 + it;
    int idxval = (lane < K_) ? idxf[(size_t)p * K_ + lane] : 0;
    int n0 = __shfl(idxval, jb, 64);
    int n1 = __shfl(idxval, jb + 4, 64);
    int n2 = __shfl(idxval, jb + 8, 64);
    int n3 = __shfl(idxval, jb + 12, 64);
    int n4 = __shfl(idxval, jb + 16, 64);
    f32x4 g0 = ((const f32x4*)(y1 + (nb + n0) * 64))[u];
    f32x4 g1 = ((const f32x4*)(y1 + (nb + n1) * 64))[u];
    f32x4 g2 = ((const f32x4*)(y1 + (nb + n2) * 64))[u];
    f32x4 g3 = ((const f32x4*)(y1 + (nb + n3) * 64))[u];
    f32x4 g4 = ((const f32x4*)(y1 + (nb + n4) * 64))[u];
    f32x4 mx = g0, mn = g0, sm = g0, s2 = g0 * g0;
    mx = max4(mx, g1); mn = min4(mn, g1); sm += g1; s2 += g1 * g1;
    mx = max4(mx, g2); mn = min4(mn, g2); sm += g2; s2 += g2 * g2;
    mx = max4(mx, g3); mn = min4(mn, g3); sm += g3; s2 += g3 * g3;
    mx = max4(mx, g4); mn = min4(mn, g4); sm += g4; s2 += g4 * g4;
#pragma unroll
    for (int c = 0; c < 4; ++c) {
      mx[c] = fmaxf(mx[c], __shfl_xor(mx[c], 16, 64));
      mx[c] = fmaxf(mx[c], __shfl_xor(mx[c], 32, 64));
      mn[c] = fminf(mn[c], __shfl_xor(mn[c], 16, 64));
      mn[c] = fminf(mn[c], __shfl_xor(mn[c], 32, 64));
      sm[c] += __shfl_xor(sm[c], 16, 64);
      sm[c] += __shfl_xor(sm[c], 32, 64);
      s2[c] += __shfl_xor(s2[c], 16, 64);
      s2[c] += __shfl_xor(s2[c], 32, 64);
    }
    if (jb == 0) {  // lanes 0..15: full 256B contiguous stores
      f32x4 y2c = ((const f32x4*)(y2 + (size_t)p * 64))[u];
      ((f32x4*)(maxh + (size_t)p * 64))[u] = mx + y2c;
      ((f32x4*)(minh + (size_t)p * 64))[u] = mn + y2c;
      css += sm + 20.0f * y2c;
      cqq += s2 + 2.0f * y2c * sm + 20.0f * y2c * y2c;
    }
  }
  if (jb == 0) {
#pragma unroll
    for (int c = 0; c < 4; ++c) {
      atomicAdd(&lsum[u * 4 + c], css[c]);
      atomicAdd(&lsq[u * 4 + c], cqq[c]);
    }
  }
  __syncthreads();
  if (tid < 64) {
    atomicAdd(&gsum[tid], lsum[tid]);
    atomicAdd(&gsq[tid], lsq[tid]);
  }
}

// ---- Kernel 5: affine + relu + max-over-k selection, transposed store ----
__global__ __launch_bounds__(256) void final_kernel(
    const float* __restrict__ maxh, const float* __restrict__ minh,
    const float* __restrict__ gsum, const float* __restrict__ gsq,
    const float* __restrict__ gamma, const float* __restrict__ beta,
    float* __restrict__ out) {
  __shared__ float sc[64], cc_[64];
  __shared__ float tile[64 * 65];
  int b = blockIdx.x >> 7;
  int n0 = (blockIdx.x & 127) * 64;
  int t = threadIdx.x;
  if (t < 64) {
    float mean = gsum[t] * (1.0f / CNT_TOTAL);
    float var = gsq[t] * (1.0f / CNT_TOTAL) - mean * mean;
    float s = gamma[t] * rsqrtf(var + BN_EPSF);
    sc[t] = s;
    cc_[t] = beta[t] - mean * s;
  }
  __syncthreads();
#pragma unroll
  for (int i = 0; i < 16; ++i) {
    int lin = i * 256 + t;
    int o = lin & 63, nl = lin >> 6;
    size_t off = ((size_t)(b * N_) + n0 + nl) * 64 + o;
    float s = sc[o];
    float v = (s >= 0.f) ? maxh[off] : minh[off];
    float val = fmaxf(fmaf(v, s, cc_[o]), 0.f);
    tile[o * 65 + nl] = val;
  }
  __syncthreads();
#pragma unroll
  for (int i = 0; i < 16; ++i) {
    int lin = i * 256 + t;
    int nl = lin & 63, o = lin >> 6;
    out[((size_t)(b * 64) + o) * N_ + n0 + nl] = tile[o * 65 + nl];
  }
}

extern "C" void kernel_launch(void* const* d_in, const int* in_sizes, int n_in,
                              void* d_out, int out_size, void* d_ws,
                              size_t ws_size, hipStream_t stream) {
  const float* x = (const float*)d_in[0];
  const float* W = (const float*)d_in[1];
  const float* gamma = (const float*)d_in[2];
  const float* beta = (const float*)d_in[3];
  float* out = (float*)d_out;

  char* ws = (char*)d_ws;
  size_t off = 0;
  auto alloc = [&](size_t bytes) {
    char* p = ws + off;
    off += (bytes + 255) & ~(size_t)255;
    return p;
  };
  float* xt = (float*)alloc((size_t)B_ * N_ * 64 * 4);
  _Float16* xt16 = (_Float16*)alloc((size_t)B_ * N_ * 64 * 2);
  float* y1 = (float*)alloc((size_t)B_ * N_ * 64 * 4);
  float* y2 = (float*)alloc((size_t)B_ * N_ * 64 * 4);
  float* sq = (float*)alloc((size_t)B_ * N_ * 4);
  double* sqd = (double*)alloc((size_t)B_ * N_ * 8);
  int* pidx = (int*)alloc((size_t)B_ * N_ * NCAND * 4);  // 67 MB
  float* maxh = (float*)alloc((size_t)B_ * N_ * 64 * 4);
  int* idxf = (int*)alloc((size_t)B_ * N_ * K_ * 4);
  float* gsum = (float*)alloc(256);
  float* gsq = (float*)alloc(256);
  // minh aliases pidx (pidx fully consumed by refine before stats runs)
  float* minh = (float*)pidx;

  hipMemsetAsync(gsum, 0, 256, stream);
  hipMemsetAsync(gsq, 0, 256, stream);

  prep_kernel<<<B_ * (N_ / 64), 256, 0, stream>>>(x, W, xt, xt16, sq, sqd,
                                                  y1, y2);
  knn_mfma_kernel<<<B_ * (N_ / 64) * NSPLIT, 256, 0, stream>>>(xt16, sq, pidx);
  refine_kernel<<<(B_ * N_) / 8, 256, 0, stream>>>(xt, sqd, pidx, idxf);
  stats_kernel<<<(B_ * N_) / 16, 256, 0, stream>>>(y1, y2, idxf, maxh, minh,
                                                   gsum, gsq);
  final_kernel<<<B_ * (N_ / 64), 256, 0, stream>>>(maxh, minh, gsum, gsq,
                                                   gamma, beta, out);
}

// Round 9
// 344.136 us; speedup vs baseline: 1.9680x; 1.0386x over previous
//
#include <hip/hip_runtime.h>

typedef _Float16 half8 __attribute__((ext_vector_type(8)));
typedef float f32x4 __attribute__((ext_vector_type(4)));

#define B_ 4
#define C_ 64
#define N_ 8192
#define K_ 20
#define LCELL 8                   // per-(split,class) sorted list depth
#define NSPLIT 4
#define NCAND (16 * LCELL * NSPLIT)  // 512 candidates per query into refine
#define CNT_TOTAL (B_ * N_ * K_)  // 655360
#define BN_EPSF 1e-5f

__device__ __forceinline__ f32x4 max4(f32x4 a, f32x4 b) {
  f32x4 r;
  r.x = fmaxf(a.x, b.x); r.y = fmaxf(a.y, b.y);
  r.z = fmaxf(a.z, b.z); r.w = fmaxf(a.w, b.w);
  return r;
}
__device__ __forceinline__ f32x4 min4(f32x4 a, f32x4 b) {
  f32x4 r;
  r.x = fminf(a.x, b.x); r.y = fminf(a.y, b.y);
  r.z = fminf(a.z, b.z); r.w = fminf(a.w, b.w);
  return r;
}

// wave-wide i32 min: 4x DPP row_ror (VALU, no DS pipe) + ds_swizzle xor16 +
// shfl_xor 32. Chain latency ~half of the 6-deep ds_bpermute butterfly.
__device__ __forceinline__ int wave_min_i32(int m) {
  m = min(m, __builtin_amdgcn_update_dpp(m, m, 0x121, 0xf, 0xf, true));
  m = min(m, __builtin_amdgcn_update_dpp(m, m, 0x122, 0xf, 0xf, true));
  m = min(m, __builtin_amdgcn_update_dpp(m, m, 0x124, 0xf, 0xf, true));
  m = min(m, __builtin_amdgcn_update_dpp(m, m, 0x128, 0xf, 0xf, true));
  m = min(m, __builtin_amdgcn_ds_swizzle(m, 0x401F));  // xor 16
  m = min(m, __shfl_xor(m, 32, 64));                   // xor 32
  return m;
}

// ---- Kernel 1: transpose x -> xt (f32 + f16), per-point sq (f32+f64),
// y1 = xt*W1^T, y2 = xt*W2^T - y1. W row o==lane held in 128 VGPRs.
// sq is stored PRE-BIASED by +512 (knn key bias folded in; refine uses sqd).
__global__ __launch_bounds__(256) void prep_kernel(
    const float* __restrict__ x, const float* __restrict__ W,
    float* __restrict__ xt, _Float16* __restrict__ xt16,
    float* __restrict__ sq, double* __restrict__ sqd,
    float* __restrict__ y1, float* __restrict__ y2) {
  __shared__ float xs[64 * 68];  // [n][c], stride 68 (16B-aligned rows)
  int b = blockIdx.x >> 7;
  int n0 = (blockIdx.x & 127) * 64;
  int t = threadIdx.x;
  int lane = t & 63;
  int wv = t >> 6;
#pragma unroll
  for (int i = 0; i < 16; ++i) {
    int lin = i * 256 + t;
    int c = lin >> 6, j = lin & 63;
    xs[j * 68 + c] = x[((b * 64 + c) * N_) + n0 + j];
  }
  // W row o = lane into registers (L1/L2-hot, 32 KB total)
  float4 w1[16], w2[16];
  const float4* wr = (const float4*)(W + lane * 128);
#pragma unroll
  for (int u = 0; u < 16; ++u) {
    w1[u] = wr[u];
    w2[u] = wr[16 + u];
  }
  __syncthreads();
#pragma unroll 2
  for (int i = 0; i < 16; ++i) {
    int nl = i * 4 + wv;
    const float4* xr = (const float4*)&xs[nl * 68];
    float d1 = 0.f, d2 = 0.f;
#pragma unroll
    for (int u = 0; u < 16; ++u) {
      float4 xv = xr[u];
      d1 = fmaf(xv.x, w1[u].x, d1); d1 = fmaf(xv.y, w1[u].y, d1);
      d1 = fmaf(xv.z, w1[u].z, d1); d1 = fmaf(xv.w, w1[u].w, d1);
      d2 = fmaf(xv.x, w2[u].x, d2); d2 = fmaf(xv.y, w2[u].y, d2);
      d2 = fmaf(xv.z, w2[u].z, d2); d2 = fmaf(xv.w, w2[u].w, d2);
    }
    int n = n0 + nl;
    y1[((b * N_) + n) * 64 + lane] = d1;
    y2[((b * N_) + n) * 64 + lane] = d2 - d1;
  }
#pragma unroll
  for (int i = 0; i < 16; ++i) {
    int lin = i * 256 + t;
    int c = lin & 63, nl = lin >> 6;
    float v = xs[nl * 68 + c];
    size_t o = ((size_t)(b * N_) + n0 + nl) * 64 + c;
    xt[o] = v;
    xt16[o] = (_Float16)v;
  }
  if (t < 64) {
    float s = 0.f;
    double sd = 0.0;
#pragma unroll
    for (int c = 0; c < 64; ++c) {
      float v = xs[t * 68 + c];
      s = fmaf(v, v, s);
      sd = fma((double)v, (double)v, sd);
    }
    sq[b * N_ + n0 + t] = s + 512.0f;  // pre-biased for knn key
    sqd[b * N_ + n0 + t] = sd;
  }
}

// ---- Kernel 2: MFMA distance scan, LDS-staged v5 (R6 form — the R8
// insert-skip guard REGRESSED +10us: VALUBusy 74->87% from guard overhead,
// skip probability (1-p)^64 too low with 256 independent lists/wave).
// Cooperative reg->LDS staging of 64-cand chunks, double-buffered; consume
// path pure LDS (ds_read_b128 + MFMA + pair-merge insert). Packed value:
// (float_bits(sq512-2dot)&~255)|tile(7b).
__global__ __launch_bounds__(256, 4) void knn_mfma_kernel(
    const _Float16* __restrict__ xt16, const float* __restrict__ sq,
    int* __restrict__ pidx) {
  __shared__ alignas(16) char bufB[2][9216];  // 4 tiles * 16 rows * 144B
  __shared__ float bufS[2][64];
  int t = threadIdx.x;
  int wave = t >> 6;
  int lane = t & 63;
  int col = lane & 15;
  int quad = lane >> 4;
  int blk = blockIdx.x;
  int split = blk & 3;
  int qt = (blk >> 2) & 127;
  int b = blk >> 9;
  int q0 = qt * 64 + wave * 16;
  size_t bbase = (size_t)b * N_;

  // A fragments: A[m=col][k=quad*8+j] -> query row q0+col
  const _Float16* arow = xt16 + (bbase + q0 + col) * 64;
  half8 A0 = *(const half8*)(arow + quad * 8);
  half8 A1 = *(const half8*)(arow + 32 + quad * 8);

  int dl[4][LCELL];
#pragma unroll
  for (int r = 0; r < 4; ++r)
#pragma unroll
    for (int j = 0; j < LCELL; ++j) dl[r][j] = 0x7fffffff;

#define PAIR_INSERT(accX, accY, sA, sB, CTB)                                 \
  {                                                                          \
    const int ctb_ = (CTB);                                                  \
    _Pragma("unroll") for (int r = 0; r < 4; ++r) {                          \
      float kA = fmaf((accX)[r], -2.0f, (sA));                               \
      float kB = fmaf((accY)[r], -2.0f, (sB));                               \
      int va = (__float_as_int(kA) & ~255) | ctb_;                           \
      int vb = (__float_as_int(kB) & ~255) | (ctb_ + 1);                     \
      int lo = min(va, vb), hi = max(va, vb);                                \
      int o0 = min(dl[r][0], lo);                                            \
      int o1 = min(min(dl[r][1], max(dl[r][0], lo)), hi);                    \
      int o2 = min(min(dl[r][2], max(dl[r][1], lo)), max(dl[r][0], hi));     \
      int o3 = min(min(dl[r][3], max(dl[r][2], lo)), max(dl[r][1], hi));     \
      int o4 = min(min(dl[r][4], max(dl[r][3], lo)), max(dl[r][2], hi));     \
      int o5 = min(min(dl[r][5], max(dl[r][4], lo)), max(dl[r][3], hi));     \
      int o6 = min(min(dl[r][6], max(dl[r][5], lo)), max(dl[r][4], hi));     \
      int o7 = min(min(dl[r][7], max(dl[r][6], lo)), max(dl[r][5], hi));     \
      dl[r][0] = o0; dl[r][1] = o1; dl[r][2] = o2; dl[r][3] = o3;            \
      dl[r][4] = o4; dl[r][5] = o5; dl[r][6] = o6; dl[r][7] = o7;            \
    }                                                                        \
  }

  int c0 = split * (N_ / NSPLIT);
  const _Float16* gpanel = xt16 + (bbase + c0) * 64;
  const float* spanel = sq + bbase + c0;

  int r0 = lane >> 3, e0 = lane & 7;  // lane's staged (row, 16B-chunk)

  int4 rA0, rA1, rB0, rB1;
  float sA = 0.f, sB = 0.f;

#define LOADR(Ra, Rb, Sv, CH)                                              \
  {                                                                        \
    const _Float16* gt = gpanel + ((size_t)(CH)*64 + wave * 16) * 64;      \
    Ra = *(const int4*)(gt + lane * 8);                                    \
    Rb = *(const int4*)(gt + 512 + lane * 8);                              \
    Sv = spanel[(CH)*64 + wave * 16 + col];                                \
  }
#define WRITEB(BUF, Ra, Rb, Sv)                                            \
  {                                                                        \
    char* lt = &bufB[BUF][wave * 2304];                                    \
    *(int4*)(lt + r0 * 144 + e0 * 16) = Ra;                                \
    *(int4*)(lt + (r0 + 8) * 144 + e0 * 16) = Rb;                          \
    if (lane < 16) bufS[BUF][wave * 16 + lane] = Sv;                       \
  }
#define CONSUME(BUF, CH)                                                   \
  {                                                                        \
    const char* lb = bufB[BUF];                                            \
    const float* sb = bufS[BUF];                                           \
    const f32x4 z = {0.f, 0.f, 0.f, 0.f};                                  \
    half8 F0 = *(const half8*)(lb + 0 * 2304 + col * 144 + quad * 16);     \
    half8 F1 = *(const half8*)(lb + 0 * 2304 + col * 144 + (4 + quad) * 16); \
    half8 G0 = *(const half8*)(lb + 1 * 2304 + col * 144 + quad * 16);     \
    half8 G1 = *(const half8*)(lb + 1 * 2304 + col * 144 + (4 + quad) * 16); \
    f32x4 a0 = __builtin_amdgcn_mfma_f32_16x16x32_f16(A0, F0, z, 0, 0, 0); \
    a0 = __builtin_amdgcn_mfma_f32_16x16x32_f16(A1, F1, a0, 0, 0, 0);      \
    f32x4 a1 = __builtin_amdgcn_mfma_f32_16x16x32_f16(A0, G0, z, 0, 0, 0); \
    a1 = __builtin_amdgcn_mfma_f32_16x16x32_f16(A1, G1, a1, 0, 0, 0);      \
    half8 H0 = *(const half8*)(lb + 2 * 2304 + col * 144 + quad * 16);     \
    half8 H1 = *(const half8*)(lb + 2 * 2304 + col * 144 + (4 + quad) * 16); \
    half8 I0 = *(const half8*)(lb + 3 * 2304 + col * 144 + quad * 16);     \
    half8 I1 = *(const half8*)(lb + 3 * 2304 + col * 144 + (4 + quad) * 16); \
    f32x4 a2 = __builtin_amdgcn_mfma_f32_16x16x32_f16(A0, H0, z, 0, 0, 0); \
    a2 = __builtin_amdgcn_mfma_f32_16x16x32_f16(A1, H1, a2, 0, 0, 0);      \
    f32x4 a3 = __builtin_amdgcn_mfma_f32_16x16x32_f16(A0, I0, z, 0, 0, 0); \
    a3 = __builtin_amdgcn_mfma_f32_16x16x32_f16(A1, I1, a3, 0, 0, 0);      \
    float s0 = sb[col], s1 = sb[16 + col];                                 \
    float s2 = sb[32 + col], s3 = sb[48 + col];                            \
    PAIR_INSERT(a0, a1, s0, s1, (CH)*4);                                   \
    PAIR_INSERT(a2, a3, s2, s3, (CH)*4 + 2);                               \
  }

  // prologue: chunk0 -> buf0, chunk1 -> regs
  LOADR(rA0, rA1, sA, 0);
  LOADR(rB0, rB1, sB, 1);
  WRITEB(0, rA0, rA1, sA);
  __syncthreads();

  for (int ch = 0; ch < 32; ch += 2) {
    if (ch + 2 < 32) LOADR(rA0, rA1, sA, ch + 2);
    WRITEB(1, rB0, rB1, sB);
    CONSUME(0, ch);
    __syncthreads();
    if (ch + 3 < 32) LOADR(rB0, rB1, sB, ch + 3);
    if (ch + 2 < 32) WRITEB(0, rA0, rA1, sA);
    CONSUME(1, ch + 1);
    __syncthreads();
  }
#undef PAIR_INSERT
#undef LOADR
#undef WRITEB
#undef CONSUME

#pragma unroll
  for (int r = 0; r < 4; ++r) {
    int q = q0 + quad * 4 + r;
    int* o = pidx + (bbase + q) * NCAND + split * (16 * LCELL) + col * LCELL;
#pragma unroll
    for (int j = 0; j < LCELL; ++j) o[j] = dl[r][j];  // raw packed value
  }
}

// ---- Kernel 3: refinement v11 (R8 WIN, unchanged) — short-chain pops,
// two points per wave, DPP min-reduce, ballot-decoded indices (no slds).
__global__ __launch_bounds__(256) void refine_kernel(
    const float* __restrict__ xt, const double* __restrict__ sqd,
    const int* __restrict__ pidx, int* __restrict__ idxf) {
  __shared__ float qs[4][2][64];
  __shared__ double klds[4][2][32];
  int tid = threadIdx.x;
  int wave = tid >> 6, lane = tid & 63;
  int pA = blockIdx.x * 8 + wave * 2;  // even global point id
  int pB = pA + 1;
  int b = pA >> 13;  // pA,pB share batch (8-aligned block of points)
  size_t bbase = (size_t)b * N_;
  int plA = pA & (N_ - 1), plB = pB & (N_ - 1);

  // stage both query rows into LDS (lanes 0..15 -> A, 16..31 -> B)
  if (lane < 16) {
    ((f32x4*)qs[wave][0])[lane] = ((const f32x4*)(xt + (size_t)pA * 64))[lane];
  } else if (lane < 32) {
    int l = lane - 16;
    ((f32x4*)qs[wave][1])[l] = ((const f32x4*)(xt + (size_t)pB * 64))[l];
  }

  // stage 1: lane's cell (split=lane>>4, col=lane&15): 8 sorted values per
  // point. Self-exclude (single displacement -> one bubble pass each).
  const int* piA = pidx + (size_t)pA * NCAND + lane * 8;
  const int* piB = pidx + (size_t)pB * NCAND + lane * 8;
  int4 ca0 = *(const int4*)piA;
  int4 ca1 = *(const int4*)(piA + 4);
  int4 cb0 = *(const int4*)piB;
  int4 cb1 = *(const int4*)(piB + 4);
  int colsplit = (lane & 15) + (lane >> 4) * (N_ / NSPLIT);

  int uA0 = ca0.x, uA1 = ca0.y, uA2 = ca0.z, uA3 = ca0.w;
  int uA4 = ca1.x, uA5 = ca1.y, uA6 = ca1.z, uA7 = ca1.w;
  int uB0 = cb0.x, uB1 = cb0.y, uB2 = cb0.z, uB3 = cb0.w;
  int uB4 = cb1.x, uB5 = cb1.y, uB6 = cb1.z, uB7 = cb1.w;
#define EXCL(v, pl) if (((((v)&255) << 4) + colsplit) == (pl)) (v) = 0x7fffffff;
  EXCL(uA0, plA) EXCL(uA1, plA) EXCL(uA2, plA) EXCL(uA3, plA)
  EXCL(uA4, plA) EXCL(uA5, plA) EXCL(uA6, plA) EXCL(uA7, plA)
  EXCL(uB0, plB) EXCL(uB1, plB) EXCL(uB2, plB) EXCL(uB3, plB)
  EXCL(uB4, plB) EXCL(uB5, plB) EXCL(uB6, plB) EXCL(uB7, plB)
#undef EXCL
#define BUB(a, b_) { int lo_ = min(a, b_), hi_ = max(a, b_); a = lo_; b_ = hi_; }
  BUB(uA0, uA1) BUB(uA1, uA2) BUB(uA2, uA3) BUB(uA3, uA4)
  BUB(uA4, uA5) BUB(uA5, uA6) BUB(uA6, uA7)
  BUB(uB0, uB1) BUB(uB1, uB2) BUB(uB2, uB3) BUB(uB3, uB4)
  BUB(uB4, uB5) BUB(uB5, uB6) BUB(uB6, uB7)
#undef BUB

  // stage 2: 32 pops per chain, interleaved; ci decoded from ballot (no LDS)
  unsigned long long mylt = (1ull << lane) - 1;
  int myci = 0;
#pragma unroll
  for (int s = 0; s < 32; ++s) {
    int mA = wave_min_i32(uA0);
    int mB = wave_min_i32(uB0);
    bool eqA = (uA0 == mA);
    bool eqB = (uB0 == mB);
    unsigned long long balA = __ballot(eqA);
    unsigned long long balB = __ballot(eqB);
    int ownA = (int)__builtin_ctzll(balA);
    int ownB = (int)__builtin_ctzll(balB);
    int ciA = ((mA & 255) << 4) + (ownA & 15) + (ownA >> 4) * (N_ / NSPLIT);
    int ciB = ((mB & 255) << 4) + (ownB & 15) + (ownB >> 4) * (N_ / NSPLIT);
    if (lane == s) myci = ciA;
    if (lane == s + 32) myci = ciB;
    bool advA = eqA && ((balA & mylt) == 0);  // first owner pops chain A
    bool advB = eqB && ((balB & mylt) == 0);
    uA0 = advA ? uA1 : uA0; uA1 = advA ? uA2 : uA1;
    uA2 = advA ? uA3 : uA2; uA3 = advA ? uA4 : uA3;
    uA4 = advA ? uA5 : uA4; uA5 = advA ? uA6 : uA5;
    uA6 = advA ? uA7 : uA6; uA7 = advA ? 0x7fffffff : uA7;
    uB0 = advB ? uB1 : uB0; uB1 = advB ? uB2 : uB1;
    uB2 = advB ? uB3 : uB2; uB3 = advB ? uB4 : uB3;
    uB4 = advB ? uB5 : uB4; uB5 = advB ? uB6 : uB5;
    uB6 = advB ? uB7 : uB6; uB7 = advB ? 0x7fffffff : uB7;
  }

  // stage 3: lane<32 -> point A candidate lane; lane>=32 -> point B
  // candidate lane-32. Full 64-dim fp64 dot per lane (4 accums).
  int half = lane >> 5;
  int s32 = lane & 31;
  int ci = myci;
  const f32x4* cr = (const f32x4*)(xt + (bbase + ci) * 64);
  const f32x4* qr = (const f32x4*)qs[wave][half];
  double a0 = 0.0, a1 = 0.0, a2 = 0.0, a3 = 0.0;
#pragma unroll
  for (int t2 = 0; t2 < 16; ++t2) {
    f32x4 cv = cr[t2];
    f32x4 qv = qr[t2];  // ds_read_b128 broadcast within each half
    a0 = fma((double)cv.x, (double)qv.x, a0);
    a1 = fma((double)cv.y, (double)qv.y, a1);
    a2 = fma((double)cv.z, (double)qv.z, a2);
    a3 = fma((double)cv.w, (double)qv.w, a3);
  }
  double dot = (a0 + a1) + (a2 + a3);
  double kd = fma(dot, -2.0, sqd[bbase + ci]) + 1024.0;
  double kv = __longlong_as_double(
      (__double_as_longlong(kd) & ~0x1FFFLL) | (long long)ci);
  klds[wave][half][s32] = kv;

  // stage 4: rank-count over own half's 32 unique exact keys
  {
    const double* kl = klds[wave][half];
    int c0 = 0, c1 = 0, c2 = 0, c3 = 0;
#pragma unroll
    for (int t2 = 0; t2 < 32; t2 += 4) {
      c0 += (kl[t2] < kv) ? 1 : 0;
      c1 += (kl[t2 + 1] < kv) ? 1 : 0;
      c2 += (kl[t2 + 2] < kv) ? 1 : 0;
      c3 += (kl[t2 + 3] < kv) ? 1 : 0;
    }
    int rank = (c0 + c1) + (c2 + c3);
    int pdst = half ? pB : pA;
    if (rank < K_) idxf[(size_t)pdst * K_ + rank] = ci;
  }
}

// ---- Kernel 4: stats v2 — 1-deep gather pipeline across the 4 points.
// The per-point chain {idxf load -> 5 shfl -> 20 L2 gathers -> reduce} was
// fully serial x4 per wave with only 8 waves/SIMD to hide it. v2 preloads
// all 4 idxf vectors (independent) and issues point it+1's gathers BEFORE
// reducing point it (double-buffered G regs): next point's L2 latency hides
// under the current reduce. ~+40 VGPR (waves/SIMD 8->6) for 2x MLP.
__global__ __launch_bounds__(256) void stats_kernel(
    const float* __restrict__ y1, const float* __restrict__ y2,
    const int* __restrict__ idxf, float* __restrict__ maxh,
    float* __restrict__ minh, float* __restrict__ gsum,
    float* __restrict__ gsq) {
  __shared__ float lsum[64], lsq[64];
  int tid = threadIdx.x;
  if (tid < 64) { lsum[tid] = 0.f; lsq[tid] = 0.f; }
  __syncthreads();
  int wv = tid >> 6, lane = tid & 63;
  int u = lane & 15, jb = lane >> 4;
  int p0 = blockIdx.x * 16 + wv * 4;  // 16 contiguous points per block
  size_t nb = (size_t)((p0 >> 13) * N_);
  f32x4 css = {0.f, 0.f, 0.f, 0.f}, cqq = {0.f, 0.f, 0.f, 0.f};

  // preload all 4 points' neighbor indices (independent loads)
  int idxv0 = (lane < K_) ? idxf[(size_t)(p0 + 0) * K_ + lane] : 0;
  int idxv1 = (lane < K_) ? idxf[(size_t)(p0 + 1) * K_ + lane] : 0;
  int idxv2 = (lane < K_) ? idxf[(size_t)(p0 + 2) * K_ + lane] : 0;
  int idxv3 = (lane < K_) ? idxf[(size_t)(p0 + 3) * K_ + lane] : 0;

  f32x4 Ga0, Ga1, Ga2, Ga3, Ga4;  // buffer A
  f32x4 Gb0, Gb1, Gb2, Gb3, Gb4;  // buffer B

#define ISSUE(B0_, B1_, B2_, B3_, B4_, IV)                                 \
  {                                                                        \
    int n0 = __shfl((IV), jb, 64);                                         \
    int n1 = __shfl((IV), jb + 4, 64);                                     \
    int n2 = __shfl((IV), jb + 8, 64);                                     \
    int n3 = __shfl((IV), jb + 12, 64);                                    \
    int n4 = __shfl((IV), jb + 16, 64);                                    \
    B0_ = ((const f32x4*)(y1 + (nb + n0) * 64))[u];                        \
    B1_ = ((const f32x4*)(y1 + (nb + n1) * 64))[u];                        \
    B2_ = ((const f32x4*)(y1 + (nb + n2) * 64))[u];                        \
    B3_ = ((const f32x4*)(y1 + (nb + n3) * 64))[u];                        \
    B4_ = ((const f32x4*)(y1 + (nb + n4) * 64))[u];                        \
  }
#define REDUCE(B0_, B1_, B2_, B3_, B4_, IT)                                \
  {                                                                        \
    int p = p0 + (IT);                                                     \
    f32x4 mx = B0_, mn = B0_, sm = B0_, s2 = B0_ * B0_;                    \
    mx = max4(mx, B1_); mn = min4(mn, B1_); sm += B1_; s2 += B1_ * B1_;    \
    mx = max4(mx, B2_); mn = min4(mn, B2_); sm += B2_; s2 += B2_ * B2_;    \
    mx = max4(mx, B3_); mn = min4(mn, B3_); sm += B3_; s2 += B3_ * B3_;    \
    mx = max4(mx, B4_); mn = min4(mn, B4_); sm += B4_; s2 += B4_ * B4_;    \
    _Pragma("unroll") for (int c = 0; c < 4; ++c) {                        \
      mx[c] = fmaxf(mx[c], __shfl_xor(mx[c], 16, 64));                     \
      mx[c] = fmaxf(mx[c], __shfl_xor(mx[c], 32, 64));                     \
      mn[c] = fminf(mn[c], __shfl_xor(mn[c], 16, 64));                     \
      mn[c] = fminf(mn[c], __shfl_xor(mn[c], 32, 64));                     \
      sm[c] += __shfl_xor(sm[c], 16, 64);                                  \
      sm[c] += __shfl_xor(sm[c], 32, 64);                                  \
      s2[c] += __shfl_xor(s2[c], 16, 64);                                  \
      s2[c] += __shfl_xor(s2[c], 32, 64);                                  \
    }                                                                      \
    if (jb == 0) {                                                         \
      f32x4 y2c = ((const f32x4*)(y2 + (size_t)p * 64))[u];                \
      ((f32x4*)(maxh + (size_t)p * 64))[u] = mx + y2c;                     \
      ((f32x4*)(minh + (size_t)p * 64))[u] = mn + y2c;                     \
      css += sm + 20.0f * y2c;                                             \
      cqq += s2 + 2.0f * y2c * sm + 20.0f * y2c * y2c;                     \
    }                                                                      \
  }

  ISSUE(Ga0, Ga1, Ga2, Ga3, Ga4, idxv0);        // point 0 -> A
  ISSUE(Gb0, Gb1, Gb2, Gb3, Gb4, idxv1);        // point 1 -> B (in flight)
  REDUCE(Ga0, Ga1, Ga2, Ga3, Ga4, 0);           // reduce 0 (hides 1's lat)
  ISSUE(Ga0, Ga1, Ga2, Ga3, Ga4, idxv2);        // point 2 -> A
  REDUCE(Gb0, Gb1, Gb2, Gb3, Gb4, 1);           // reduce 1 (hides 2's lat)
  ISSUE(Gb0, Gb1, Gb2, Gb3, Gb4, idxv3);        // point 3 -> B
  REDUCE(Ga0, Ga1, Ga2, Ga3, Ga4, 2);           // reduce 2 (hides 3's lat)
  REDUCE(Gb0, Gb1, Gb2, Gb3, Gb4, 3);           // reduce 3
#undef ISSUE
#undef REDUCE

  if (jb == 0) {
#pragma unroll
    for (int c = 0; c < 4; ++c) {
      atomicAdd(&lsum[u * 4 + c], css[c]);
      atomicAdd(&lsq[u * 4 + c], cqq[c]);
    }
  }
  __syncthreads();
  if (tid < 64) {
    atomicAdd(&gsum[tid], lsum[tid]);
    atomicAdd(&gsq[tid], lsq[tid]);
  }
}

// ---- Kernel 5: affine + relu + max-over-k selection, transposed store ----
__global__ __launch_bounds__(256) void final_kernel(
    const float* __restrict__ maxh, const float* __restrict__ minh,
    const float* __restrict__ gsum, const float* __restrict__ gsq,
    const float* __restrict__ gamma, const float* __restrict__ beta,
    float* __restrict__ out) {
  __shared__ float sc[64], cc_[64];
  __shared__ float tile[64 * 65];
  int b = blockIdx.x >> 7;
  int n0 = (blockIdx.x & 127) * 64;
  int t = threadIdx.x;
  if (t < 64) {
    float mean = gsum[t] * (1.0f / CNT_TOTAL);
    float var = gsq[t] * (1.0f / CNT_TOTAL) - mean * mean;
    float s = gamma[t] * rsqrtf(var + BN_EPSF);
    sc[t] = s;
    cc_[t] = beta[t] - mean * s;
  }
  __syncthreads();
#pragma unroll
  for (int i = 0; i < 16; ++i) {
    int lin = i * 256 + t;
    int o = lin & 63, nl = lin >> 6;
    size_t off = ((size_t)(b * N_) + n0 + nl) * 64 + o;
    float s = sc[o];
    float v = (s >= 0.f) ? maxh[off] : minh[off];
    float val = fmaxf(fmaf(v, s, cc_[o]), 0.f);
    tile[o * 65 + nl] = val;
  }
  __syncthreads();
#pragma unroll
  for (int i = 0; i < 16; ++i) {
    int lin = i * 256 + t;
    int nl = lin & 63, o = lin >> 6;
    out[((size_t)(b * 64) + o) * N_ + n0 + nl] = tile[o * 65 + nl];
  }
}

extern "C" void kernel_launch(void* const* d_in, const int* in_sizes, int n_in,
                              void* d_out, int out_size, void* d_ws,
                              size_t ws_size, hipStream_t stream) {
  const float* x = (const float*)d_in[0];
  const float* W = (const float*)d_in[1];
  const float* gamma = (const float*)d_in[2];
  const float* beta = (const float*)d_in[3];
  float* out = (float*)d_out;

  char* ws = (char*)d_ws;
  size_t off = 0;
  auto alloc = [&](size_t bytes) {
    char* p = ws + off;
    off += (bytes + 255) & ~(size_t)255;
    return p;
  };
  float* xt = (float*)alloc((size_t)B_ * N_ * 64 * 4);
  _Float16* xt16 = (_Float16*)alloc((size_t)B_ * N_ * 64 * 2);
  float* y1 = (float*)alloc((size_t)B_ * N_ * 64 * 4);
  float* y2 = (float*)alloc((size_t)B_ * N_ * 64 * 4);
  float* sq = (float*)alloc((size_t)B_ * N_ * 4);
  double* sqd = (double*)alloc((size_t)B_ * N_ * 8);
  int* pidx = (int*)alloc((size_t)B_ * N_ * NCAND * 4);  // 67 MB
  float* maxh = (float*)alloc((size_t)B_ * N_ * 64 * 4);
  int* idxf = (int*)alloc((size_t)B_ * N_ * K_ * 4);
  float* gsum = (float*)alloc(256);
  float* gsq = (float*)alloc(256);
  // minh aliases pidx (pidx fully consumed by refine before stats runs)
  float* minh = (float*)pidx;

  hipMemsetAsync(gsum, 0, 256, stream);
  hipMemsetAsync(gsq, 0, 256, stream);

  prep_kernel<<<B_ * (N_ / 64), 256, 0, stream>>>(x, W, xt, xt16, sq, sqd,
                                                  y1, y2);
  knn_mfma_kernel<<<B_ * (N_ / 64) * NSPLIT, 256, 0, stream>>>(xt16, sq, pidx);
  refine_kernel<<<(B_ * N_) / 8, 256, 0, stream>>>(xt, sqd, pidx, idxf);
  stats_kernel<<<(B_ * N_) / 16, 256, 0, stream>>>(y1, y2, idxf, maxh, minh,
                                                   gsum, gsq);
  final_kernel<<<B_ * (N_ / 64), 256, 0, stream>>>(maxh, minh, gsum, gsq,
                                                   gamma, beta, out);
}